// Round 1
// baseline (1070.406 us; speedup 1.0000x reference)
//
#include <hip/hip_runtime.h>
#include <math.h>

#define NN 50000
#define NE 800000
#define HID 256
#define NH 4
#define DH 64

static inline int cdiv(int a, int b) { return (a + b - 1) / b; }

// ------------------------- CSR build -------------------------
__global__ void hist_kernel(const int* __restrict__ dst, int* __restrict__ deg, int e) {
    int i = blockIdx.x * blockDim.x + threadIdx.x;
    if (i < e) atomicAdd(&deg[dst[i]], 1);
}

// single block, 1024 threads; degcur in: degree counts, out: row start offsets (cursor)
__global__ void scan_kernel(int* __restrict__ degcur, int* __restrict__ row_ptr, int n) {
    __shared__ int sums[1024];
    int tid = threadIdx.x;
    int per = (n + 1023) / 1024;
    int s0 = tid * per;
    int s1 = min(s0 + per, n);
    int local = 0;
    for (int i = s0; i < s1; i++) local += degcur[i];
    sums[tid] = local;
    __syncthreads();
    for (int off = 1; off < 1024; off <<= 1) {
        int t = (tid >= off) ? sums[tid - off] : 0;
        __syncthreads();
        sums[tid] += t;
        __syncthreads();
    }
    int run = sums[tid] - local;  // exclusive
    for (int i = s0; i < s1; i++) {
        int d = degcur[i];
        row_ptr[i] = run;
        degcur[i] = run;   // becomes cursor for scatter
        run += d;
    }
    if (tid == 1023) row_ptr[n] = run;
}

__global__ void scatter_kernel(const int* __restrict__ src, const int* __restrict__ dst,
                               int* __restrict__ cursor, int* __restrict__ csr_src, int e) {
    int i = blockIdx.x * blockDim.x + threadIdx.x;
    if (i < e) {
        int p = atomicAdd(&cursor[dst[i]], 1);
        csr_src[p] = src[i];
    }
}

// ------------------------- GEMM (f32 vector) -------------------------
// C[M,256] = A[M,K] @ W[K,256], tile 64x128, BK=32, 256 threads.
// EPI: 0 = plain store; 1 = elu(acc + add + bias); 2 = relu(bn(acc + bias))
#define BM 64
#define BN 128
#define BK 32

template <int EPI>
__global__ __launch_bounds__(256) void gemm_kernel(
    const float* __restrict__ A, const float* __restrict__ W, float* __restrict__ C,
    int M, int K,
    const float* __restrict__ add, const float* __restrict__ bias,
    const float* __restrict__ g, const float* __restrict__ bt,
    const float* __restrict__ mean, const float* __restrict__ var) {
    __shared__ float As[BK][BM + 4];   // transposed: As[k][m]
    __shared__ float Bs[BK][BN + 4];
    int tid = threadIdx.x;
    int tx = tid & 15, ty = tid >> 4;
    int m0 = blockIdx.x * BM;
    int n0 = blockIdx.y * BN;

    float acc[4][8];
#pragma unroll
    for (int i = 0; i < 4; i++)
#pragma unroll
        for (int j = 0; j < 8; j++) acc[i][j] = 0.f;

    int a_r = tid >> 2;          // 0..63
    int a_c = (tid & 3) * 8;     // 0,8,16,24
    int b_r = tid >> 3;          // 0..31
    int b_c = (tid & 7) * 16;

    for (int k0 = 0; k0 < K; k0 += BK) {
        // load A tile (guarded rows), store transposed
        {
            int gr = m0 + a_r;
            float4 v0 = make_float4(0.f, 0.f, 0.f, 0.f), v1 = v0;
            if (gr < M) {
                const float* ap = A + (size_t)gr * K + k0 + a_c;
                v0 = *(const float4*)(ap);
                v1 = *(const float4*)(ap + 4);
            }
            As[a_c + 0][a_r] = v0.x; As[a_c + 1][a_r] = v0.y;
            As[a_c + 2][a_r] = v0.z; As[a_c + 3][a_r] = v0.w;
            As[a_c + 4][a_r] = v1.x; As[a_c + 5][a_r] = v1.y;
            As[a_c + 6][a_r] = v1.z; As[a_c + 7][a_r] = v1.w;
        }
        // load B tile
        {
            const float* bp = W + (size_t)(k0 + b_r) * HID + n0 + b_c;
            float4 u0 = *(const float4*)(bp + 0);
            float4 u1 = *(const float4*)(bp + 4);
            float4 u2 = *(const float4*)(bp + 8);
            float4 u3 = *(const float4*)(bp + 12);
            *(float4*)&Bs[b_r][b_c + 0] = u0;
            *(float4*)&Bs[b_r][b_c + 4] = u1;
            *(float4*)&Bs[b_r][b_c + 8] = u2;
            *(float4*)&Bs[b_r][b_c + 12] = u3;
        }
        __syncthreads();
#pragma unroll
        for (int k = 0; k < BK; k++) {
            float a[4], b[8];
            *(float4*)a = *(const float4*)&As[k][ty * 4];
            *(float4*)(b + 0) = *(const float4*)&Bs[k][tx * 8];
            *(float4*)(b + 4) = *(const float4*)&Bs[k][tx * 8 + 4];
#pragma unroll
            for (int i = 0; i < 4; i++)
#pragma unroll
                for (int j = 0; j < 8; j++) acc[i][j] = fmaf(a[i], b[j], acc[i][j]);
        }
        __syncthreads();
    }

    // epilogue
#pragma unroll
    for (int i = 0; i < 4; i++) {
        int m = m0 + ty * 4 + i;
        if (m >= M) continue;
        size_t row = (size_t)m * HID;
#pragma unroll
        for (int j = 0; j < 8; j++) {
            int n = n0 + tx * 8 + j;
            float v = acc[i][j];
            if (EPI == 0) {
                C[row + n] = v;
            } else if (EPI == 1) {
                v += add[row + n] + bias[n];
                C[row + n] = (v > 0.f) ? v : expm1f(v);
            } else {
                float s = g[n] * rsqrtf(var[n] + 1e-5f);
                v = (v + bias[n] - mean[n]) * s + bt[n];
                C[row + n] = fmaxf(v, 0.f);
            }
        }
    }
}

// ------------------------- attention scores -------------------------
// one wave per node: el[n][h] = sum_d z[n][h*64+d]*al[h*64+d], er likewise
__global__ __launch_bounds__(256) void attn_scores_kernel(
    const float* __restrict__ z, const float* __restrict__ al, const float* __restrict__ ar,
    float4* __restrict__ el4, float4* __restrict__ er4, int n) {
    int wid = threadIdx.x >> 6;
    int lane = threadIdx.x & 63;
    int node = blockIdx.x * 4 + wid;
    if (node >= n) return;
    const float* zr = z + (size_t)node * HID;
    float elv[NH], erv[NH];
#pragma unroll
    for (int h = 0; h < NH; h++) {
        float zv = zr[h * 64 + lane];
        float p = zv * al[h * 64 + lane];
        float q = zv * ar[h * 64 + lane];
#pragma unroll
        for (int off = 32; off; off >>= 1) {
            p += __shfl_xor(p, off);
            q += __shfl_xor(q, off);
        }
        elv[h] = p; erv[h] = q;
    }
    if (lane == 0) {
        el4[node] = make_float4(elv[0], elv[1], elv[2], elv[3]);
        er4[node] = make_float4(erv[0], erv[1], erv[2], erv[3]);
    }
}

// ------------------------- GAT aggregate (one wave per dst node) ---------
__global__ __launch_bounds__(256) void aggregate_kernel(
    const int* __restrict__ row_ptr, const int* __restrict__ csr_src,
    const float4* __restrict__ el4, const float4* __restrict__ er4,
    const float* __restrict__ z, const float* __restrict__ bias,
    float* __restrict__ out, int n) {
    __shared__ float s_w[4][NH][64];
    __shared__ int s_s[4][64];
    int wid = threadIdx.x >> 6;
    int lane = threadIdx.x & 63;
    int node = blockIdx.x * 4 + wid;
    if (node >= n) return;
    int rb = row_ptr[node], re = row_ptr[node + 1];
    int deg = re - rb;
    float4 ern = er4[node];
    float er_h[NH] = {ern.x, ern.y, ern.z, ern.w};

    // pass 1: denominators
    float wsum[NH] = {0.f, 0.f, 0.f, 0.f};
    for (int c = 0; c < deg; c += 64) {
        int i = c + lane;
        if (i < deg) {
            int s = csr_src[rb + i];
            float4 elv = el4[s];
            float ev[NH] = {elv.x, elv.y, elv.z, elv.w};
#pragma unroll
            for (int h = 0; h < NH; h++) {
                float e = ev[h] + er_h[h];
                e = (e > 0.f) ? e : 0.2f * e;
                wsum[h] += __expf(e);
            }
        }
    }
#pragma unroll
    for (int h = 0; h < NH; h++)
#pragma unroll
        for (int off = 32; off; off >>= 1) wsum[h] += __shfl_xor(wsum[h], off);
    float inv[NH];
#pragma unroll
    for (int h = 0; h < NH; h++) inv[h] = (wsum[h] > 0.f) ? 1.f / wsum[h] : 0.f;

    // pass 2: weighted aggregate
    float acc[NH] = {0.f, 0.f, 0.f, 0.f};
    for (int c = 0; c < deg; c += 64) {
        int i = c + lane;
        int cnt = min(64, deg - c);
        if (i < deg) {
            int s = csr_src[rb + i];
            s_s[wid][lane] = s;
            float4 elv = el4[s];
            float ev[NH] = {elv.x, elv.y, elv.z, elv.w};
#pragma unroll
            for (int h = 0; h < NH; h++) {
                float e = ev[h] + er_h[h];
                e = (e > 0.f) ? e : 0.2f * e;
                s_w[wid][h][lane] = __expf(e) * inv[h];
            }
        }
        __builtin_amdgcn_wave_barrier();
        for (int e = 0; e < cnt; e++) {
            int s = s_s[wid][e];
            const float* zr = z + (size_t)s * HID;
#pragma unroll
            for (int h = 0; h < NH; h++) acc[h] += s_w[wid][h][e] * zr[h * 64 + lane];
        }
        __builtin_amdgcn_wave_barrier();
    }
#pragma unroll
    for (int h = 0; h < NH; h++)
        out[(size_t)node * HID + h * 64 + lane] = acc[h] + bias[h * 64 + lane];
}

// ------------------------- MLP head: logits + log_softmax ----------------
__global__ __launch_bounds__(256) void head_kernel(
    const float* __restrict__ m, const float* __restrict__ W2,
    const float* __restrict__ b2, float* __restrict__ out, int n) {
    __shared__ float sW[HID * 47];
    __shared__ float sm[4][HID];
    for (int i = threadIdx.x; i < HID * 47; i += 256) sW[i] = W2[i];
    __syncthreads();
    int wid = threadIdx.x >> 6;
    int lane = threadIdx.x & 63;
    int node = blockIdx.x * 4 + wid;
    if (node >= n) return;
    float4 mv = ((const float4*)(m + (size_t)node * HID))[lane];
    *(float4*)&sm[wid][lane * 4] = mv;
    __builtin_amdgcn_wave_barrier();
    float logit = (lane < 47) ? b2[lane] : -INFINITY;
    if (lane < 47) {
#pragma unroll 4
        for (int k = 0; k < HID; k++) logit = fmaf(sm[wid][k], sW[k * 47 + lane], logit);
    }
    float mx = logit;
#pragma unroll
    for (int off = 32; off; off >>= 1) mx = fmaxf(mx, __shfl_xor(mx, off));
    float ex = (lane < 47) ? __expf(logit - mx) : 0.f;
    float sum = ex;
#pragma unroll
    for (int off = 32; off; off >>= 1) sum += __shfl_xor(sum, off);
    float ls = logit - mx - logf(sum);
    if (lane < 47) out[(size_t)node * 47 + lane] = ls;
}

// ------------------------- launch -------------------------
extern "C" void kernel_launch(void* const* d_in, const int* in_sizes, int n_in,
                              void* d_out, int out_size, void* d_ws, size_t ws_size,
                              hipStream_t stream) {
    const float* x        = (const float*)d_in[0];
    const float* conv0_W  = (const float*)d_in[1];
    const float* conv0_al = (const float*)d_in[2];
    const float* conv0_ar = (const float*)d_in[3];
    const float* conv0_b  = (const float*)d_in[4];
    const float* skip0_W  = (const float*)d_in[5];
    const float* skip0_b  = (const float*)d_in[6];
    const float* conv1_W  = (const float*)d_in[7];
    const float* conv1_al = (const float*)d_in[8];
    const float* conv1_ar = (const float*)d_in[9];
    const float* conv1_b  = (const float*)d_in[10];
    const float* skip1_W  = (const float*)d_in[11];
    const float* skip1_b  = (const float*)d_in[12];
    const float* mlp_W1   = (const float*)d_in[13];
    const float* mlp_b1   = (const float*)d_in[14];
    const float* bn_gamma = (const float*)d_in[15];
    const float* bn_beta  = (const float*)d_in[16];
    const float* bn_mean  = (const float*)d_in[17];
    const float* bn_var   = (const float*)d_in[18];
    const float* mlp_W2   = (const float*)d_in[19];
    const float* mlp_b2   = (const float*)d_in[20];
    const int* edge_src   = (const int*)d_in[21];
    const int* edge_dst   = (const int*)d_in[22];
    float* out = (float*)d_out;

    // workspace carve-up
    char* w = (char*)d_ws;
    size_t off = 0;
    auto alloc = [&](size_t bytes) {
        char* p = w + off;
        off += (bytes + 255) & ~(size_t)255;
        return p;
    };
    int*    row_ptr = (int*)alloc((NN + 1) * sizeof(int));
    int*    cursor  = (int*)alloc(NN * sizeof(int));
    int*    csr_src = (int*)alloc(NE * sizeof(int));
    float4* el4     = (float4*)alloc(NN * sizeof(float4));
    float4* er4     = (float4*)alloc(NN * sizeof(float4));
    float*  zbuf    = (float*)alloc((size_t)NN * HID * sizeof(float));
    float*  aggbuf  = (float*)alloc((size_t)NN * HID * sizeof(float));
    float*  hbuf    = (float*)alloc((size_t)NN * HID * sizeof(float));
    (void)ws_size;

    dim3 gemm_grid(cdiv(NN, BM), HID / BN);
    int nodeblocks = cdiv(NN, 4);

    // CSR build (shared by both layers)
    hipMemsetAsync(cursor, 0, NN * sizeof(int), stream);
    hist_kernel<<<cdiv(NE, 256), 256, 0, stream>>>(edge_dst, cursor, NE);
    scan_kernel<<<1, 1024, 0, stream>>>(cursor, row_ptr, NN);
    scatter_kernel<<<cdiv(NE, 256), 256, 0, stream>>>(edge_src, edge_dst, cursor, csr_src, NE);

    // layer 0
    gemm_kernel<0><<<gemm_grid, 256, 0, stream>>>(x, conv0_W, zbuf, NN, 128,
                                                  nullptr, nullptr, nullptr, nullptr, nullptr, nullptr);
    attn_scores_kernel<<<nodeblocks, 256, 0, stream>>>(zbuf, conv0_al, conv0_ar, el4, er4, NN);
    aggregate_kernel<<<nodeblocks, 256, 0, stream>>>(row_ptr, csr_src, el4, er4, zbuf, conv0_b, aggbuf, NN);
    gemm_kernel<1><<<gemm_grid, 256, 0, stream>>>(x, skip0_W, hbuf, NN, 128,
                                                  aggbuf, skip0_b, nullptr, nullptr, nullptr, nullptr);

    // layer 1
    gemm_kernel<0><<<gemm_grid, 256, 0, stream>>>(hbuf, conv1_W, zbuf, NN, 256,
                                                  nullptr, nullptr, nullptr, nullptr, nullptr, nullptr);
    attn_scores_kernel<<<nodeblocks, 256, 0, stream>>>(zbuf, conv1_al, conv1_ar, el4, er4, NN);
    aggregate_kernel<<<nodeblocks, 256, 0, stream>>>(row_ptr, csr_src, el4, er4, zbuf, conv1_b, aggbuf, NN);
    gemm_kernel<1><<<gemm_grid, 256, 0, stream>>>(hbuf, skip1_W, zbuf, NN, 256,
                                                  aggbuf, skip1_b, nullptr, nullptr, nullptr, nullptr);
    // h2 now lives in zbuf

    // MLP head
    gemm_kernel<2><<<gemm_grid, 256, 0, stream>>>(zbuf, mlp_W1, aggbuf, NN, 256,
                                                  nullptr, mlp_b1, bn_gamma, bn_beta, bn_mean, bn_var);
    head_kernel<<<nodeblocks, 256, 0, stream>>>(aggbuf, mlp_W2, mlp_b2, out, NN);
}

// Round 2
// 853.608 us; speedup vs baseline: 1.2540x; 1.2540x over previous
//
#include <hip/hip_runtime.h>
#include <math.h>

#define NN 50000
#define NE 800000
#define HID 256
#define NH 4
#define DH 64

static inline int cdiv(int a, int b) { return (a + b - 1) / b; }

typedef __attribute__((ext_vector_type(8))) short short8;
typedef __attribute__((ext_vector_type(4))) short short4v;
typedef __attribute__((ext_vector_type(4))) float f32x4;

// bf16 helpers (round-to-nearest-even)
__device__ inline unsigned short f2bf(float x) {
    union { float f; unsigned u; } v; v.f = x;
    unsigned r = v.u + 0x7FFFu + ((v.u >> 16) & 1u);
    return (unsigned short)(r >> 16);
}
__device__ inline float bf2f(unsigned short h) {
    union { unsigned u; float f; } v; v.u = ((unsigned)h) << 16;
    return v.f;
}

// ------------------------- CSR build -------------------------
__global__ void hist_kernel(const int* __restrict__ dst, int* __restrict__ deg, int e) {
    int i = blockIdx.x * blockDim.x + threadIdx.x;
    if (i < e) atomicAdd(&deg[dst[i]], 1);
}

__global__ void scan_kernel(int* __restrict__ degcur, int* __restrict__ row_ptr, int n) {
    __shared__ int sums[1024];
    int tid = threadIdx.x;
    int per = (n + 1023) / 1024;
    int s0 = tid * per;
    int s1 = min(s0 + per, n);
    int local = 0;
    for (int i = s0; i < s1; i++) local += degcur[i];
    sums[tid] = local;
    __syncthreads();
    for (int off = 1; off < 1024; off <<= 1) {
        int t = (tid >= off) ? sums[tid - off] : 0;
        __syncthreads();
        sums[tid] += t;
        __syncthreads();
    }
    int run = sums[tid] - local;  // exclusive
    for (int i = s0; i < s1; i++) {
        int d = degcur[i];
        row_ptr[i] = run;
        degcur[i] = run;   // becomes cursor for scatter
        run += d;
    }
    if (tid == 1023) row_ptr[n] = run;
}

__global__ void scatter_kernel(const int* __restrict__ src, const int* __restrict__ dst,
                               int* __restrict__ cursor, int* __restrict__ csr_src, int e) {
    int i = blockIdx.x * blockDim.x + threadIdx.x;
    if (i < e) {
        int p = atomicAdd(&cursor[dst[i]], 1);
        csr_src[p] = src[i];
    }
}

// ------------------------- weight pre-split (hi/lo bf16, permuted) ------
// W[K][256] f32 -> Bh/Bl in MFMA-fragment order:
// off = kt*8192 + (n>>4)*512 + ((k>>3)&3)*128 + (n&15)*8 + (k&7)
__global__ void wcast_kernel(const float* __restrict__ W,
                             unsigned short* __restrict__ Bh,
                             unsigned short* __restrict__ Bl, int K) {
    int i = blockIdx.x * blockDim.x + threadIdx.x;
    if (i >= K * 256) return;
    int k = i >> 8, n = i & 255;
    float x = W[i];
    unsigned short h = f2bf(x);
    unsigned short l = f2bf(x - bf2f(h));
    int off = (k >> 5) * 8192 + (n >> 4) * 512 + ((k >> 3) & 3) * 128 + (n & 15) * 8 + (k & 7);
    Bh[off] = h;
    Bl[off] = l;
}

// ------------------------- MFMA GEMM (bf16x3 split) ----------------------
// C[M,256] = A[M,K] @ W[K,256].  Tile 64 x 256, BK=32, 256 threads (4 waves),
// each wave owns a 64x64 quadrant (4x4 frags of 16x16x32).
// EPI: 0 = plain; 1 = elu(acc + add + bias); 2 = relu(bn(acc + bias))
template <int EPI>
__global__ __launch_bounds__(256) void gemm_kernel(
    const float* __restrict__ A,
    const unsigned short* __restrict__ Bh_g, const unsigned short* __restrict__ Bl_g,
    float* __restrict__ C, int M, int K,
    const float* __restrict__ add, const float* __restrict__ bias,
    const float* __restrict__ g, const float* __restrict__ bt,
    const float* __restrict__ mean, const float* __restrict__ var) {
    __shared__ short sAh[2048], sAl[2048];   // 64x32 bf16 hi/lo, frag-ordered
    __shared__ short sBh[8192], sBl[8192];   // 32x256 bf16 hi/lo, frag-ordered

    int tid = threadIdx.x;
    int lane = tid & 63;
    int wid = tid >> 6;
    int m0 = blockIdx.x * 64;

    f32x4 acc[4][4];
#pragma unroll
    for (int i = 0; i < 4; i++)
#pragma unroll
        for (int j = 0; j < 4; j++) acc[i][j] = (f32x4){0.f, 0.f, 0.f, 0.f};

    int nkt = K >> 5;
    for (int kt = 0; kt < nkt; kt++) {
        // ---- stage A: 64x32 f32 -> hi/lo bf16, permuted to frag order ----
#pragma unroll
        for (int p = 0; p < 2; p++) {
            int q = tid + p * 256;          // float4 id 0..511
            int r = q >> 3, kq = q & 7;     // row, k-quad
            int gr = m0 + r;
            float4 v = make_float4(0.f, 0.f, 0.f, 0.f);
            if (gr < M) v = *(const float4*)(A + (size_t)gr * K + kt * 32 + kq * 4);
            float f[4] = {v.x, v.y, v.z, v.w};
            short4v h, l;
#pragma unroll
            for (int j = 0; j < 4; j++) {
                unsigned short hh = f2bf(f[j]);
                h[j] = (short)hh;
                l[j] = (short)f2bf(f[j] - bf2f(hh));
            }
            int off = (r >> 4) * 512 + (kq >> 1) * 128 + (r & 15) * 8 + (kq & 1) * 4;
            *(short4v*)&sAh[off] = h;
            *(short4v*)&sAl[off] = l;
        }
        // ---- stage B: contiguous copy of pre-permuted chunk ----
        {
            const short8* gh = (const short8*)Bh_g + kt * 1024;
            const short8* gl = (const short8*)Bl_g + kt * 1024;
            short8* dh = (short8*)sBh;
            short8* dl = (short8*)sBl;
#pragma unroll
            for (int p = 0; p < 4; p++) {
                dh[tid + p * 256] = gh[tid + p * 256];
                dl[tid + p * 256] = gl[tid + p * 256];
            }
        }
        __syncthreads();

        short8 ah[4], am[4];
#pragma unroll
        for (int mf = 0; mf < 4; mf++) {
            ah[mf] = *(const short8*)&sAh[mf * 512 + lane * 8];
            am[mf] = *(const short8*)&sAl[mf * 512 + lane * 8];
        }
#pragma unroll
        for (int nf = 0; nf < 4; nf++) {
            short8 bh = *(const short8*)&sBh[(wid * 4 + nf) * 512 + lane * 8];
            short8 bl = *(const short8*)&sBl[(wid * 4 + nf) * 512 + lane * 8];
#pragma unroll
            for (int mf = 0; mf < 4; mf++) {
                acc[mf][nf] = __builtin_amdgcn_mfma_f32_16x16x32_bf16(ah[mf], bh, acc[mf][nf], 0, 0, 0);
                acc[mf][nf] = __builtin_amdgcn_mfma_f32_16x16x32_bf16(ah[mf], bl, acc[mf][nf], 0, 0, 0);
                acc[mf][nf] = __builtin_amdgcn_mfma_f32_16x16x32_bf16(am[mf], bh, acc[mf][nf], 0, 0, 0);
            }
        }
        __syncthreads();
    }

    // ---- epilogue: C layout col=lane&15, row=(lane>>4)*4+reg ----
#pragma unroll
    for (int mf = 0; mf < 4; mf++) {
        int row0 = m0 + mf * 16 + (lane >> 4) * 4;
#pragma unroll
        for (int reg = 0; reg < 4; reg++) {
            int row = row0 + reg;
            if (row >= M) continue;
            size_t rb = (size_t)row * HID;
#pragma unroll
            for (int nf = 0; nf < 4; nf++) {
                int col = wid * 64 + nf * 16 + (lane & 15);
                float v = acc[mf][nf][reg];
                if (EPI == 0) {
                    C[rb + col] = v;
                } else if (EPI == 1) {
                    v += add[rb + col] + bias[col];
                    C[rb + col] = (v > 0.f) ? v : expm1f(v);
                } else {
                    float s = g[col] * rsqrtf(var[col] + 1e-5f);
                    v = (v + bias[col] - mean[col]) * s + bt[col];
                    C[rb + col] = fmaxf(v, 0.f);
                }
            }
        }
    }
}

// ------------------------- attention scores -------------------------
__global__ __launch_bounds__(256) void attn_scores_kernel(
    const float* __restrict__ z, const float* __restrict__ al, const float* __restrict__ ar,
    float4* __restrict__ el4, float4* __restrict__ er4, int n) {
    int wid = threadIdx.x >> 6;
    int lane = threadIdx.x & 63;
    int node = blockIdx.x * 4 + wid;
    if (node >= n) return;
    const float* zr = z + (size_t)node * HID;
    float elv[NH], erv[NH];
#pragma unroll
    for (int h = 0; h < NH; h++) {
        float zv = zr[h * 64 + lane];
        float p = zv * al[h * 64 + lane];
        float q = zv * ar[h * 64 + lane];
#pragma unroll
        for (int off = 32; off; off >>= 1) {
            p += __shfl_xor(p, off);
            q += __shfl_xor(q, off);
        }
        elv[h] = p; erv[h] = q;
    }
    if (lane == 0) {
        el4[node] = make_float4(elv[0], elv[1], elv[2], elv[3]);
        er4[node] = make_float4(erv[0], erv[1], erv[2], erv[3]);
    }
}

// ------------------------- GAT aggregate (one wave per dst node) ---------
__global__ __launch_bounds__(256) void aggregate_kernel(
    const int* __restrict__ row_ptr, const int* __restrict__ csr_src,
    const float4* __restrict__ el4, const float4* __restrict__ er4,
    const float* __restrict__ z, const float* __restrict__ bias,
    float* __restrict__ out, int n) {
    __shared__ float s_w[4][NH][64];
    __shared__ int s_s[4][64];
    int wid = threadIdx.x >> 6;
    int lane = threadIdx.x & 63;
    int node = blockIdx.x * 4 + wid;
    if (node >= n) return;
    int rb = row_ptr[node], re = row_ptr[node + 1];
    int deg = re - rb;
    float4 ern = er4[node];
    float er_h[NH] = {ern.x, ern.y, ern.z, ern.w};

    // pass 1: denominators
    float wsum[NH] = {0.f, 0.f, 0.f, 0.f};
    for (int c = 0; c < deg; c += 64) {
        int i = c + lane;
        if (i < deg) {
            int s = csr_src[rb + i];
            float4 elv = el4[s];
            float ev[NH] = {elv.x, elv.y, elv.z, elv.w};
#pragma unroll
            for (int h = 0; h < NH; h++) {
                float e = ev[h] + er_h[h];
                e = (e > 0.f) ? e : 0.2f * e;
                wsum[h] += __expf(e);
            }
        }
    }
#pragma unroll
    for (int h = 0; h < NH; h++)
#pragma unroll
        for (int off = 32; off; off >>= 1) wsum[h] += __shfl_xor(wsum[h], off);
    float inv[NH];
#pragma unroll
    for (int h = 0; h < NH; h++) inv[h] = (wsum[h] > 0.f) ? 1.f / wsum[h] : 0.f;

    // pass 2: weighted aggregate
    float acc[NH] = {0.f, 0.f, 0.f, 0.f};
    for (int c = 0; c < deg; c += 64) {
        int i = c + lane;
        int cnt = min(64, deg - c);
        if (i < deg) {
            int s = csr_src[rb + i];
            s_s[wid][lane] = s;
            float4 elv = el4[s];
            float ev[NH] = {elv.x, elv.y, elv.z, elv.w};
#pragma unroll
            for (int h = 0; h < NH; h++) {
                float e = ev[h] + er_h[h];
                e = (e > 0.f) ? e : 0.2f * e;
                s_w[wid][h][lane] = __expf(e) * inv[h];
            }
        }
        __builtin_amdgcn_wave_barrier();
        for (int e = 0; e < cnt; e++) {
            int s = s_s[wid][e];
            const float* zr = z + (size_t)s * HID;
#pragma unroll
            for (int h = 0; h < NH; h++) acc[h] += s_w[wid][h][e] * zr[h * 64 + lane];
        }
        __builtin_amdgcn_wave_barrier();
    }
#pragma unroll
    for (int h = 0; h < NH; h++)
        out[(size_t)node * HID + h * 64 + lane] = acc[h] + bias[h * 64 + lane];
}

// ------------------------- MLP head: logits + log_softmax ----------------
__global__ __launch_bounds__(256) void head_kernel(
    const float* __restrict__ m, const float* __restrict__ W2,
    const float* __restrict__ b2, float* __restrict__ out, int n) {
    __shared__ float sW[HID * 47];
    __shared__ float sm[4][HID];
    for (int i = threadIdx.x; i < HID * 47; i += 256) sW[i] = W2[i];
    __syncthreads();
    int wid = threadIdx.x >> 6;
    int lane = threadIdx.x & 63;
    int node = blockIdx.x * 4 + wid;
    if (node >= n) return;
    float4 mv = ((const float4*)(m + (size_t)node * HID))[lane];
    *(float4*)&sm[wid][lane * 4] = mv;
    __builtin_amdgcn_wave_barrier();
    float logit = (lane < 47) ? b2[lane] : -INFINITY;
    if (lane < 47) {
#pragma unroll 4
        for (int k = 0; k < HID; k++) logit = fmaf(sm[wid][k], sW[k * 47 + lane], logit);
    }
    float mx = logit;
#pragma unroll
    for (int off = 32; off; off >>= 1) mx = fmaxf(mx, __shfl_xor(mx, off));
    float ex = (lane < 47) ? __expf(logit - mx) : 0.f;
    float sum = ex;
#pragma unroll
    for (int off = 32; off; off >>= 1) sum += __shfl_xor(sum, off);
    float ls = logit - mx - logf(sum);
    if (lane < 47) out[(size_t)node * 47 + lane] = ls;
}

// ------------------------- launch -------------------------
extern "C" void kernel_launch(void* const* d_in, const int* in_sizes, int n_in,
                              void* d_out, int out_size, void* d_ws, size_t ws_size,
                              hipStream_t stream) {
    const float* x        = (const float*)d_in[0];
    const float* conv0_W  = (const float*)d_in[1];
    const float* conv0_al = (const float*)d_in[2];
    const float* conv0_ar = (const float*)d_in[3];
    const float* conv0_b  = (const float*)d_in[4];
    const float* skip0_W  = (const float*)d_in[5];
    const float* skip0_b  = (const float*)d_in[6];
    const float* conv1_W  = (const float*)d_in[7];
    const float* conv1_al = (const float*)d_in[8];
    const float* conv1_ar = (const float*)d_in[9];
    const float* conv1_b  = (const float*)d_in[10];
    const float* skip1_W  = (const float*)d_in[11];
    const float* skip1_b  = (const float*)d_in[12];
    const float* mlp_W1   = (const float*)d_in[13];
    const float* mlp_b1   = (const float*)d_in[14];
    const float* bn_gamma = (const float*)d_in[15];
    const float* bn_beta  = (const float*)d_in[16];
    const float* bn_mean  = (const float*)d_in[17];
    const float* bn_var   = (const float*)d_in[18];
    const float* mlp_W2   = (const float*)d_in[19];
    const float* mlp_b2   = (const float*)d_in[20];
    const int* edge_src   = (const int*)d_in[21];
    const int* edge_dst   = (const int*)d_in[22];
    float* out = (float*)d_out;

    // workspace carve-up
    char* w = (char*)d_ws;
    size_t off = 0;
    auto alloc = [&](size_t bytes) {
        char* p = w + off;
        off += (bytes + 255) & ~(size_t)255;
        return p;
    };
    int*    row_ptr = (int*)alloc((NN + 1) * sizeof(int));
    int*    cursor  = (int*)alloc(NN * sizeof(int));
    int*    csr_src = (int*)alloc(NE * sizeof(int));
    float4* el4     = (float4*)alloc(NN * sizeof(float4));
    float4* er4     = (float4*)alloc(NN * sizeof(float4));
    float*  zbuf    = (float*)alloc((size_t)NN * HID * sizeof(float));
    float*  aggbuf  = (float*)alloc((size_t)NN * HID * sizeof(float));
    float*  hbuf    = (float*)alloc((size_t)NN * HID * sizeof(float));
    unsigned short* c0h = (unsigned short*)alloc(128 * 256 * 2);
    unsigned short* c0l = (unsigned short*)alloc(128 * 256 * 2);
    unsigned short* s0h = (unsigned short*)alloc(128 * 256 * 2);
    unsigned short* s0l = (unsigned short*)alloc(128 * 256 * 2);
    unsigned short* c1h = (unsigned short*)alloc(256 * 256 * 2);
    unsigned short* c1l = (unsigned short*)alloc(256 * 256 * 2);
    unsigned short* s1h = (unsigned short*)alloc(256 * 256 * 2);
    unsigned short* s1l = (unsigned short*)alloc(256 * 256 * 2);
    unsigned short* m1h = (unsigned short*)alloc(256 * 256 * 2);
    unsigned short* m1l = (unsigned short*)alloc(256 * 256 * 2);
    (void)ws_size;

    int gemm_grid = cdiv(NN, 64);
    int nodeblocks = cdiv(NN, 4);

    // weight pre-split (hi/lo bf16, permuted fragment layout)
    wcast_kernel<<<cdiv(128 * 256, 256), 256, 0, stream>>>(conv0_W, c0h, c0l, 128);
    wcast_kernel<<<cdiv(128 * 256, 256), 256, 0, stream>>>(skip0_W, s0h, s0l, 128);
    wcast_kernel<<<cdiv(256 * 256, 256), 256, 0, stream>>>(conv1_W, c1h, c1l, 256);
    wcast_kernel<<<cdiv(256 * 256, 256), 256, 0, stream>>>(skip1_W, s1h, s1l, 256);
    wcast_kernel<<<cdiv(256 * 256, 256), 256, 0, stream>>>(mlp_W1, m1h, m1l, 256);

    // CSR build (shared by both layers)
    hipMemsetAsync(cursor, 0, NN * sizeof(int), stream);
    hist_kernel<<<cdiv(NE, 256), 256, 0, stream>>>(edge_dst, cursor, NE);
    scan_kernel<<<1, 1024, 0, stream>>>(cursor, row_ptr, NN);
    scatter_kernel<<<cdiv(NE, 256), 256, 0, stream>>>(edge_src, edge_dst, cursor, csr_src, NE);

    // layer 0
    gemm_kernel<0><<<gemm_grid, 256, 0, stream>>>(x, c0h, c0l, zbuf, NN, 128,
                                                  nullptr, nullptr, nullptr, nullptr, nullptr, nullptr);
    attn_scores_kernel<<<nodeblocks, 256, 0, stream>>>(zbuf, conv0_al, conv0_ar, el4, er4, NN);
    aggregate_kernel<<<nodeblocks, 256, 0, stream>>>(row_ptr, csr_src, el4, er4, zbuf, conv0_b, aggbuf, NN);
    gemm_kernel<1><<<gemm_grid, 256, 0, stream>>>(x, s0h, s0l, hbuf, NN, 128,
                                                  aggbuf, skip0_b, nullptr, nullptr, nullptr, nullptr);

    // layer 1
    gemm_kernel<0><<<gemm_grid, 256, 0, stream>>>(hbuf, c1h, c1l, zbuf, NN, 256,
                                                  nullptr, nullptr, nullptr, nullptr, nullptr, nullptr);
    attn_scores_kernel<<<nodeblocks, 256, 0, stream>>>(zbuf, conv1_al, conv1_ar, el4, er4, NN);
    aggregate_kernel<<<nodeblocks, 256, 0, stream>>>(row_ptr, csr_src, el4, er4, zbuf, conv1_b, aggbuf, NN);
    gemm_kernel<1><<<gemm_grid, 256, 0, stream>>>(hbuf, s1h, s1l, zbuf, NN, 256,
                                                  aggbuf, skip1_b, nullptr, nullptr, nullptr, nullptr);
    // h2 now lives in zbuf

    // MLP head
    gemm_kernel<2><<<gemm_grid, 256, 0, stream>>>(zbuf, m1h, m1l, aggbuf, NN, 256,
                                                  nullptr, mlp_b1, bn_gamma, bn_beta, bn_mean, bn_var);
    head_kernel<<<nodeblocks, 256, 0, stream>>>(aggbuf, mlp_W2, mlp_b2, out, NN);
}

// Round 3
// 716.279 us; speedup vs baseline: 1.4944x; 1.1917x over previous
//
#include <hip/hip_runtime.h>
#include <math.h>

#define NN 50000
#define NE 800000
#define HID 256
#define NH 4
#define DH 64

static inline int cdiv(int a, int b) { return (a + b - 1) / b; }

typedef __attribute__((ext_vector_type(8))) short short8;
typedef __attribute__((ext_vector_type(4))) short short4v;
typedef __attribute__((ext_vector_type(4))) float f32x4;

// bf16 helpers (round-to-nearest-even)
__device__ inline unsigned short f2bf(float x) {
    union { float f; unsigned u; } v; v.f = x;
    unsigned r = v.u + 0x7FFFu + ((v.u >> 16) & 1u);
    return (unsigned short)(r >> 16);
}
__device__ inline float bf2f(unsigned short h) {
    union { unsigned u; float f; } v; v.u = ((unsigned)h) << 16;
    return v.f;
}

// ------------------------- CSR build -------------------------
__global__ void hist_kernel(const int* __restrict__ dst, int* __restrict__ deg, int e) {
    int i = blockIdx.x * blockDim.x + threadIdx.x;
    if (i < e) atomicAdd(&deg[dst[i]], 1);
}

__global__ void scan_kernel(int* __restrict__ degcur, int* __restrict__ row_ptr, int n) {
    __shared__ int sums[1024];
    int tid = threadIdx.x;
    int per = (n + 1023) / 1024;
    int s0 = tid * per;
    int s1 = min(s0 + per, n);
    int local = 0;
    for (int i = s0; i < s1; i++) local += degcur[i];
    sums[tid] = local;
    __syncthreads();
    for (int off = 1; off < 1024; off <<= 1) {
        int t = (tid >= off) ? sums[tid - off] : 0;
        __syncthreads();
        sums[tid] += t;
        __syncthreads();
    }
    int run = sums[tid] - local;  // exclusive
    for (int i = s0; i < s1; i++) {
        int d = degcur[i];
        row_ptr[i] = run;
        degcur[i] = run;   // becomes cursor for scatter
        run += d;
    }
    if (tid == 1023) row_ptr[n] = run;
}

__global__ void scatter_kernel(const int* __restrict__ src, const int* __restrict__ dst,
                               int* __restrict__ cursor, int* __restrict__ csr_src, int e) {
    int i = blockIdx.x * blockDim.x + threadIdx.x;
    if (i < e) {
        int p = atomicAdd(&cursor[dst[i]], 1);
        csr_src[p] = src[i];
    }
}

// ------------------------- weight pre-split (hi/lo bf16, permuted) ------
// 256-col weights: off = (k>>5)*8192 + (n>>4)*512 + ((k>>3)&3)*128 + (n&15)*8 + (k&7)
// head (64-col padded from 47): off = (k>>5)*2048 + (n>>4)*512 + ((k>>3)&3)*128 + (n&15)*8 + (k&7)
__global__ void wcast_all_kernel(
    const float* __restrict__ c0W, const float* __restrict__ s0W,
    const float* __restrict__ c1W, const float* __restrict__ s1W,
    const float* __restrict__ m1W, const float* __restrict__ W2,
    unsigned short* __restrict__ c0h, unsigned short* __restrict__ c0l,
    unsigned short* __restrict__ s0h, unsigned short* __restrict__ s0l,
    unsigned short* __restrict__ c1h, unsigned short* __restrict__ c1l,
    unsigned short* __restrict__ s1h, unsigned short* __restrict__ s1l,
    unsigned short* __restrict__ m1h, unsigned short* __restrict__ m1l,
    unsigned short* __restrict__ hWh, unsigned short* __restrict__ hWl) {
    int i = blockIdx.x * blockDim.x + threadIdx.x;
    const float* W; unsigned short *H, *L; int base; int head = 0;
    if (i < 32768)        { W = c0W; H = c0h; L = c0l; base = i; }
    else if (i < 65536)   { W = s0W; H = s0h; L = s0l; base = i - 32768; }
    else if (i < 131072)  { W = c1W; H = c1h; L = c1l; base = i - 65536; }
    else if (i < 196608)  { W = s1W; H = s1h; L = s1l; base = i - 131072; }
    else if (i < 262144)  { W = m1W; H = m1h; L = m1l; base = i - 196608; }
    else if (i < 278528)  { W = W2;  H = hWh; L = hWl; base = i - 262144; head = 1; }
    else return;
    float x; int off;
    if (!head) {
        int k = base >> 8, n = base & 255;
        x = W[base];
        off = (k >> 5) * 8192 + (n >> 4) * 512 + ((k >> 3) & 3) * 128 + (n & 15) * 8 + (k & 7);
    } else {
        int k = base >> 6, n = base & 63;
        x = (n < 47) ? W[k * 47 + n] : 0.f;
        off = (k >> 5) * 2048 + (n >> 4) * 512 + ((k >> 3) & 3) * 128 + (n & 15) * 8 + (k & 7);
    }
    unsigned short h = f2bf(x);
    unsigned short l = f2bf(x - bf2f(h));
    H[off] = h;
    L[off] = l;
}

// ------------------------- MFMA GEMM (bf16x3 split) ----------------------
// C[M,256] = A[M,K] @ W[K,256].  Tile 64 x 256, BK=32, 256 threads (4 waves),
// each wave owns a 64x64 quadrant (4x4 frags of 16x16x32).
// EPI: 1 = elu(acc + add + bias); 2 = relu(bn(acc + bias)); 3 = plain store + fused attn scores
template <int EPI>
__global__ __launch_bounds__(256) void gemm_kernel(
    const float* __restrict__ A,
    const unsigned short* __restrict__ Bh_g, const unsigned short* __restrict__ Bl_g,
    float* __restrict__ C, int M, int K,
    const float* __restrict__ add, const float* __restrict__ bias,
    const float* __restrict__ g, const float* __restrict__ bt,
    const float* __restrict__ mean, const float* __restrict__ var,
    const float* __restrict__ al, const float* __restrict__ ar,
    float* __restrict__ el, float* __restrict__ er) {
    __shared__ short sAh[2048], sAl[2048];   // 64x32 bf16 hi/lo, frag-ordered
    __shared__ short sBh[8192], sBl[8192];   // 32x256 bf16 hi/lo, frag-ordered

    int tid = threadIdx.x;
    int lane = tid & 63;
    int wid = tid >> 6;
    int m0 = blockIdx.x * 64;

    f32x4 acc[4][4];
#pragma unroll
    for (int i = 0; i < 4; i++)
#pragma unroll
        for (int j = 0; j < 4; j++) acc[i][j] = (f32x4){0.f, 0.f, 0.f, 0.f};

    int nkt = K >> 5;
    for (int kt = 0; kt < nkt; kt++) {
        // ---- stage A: 64x32 f32 -> hi/lo bf16, permuted to frag order ----
#pragma unroll
        for (int p = 0; p < 2; p++) {
            int q = tid + p * 256;          // float4 id 0..511
            int r = q >> 3, kq = q & 7;     // row, k-quad
            int gr = m0 + r;
            float4 v = make_float4(0.f, 0.f, 0.f, 0.f);
            if (gr < M) v = *(const float4*)(A + (size_t)gr * K + kt * 32 + kq * 4);
            float f[4] = {v.x, v.y, v.z, v.w};
            short4v h, l;
#pragma unroll
            for (int j = 0; j < 4; j++) {
                unsigned short hh = f2bf(f[j]);
                h[j] = (short)hh;
                l[j] = (short)f2bf(f[j] - bf2f(hh));
            }
            int off = (r >> 4) * 512 + (kq >> 1) * 128 + (r & 15) * 8 + (kq & 1) * 4;
            *(short4v*)&sAh[off] = h;
            *(short4v*)&sAl[off] = l;
        }
        // ---- stage B: contiguous copy of pre-permuted chunk ----
        {
            const short8* gh = (const short8*)Bh_g + kt * 1024;
            const short8* gl = (const short8*)Bl_g + kt * 1024;
            short8* dh = (short8*)sBh;
            short8* dl = (short8*)sBl;
#pragma unroll
            for (int p = 0; p < 4; p++) {
                dh[tid + p * 256] = gh[tid + p * 256];
                dl[tid + p * 256] = gl[tid + p * 256];
            }
        }
        __syncthreads();

        short8 ah[4], am[4];
#pragma unroll
        for (int mf = 0; mf < 4; mf++) {
            ah[mf] = *(const short8*)&sAh[mf * 512 + lane * 8];
            am[mf] = *(const short8*)&sAl[mf * 512 + lane * 8];
        }
#pragma unroll
        for (int nf = 0; nf < 4; nf++) {
            short8 bh = *(const short8*)&sBh[(wid * 4 + nf) * 512 + lane * 8];
            short8 bl = *(const short8*)&sBl[(wid * 4 + nf) * 512 + lane * 8];
#pragma unroll
            for (int mf = 0; mf < 4; mf++) {
                acc[mf][nf] = __builtin_amdgcn_mfma_f32_16x16x32_bf16(ah[mf], bh, acc[mf][nf], 0, 0, 0);
                acc[mf][nf] = __builtin_amdgcn_mfma_f32_16x16x32_bf16(ah[mf], bl, acc[mf][nf], 0, 0, 0);
                acc[mf][nf] = __builtin_amdgcn_mfma_f32_16x16x32_bf16(am[mf], bh, acc[mf][nf], 0, 0, 0);
            }
        }
        __syncthreads();
    }

    // ---- epilogue: C layout col=lane&15, row=(lane>>4)*4+reg ----
#pragma unroll
    for (int mf = 0; mf < 4; mf++) {
        int row0 = m0 + mf * 16 + (lane >> 4) * 4;
#pragma unroll
        for (int reg = 0; reg < 4; reg++) {
            int row = row0 + reg;
            if (row >= M) continue;
            size_t rb = (size_t)row * HID;
#pragma unroll
            for (int nf = 0; nf < 4; nf++) {
                int col = wid * 64 + nf * 16 + (lane & 15);
                float v = acc[mf][nf][reg];
                if (EPI == 3) {
                    C[rb + col] = v;
                } else if (EPI == 1) {
                    v += add[rb + col] + bias[col];
                    C[rb + col] = (v > 0.f) ? v : expm1f(v);
                } else {
                    float s = g[col] * rsqrtf(var[col] + 1e-5f);
                    v = (v + bias[col] - mean[col]) * s + bt[col];
                    C[rb + col] = fmaxf(v, 0.f);
                }
            }
        }
    }

    // ---- fused attention scores (EPI==3): wave wid == head wid ----
    if (EPI == 3) {
        float alv[4], arv[4];
#pragma unroll
        for (int nf = 0; nf < 4; nf++) {
            int col = wid * 64 + nf * 16 + (lane & 15);
            alv[nf] = al[col];
            arv[nf] = ar[col];
        }
#pragma unroll
        for (int mf = 0; mf < 4; mf++) {
#pragma unroll
            for (int reg = 0; reg < 4; reg++) {
                float pl = 0.f, pr = 0.f;
#pragma unroll
                for (int nf = 0; nf < 4; nf++) {
                    pl = fmaf(acc[mf][nf][reg], alv[nf], pl);
                    pr = fmaf(acc[mf][nf][reg], arv[nf], pr);
                }
#pragma unroll
                for (int off = 8; off; off >>= 1) {
                    pl += __shfl_xor(pl, off);
                    pr += __shfl_xor(pr, off);
                }
                int row = m0 + mf * 16 + (lane >> 4) * 4 + reg;
                if ((lane & 15) == 0 && row < M) {
                    el[row * 4 + wid] = pl;
                    er[row * 4 + wid] = pr;
                }
            }
        }
    }
}

// ------------------------- GAT aggregate (one wave per dst node) ---------
__global__ __launch_bounds__(256) void aggregate_kernel(
    const int* __restrict__ row_ptr, const int* __restrict__ csr_src,
    const float4* __restrict__ el4, const float4* __restrict__ er4,
    const float* __restrict__ z, const float* __restrict__ bias,
    float* __restrict__ out, int n) {
    __shared__ float s_w[4][NH][64];
    __shared__ int s_s[4][64];
    int wid = threadIdx.x >> 6;
    int lane = threadIdx.x & 63;
    int node = blockIdx.x * 4 + wid;
    if (node >= n) return;
    int rb = row_ptr[node], re = row_ptr[node + 1];
    int deg = re - rb;
    float4 ern = er4[node];
    float er_h[NH] = {ern.x, ern.y, ern.z, ern.w};

    // pass 1: denominators
    float wsum[NH] = {0.f, 0.f, 0.f, 0.f};
    for (int c = 0; c < deg; c += 64) {
        int i = c + lane;
        if (i < deg) {
            int s = csr_src[rb + i];
            float4 elv = el4[s];
            float ev[NH] = {elv.x, elv.y, elv.z, elv.w};
#pragma unroll
            for (int h = 0; h < NH; h++) {
                float e = ev[h] + er_h[h];
                e = (e > 0.f) ? e : 0.2f * e;
                wsum[h] += __expf(e);
            }
        }
    }
#pragma unroll
    for (int h = 0; h < NH; h++)
#pragma unroll
        for (int off = 32; off; off >>= 1) wsum[h] += __shfl_xor(wsum[h], off);
    float inv[NH];
#pragma unroll
    for (int h = 0; h < NH; h++) inv[h] = (wsum[h] > 0.f) ? 1.f / wsum[h] : 0.f;

    // pass 2: weighted aggregate
    float acc[NH] = {0.f, 0.f, 0.f, 0.f};
    for (int c = 0; c < deg; c += 64) {
        int i = c + lane;
        int cnt = min(64, deg - c);
        if (i < deg) {
            int s = csr_src[rb + i];
            s_s[wid][lane] = s;
            float4 elv = el4[s];
            float ev[NH] = {elv.x, elv.y, elv.z, elv.w};
#pragma unroll
            for (int h = 0; h < NH; h++) {
                float e = ev[h] + er_h[h];
                e = (e > 0.f) ? e : 0.2f * e;
                s_w[wid][h][lane] = __expf(e) * inv[h];
            }
        }
        __builtin_amdgcn_wave_barrier();
        for (int e = 0; e < cnt; e++) {
            int s = s_s[wid][e];
            const float* zr = z + (size_t)s * HID;
#pragma unroll
            for (int h = 0; h < NH; h++) acc[h] += s_w[wid][h][e] * zr[h * 64 + lane];
        }
        __builtin_amdgcn_wave_barrier();
    }
#pragma unroll
    for (int h = 0; h < NH; h++)
        out[(size_t)node * HID + h * 64 + lane] = acc[h] + bias[h * 64 + lane];
}

// ------------------------- MFMA head: logits + log_softmax ---------------
// Tile 64 rows x 64 cols (47 valid), K=256. 4 waves; wave w = rows [w*16, w*16+16),
// all 64 cols (4 n-frags). Row softmax = 16-lane shuffle reduce.
__global__ __launch_bounds__(256) void head_kernel(
    const float* __restrict__ A, const unsigned short* __restrict__ Bh_g,
    const unsigned short* __restrict__ Bl_g, const float* __restrict__ b2,
    float* __restrict__ out, int M) {
    __shared__ short sAh[2048], sAl[2048];    // 64x32
    __shared__ short sBh[16384], sBl[16384];  // 256x64 (all k)
    int tid = threadIdx.x;
    int lane = tid & 63;
    int wid = tid >> 6;
    int m0 = blockIdx.x * 64;

    // stage all of W2 (pre-permuted) once
#pragma unroll
    for (int p = 0; p < 8; p++) {
        ((short8*)sBh)[tid + p * 256] = ((const short8*)Bh_g)[tid + p * 256];
        ((short8*)sBl)[tid + p * 256] = ((const short8*)Bl_g)[tid + p * 256];
    }

    f32x4 acc[4];
#pragma unroll
    for (int nf = 0; nf < 4; nf++) acc[nf] = (f32x4){0.f, 0.f, 0.f, 0.f};

    for (int kt = 0; kt < 8; kt++) {
#pragma unroll
        for (int p = 0; p < 2; p++) {
            int q = tid + p * 256;
            int r = q >> 3, kq = q & 7;
            int gr = m0 + r;
            float4 v = make_float4(0.f, 0.f, 0.f, 0.f);
            if (gr < M) v = *(const float4*)(A + (size_t)gr * HID + kt * 32 + kq * 4);
            float f[4] = {v.x, v.y, v.z, v.w};
            short4v h, l;
#pragma unroll
            for (int j = 0; j < 4; j++) {
                unsigned short hh = f2bf(f[j]);
                h[j] = (short)hh;
                l[j] = (short)f2bf(f[j] - bf2f(hh));
            }
            int off = (r >> 4) * 512 + (kq >> 1) * 128 + (r & 15) * 8 + (kq & 1) * 4;
            *(short4v*)&sAh[off] = h;
            *(short4v*)&sAl[off] = l;
        }
        __syncthreads();
        short8 ah = *(const short8*)&sAh[wid * 512 + lane * 8];
        short8 am = *(const short8*)&sAl[wid * 512 + lane * 8];
#pragma unroll
        for (int nf = 0; nf < 4; nf++) {
            short8 bh = *(const short8*)&sBh[kt * 2048 + nf * 512 + lane * 8];
            short8 bl = *(const short8*)&sBl[kt * 2048 + nf * 512 + lane * 8];
            acc[nf] = __builtin_amdgcn_mfma_f32_16x16x32_bf16(ah, bh, acc[nf], 0, 0, 0);
            acc[nf] = __builtin_amdgcn_mfma_f32_16x16x32_bf16(ah, bl, acc[nf], 0, 0, 0);
            acc[nf] = __builtin_amdgcn_mfma_f32_16x16x32_bf16(am, bh, acc[nf], 0, 0, 0);
        }
        __syncthreads();
    }

    // fused log-softmax over 47 valid cols; row = m0+wid*16+(lane>>4)*4+reg
    int col0 = lane & 15;
    float bias_[4];
#pragma unroll
    for (int nf = 0; nf < 4; nf++) {
        int col = nf * 16 + col0;
        bias_[nf] = (col < 47) ? b2[col] : 0.f;
    }
#pragma unroll
    for (int reg = 0; reg < 4; reg++) {
        int row = m0 + wid * 16 + (lane >> 4) * 4 + reg;
        float lg[4];
        float mx = -INFINITY;
#pragma unroll
        for (int nf = 0; nf < 4; nf++) {
            int col = nf * 16 + col0;
            float v = acc[nf][reg] + bias_[nf];
            lg[nf] = v;
            if (col < 47) mx = fmaxf(mx, v);
        }
#pragma unroll
        for (int off = 8; off; off >>= 1) mx = fmaxf(mx, __shfl_xor(mx, off));
        float s = 0.f;
#pragma unroll
        for (int nf = 0; nf < 4; nf++) {
            int col = nf * 16 + col0;
            if (col < 47) s += __expf(lg[nf] - mx);
        }
#pragma unroll
        for (int off = 8; off; off >>= 1) s += __shfl_xor(s, off);
        float li = logf(s);
        if (row < M) {
#pragma unroll
            for (int nf = 0; nf < 3; nf++) {
                int col = nf * 16 + col0;
                if (col < 47) out[(size_t)row * 47 + col] = lg[nf] - mx - li;
            }
        }
    }
}

// ------------------------- launch -------------------------
extern "C" void kernel_launch(void* const* d_in, const int* in_sizes, int n_in,
                              void* d_out, int out_size, void* d_ws, size_t ws_size,
                              hipStream_t stream) {
    const float* x        = (const float*)d_in[0];
    const float* conv0_W  = (const float*)d_in[1];
    const float* conv0_al = (const float*)d_in[2];
    const float* conv0_ar = (const float*)d_in[3];
    const float* conv0_b  = (const float*)d_in[4];
    const float* skip0_W  = (const float*)d_in[5];
    const float* skip0_b  = (const float*)d_in[6];
    const float* conv1_W  = (const float*)d_in[7];
    const float* conv1_al = (const float*)d_in[8];
    const float* conv1_ar = (const float*)d_in[9];
    const float* conv1_b  = (const float*)d_in[10];
    const float* skip1_W  = (const float*)d_in[11];
    const float* skip1_b  = (const float*)d_in[12];
    const float* mlp_W1   = (const float*)d_in[13];
    const float* mlp_b1   = (const float*)d_in[14];
    const float* bn_gamma = (const float*)d_in[15];
    const float* bn_beta  = (const float*)d_in[16];
    const float* bn_mean  = (const float*)d_in[17];
    const float* bn_var   = (const float*)d_in[18];
    const float* mlp_W2   = (const float*)d_in[19];
    const float* mlp_b2   = (const float*)d_in[20];
    const int* edge_src   = (const int*)d_in[21];
    const int* edge_dst   = (const int*)d_in[22];
    float* out = (float*)d_out;

    // workspace carve-up
    char* w = (char*)d_ws;
    size_t off = 0;
    auto alloc = [&](size_t bytes) {
        char* p = w + off;
        off += (bytes + 255) & ~(size_t)255;
        return p;
    };
    int*    row_ptr = (int*)alloc((NN + 1) * sizeof(int));
    int*    cursor  = (int*)alloc(NN * sizeof(int));
    int*    csr_src = (int*)alloc(NE * sizeof(int));
    float*  el      = (float*)alloc((size_t)NN * 4 * sizeof(float));
    float*  er      = (float*)alloc((size_t)NN * 4 * sizeof(float));
    float*  zbuf    = (float*)alloc((size_t)NN * HID * sizeof(float));
    float*  aggbuf  = (float*)alloc((size_t)NN * HID * sizeof(float));
    float*  hbuf    = (float*)alloc((size_t)NN * HID * sizeof(float));
    unsigned short* c0h = (unsigned short*)alloc(128 * 256 * 2);
    unsigned short* c0l = (unsigned short*)alloc(128 * 256 * 2);
    unsigned short* s0h = (unsigned short*)alloc(128 * 256 * 2);
    unsigned short* s0l = (unsigned short*)alloc(128 * 256 * 2);
    unsigned short* c1h = (unsigned short*)alloc(256 * 256 * 2);
    unsigned short* c1l = (unsigned short*)alloc(256 * 256 * 2);
    unsigned short* s1h = (unsigned short*)alloc(256 * 256 * 2);
    unsigned short* s1l = (unsigned short*)alloc(256 * 256 * 2);
    unsigned short* m1h = (unsigned short*)alloc(256 * 256 * 2);
    unsigned short* m1l = (unsigned short*)alloc(256 * 256 * 2);
    unsigned short* hWh = (unsigned short*)alloc(256 * 64 * 2);
    unsigned short* hWl = (unsigned short*)alloc(256 * 64 * 2);
    (void)ws_size;

    int gemm_grid = cdiv(NN, 64);
    int nodeblocks = cdiv(NN, 4);

    // weight pre-split (hi/lo bf16, permuted fragment layout) — one launch
    wcast_all_kernel<<<cdiv(278528, 256), 256, 0, stream>>>(
        conv0_W, skip0_W, conv1_W, skip1_W, mlp_W1, mlp_W2,
        c0h, c0l, s0h, s0l, c1h, c1l, s1h, s1l, m1h, m1l, hWh, hWl);

    // CSR build (shared by both layers)
    hipMemsetAsync(cursor, 0, NN * sizeof(int), stream);
    hist_kernel<<<cdiv(NE, 256), 256, 0, stream>>>(edge_dst, cursor, NE);
    scan_kernel<<<1, 1024, 0, stream>>>(cursor, row_ptr, NN);
    scatter_kernel<<<cdiv(NE, 256), 256, 0, stream>>>(edge_src, edge_dst, cursor, csr_src, NE);

    // layer 0
    gemm_kernel<3><<<gemm_grid, 256, 0, stream>>>(x, c0h, c0l, zbuf, NN, 128,
                                                  nullptr, nullptr, nullptr, nullptr, nullptr, nullptr,
                                                  conv0_al, conv0_ar, el, er);
    aggregate_kernel<<<nodeblocks, 256, 0, stream>>>(row_ptr, csr_src, (const float4*)el, (const float4*)er,
                                                     zbuf, conv0_b, aggbuf, NN);
    gemm_kernel<1><<<gemm_grid, 256, 0, stream>>>(x, s0h, s0l, hbuf, NN, 128,
                                                  aggbuf, skip0_b, nullptr, nullptr, nullptr, nullptr,
                                                  nullptr, nullptr, nullptr, nullptr);

    // layer 1
    gemm_kernel<3><<<gemm_grid, 256, 0, stream>>>(hbuf, c1h, c1l, zbuf, NN, 256,
                                                  nullptr, nullptr, nullptr, nullptr, nullptr, nullptr,
                                                  conv1_al, conv1_ar, el, er);
    aggregate_kernel<<<nodeblocks, 256, 0, stream>>>(row_ptr, csr_src, (const float4*)el, (const float4*)er,
                                                     zbuf, conv1_b, aggbuf, NN);
    gemm_kernel<1><<<gemm_grid, 256, 0, stream>>>(hbuf, s1h, s1l, zbuf, NN, 256,
                                                  aggbuf, skip1_b, nullptr, nullptr, nullptr, nullptr,
                                                  nullptr, nullptr, nullptr, nullptr);
    // h2 now lives in zbuf

    // MLP head
    gemm_kernel<2><<<gemm_grid, 256, 0, stream>>>(zbuf, m1h, m1l, aggbuf, NN, 256,
                                                  nullptr, mlp_b1, bn_gamma, bn_beta, bn_mean, bn_var,
                                                  nullptr, nullptr, nullptr, nullptr);
    head_kernel<<<gemm_grid, 256, 0, stream>>>(aggbuf, hWh, hWl, mlp_b2, out, NN);
}

// Round 4
// 589.340 us; speedup vs baseline: 1.8163x; 1.2154x over previous
//
#include <hip/hip_runtime.h>
#include <math.h>

#define NN 50000
#define NE 800000
#define HID 256
#define NH 4
#define DH 64

static inline int cdiv(int a, int b) { return (a + b - 1) / b; }

typedef __attribute__((ext_vector_type(8))) short short8;
typedef __attribute__((ext_vector_type(4))) short short4v;
typedef __attribute__((ext_vector_type(4))) float f32x4;

// bf16 helpers (round-to-nearest-even)
__device__ inline unsigned short f2bf(float x) {
    union { float f; unsigned u; } v; v.f = x;
    unsigned r = v.u + 0x7FFFu + ((v.u >> 16) & 1u);
    return (unsigned short)(r >> 16);
}
__device__ inline float bf2f(unsigned short h) {
    union { unsigned u; float f; } v; v.u = ((unsigned)h) << 16;
    return v.f;
}
__device__ inline short8 zero8() {
    short8 z;
#pragma unroll
    for (int j = 0; j < 8; j++) z[j] = 0;
    return z;
}

// ------------------------- CSR build -------------------------
__global__ void hist_kernel(const int* __restrict__ dst, int* __restrict__ deg, int e) {
    int i = blockIdx.x * blockDim.x + threadIdx.x;
    if (i < e) atomicAdd(&deg[dst[i]], 1);
}

__global__ void scan_kernel(int* __restrict__ degcur, int* __restrict__ row_ptr, int n) {
    __shared__ int sums[1024];
    int tid = threadIdx.x;
    int per = (n + 1023) / 1024;
    int s0 = tid * per;
    int s1 = min(s0 + per, n);
    int local = 0;
    for (int i = s0; i < s1; i++) local += degcur[i];
    sums[tid] = local;
    __syncthreads();
    for (int off = 1; off < 1024; off <<= 1) {
        int t = (tid >= off) ? sums[tid - off] : 0;
        __syncthreads();
        sums[tid] += t;
        __syncthreads();
    }
    int run = sums[tid] - local;  // exclusive
    for (int i = s0; i < s1; i++) {
        int d = degcur[i];
        row_ptr[i] = run;
        degcur[i] = run;   // becomes cursor for scatter
        run += d;
    }
    if (tid == 1023) row_ptr[n] = run;
}

__global__ void scatter_kernel(const int* __restrict__ src, const int* __restrict__ dst,
                               int* __restrict__ cursor, int* __restrict__ csr_src, int e) {
    int i = blockIdx.x * blockDim.x + threadIdx.x;
    if (i < e) {
        int p = atomicAdd(&cursor[dst[i]], 1);
        csr_src[p] = src[i];
    }
}

// ------------------------- weight pre-split (hi/lo bf16, permuted) ------
// 256-col: off = (k>>5)*8192 + (n>>4)*512 + ((k>>3)&3)*128 + (n&15)*8 + (k&7)
// head (64-col padded from 47): off = (k>>5)*2048 + ... same inner
__global__ void wcast_all_kernel(
    const float* __restrict__ c0W, const float* __restrict__ s0W,
    const float* __restrict__ c1W, const float* __restrict__ s1W,
    const float* __restrict__ m1W, const float* __restrict__ W2,
    unsigned short* __restrict__ c0h, unsigned short* __restrict__ c0l,
    unsigned short* __restrict__ s0h, unsigned short* __restrict__ s0l,
    unsigned short* __restrict__ c1h, unsigned short* __restrict__ c1l,
    unsigned short* __restrict__ s1h, unsigned short* __restrict__ s1l,
    unsigned short* __restrict__ m1h, unsigned short* __restrict__ m1l,
    unsigned short* __restrict__ hWh, unsigned short* __restrict__ hWl) {
    int i = blockIdx.x * blockDim.x + threadIdx.x;
    const float* W; unsigned short *H, *L; int base; int head = 0;
    if (i < 32768)        { W = c0W; H = c0h; L = c0l; base = i; }
    else if (i < 65536)   { W = s0W; H = s0h; L = s0l; base = i - 32768; }
    else if (i < 131072)  { W = c1W; H = c1h; L = c1l; base = i - 65536; }
    else if (i < 196608)  { W = s1W; H = s1h; L = s1l; base = i - 131072; }
    else if (i < 262144)  { W = m1W; H = m1h; L = m1l; base = i - 196608; }
    else if (i < 278528)  { W = W2;  H = hWh; L = hWl; base = i - 262144; head = 1; }
    else return;
    float x; int off;
    if (!head) {
        int k = base >> 8, n = base & 255;
        x = W[base];
        off = (k >> 5) * 8192 + (n >> 4) * 512 + ((k >> 3) & 3) * 128 + (n & 15) * 8 + (k & 7);
    } else {
        int k = base >> 6, n = base & 63;
        x = (n < 47) ? W[k * 47 + n] : 0.f;
        off = (k >> 5) * 2048 + (n >> 4) * 512 + ((k >> 3) & 3) * 128 + (n & 15) * 8 + (k & 7);
    }
    unsigned short h = f2bf(x);
    unsigned short l = f2bf(x - bf2f(h));
    H[off] = h;
    L[off] = l;
}

// ------------------------- x pre-split (row-major hi/lo bf16) ------------
__global__ void acast_kernel(const float* __restrict__ in,
                             unsigned short* __restrict__ H,
                             unsigned short* __restrict__ L, int n4) {
    int i = blockIdx.x * blockDim.x + threadIdx.x;
    if (i >= n4) return;
    float4 v = ((const float4*)in)[i];
    float f[4] = {v.x, v.y, v.z, v.w};
    short4v h, l;
#pragma unroll
    for (int j = 0; j < 4; j++) {
        unsigned short hh = f2bf(f[j]);
        h[j] = (short)hh;
        l[j] = (short)f2bf(f[j] - bf2f(hh));
    }
    *(short4v*)&H[i * 4] = h;
    *(short4v*)&L[i * 4] = l;
}

// ------------------------- MFMA GEMM (bf16x3 split, pre-split A) ---------
// C[M,256] = A[M,K] @ W[K,256].  Tile 64 x 256, BK=32, 256 threads (4 waves),
// each wave owns a 64x64 quadrant (4x4 frags of 16x16x32).
// EPI 1: elu(acc+add+bias) -> Ch/Cl bf16 hi/lo
// EPI 2: relu(bn(acc+bias)) -> Ch/Cl bf16 hi/lo
// EPI 3: zb bf16 store + fused attn scores el/er
template <int EPI>
__global__ __launch_bounds__(256) void gemm_kernel(
    const unsigned short* __restrict__ Ah, const unsigned short* __restrict__ Al,
    const unsigned short* __restrict__ Bh_g, const unsigned short* __restrict__ Bl_g,
    int M, int K,
    unsigned short* __restrict__ Ch, unsigned short* __restrict__ Cl,
    const float* __restrict__ add, const float* __restrict__ bias,
    const float* __restrict__ g, const float* __restrict__ bt,
    const float* __restrict__ mean, const float* __restrict__ var,
    unsigned short* __restrict__ zb,
    const float* __restrict__ al, const float* __restrict__ ar,
    float* __restrict__ el, float* __restrict__ er) {
    __shared__ short sAh[2048], sAl[2048];   // 64x32 bf16 hi/lo, frag-ordered
    __shared__ short sBh[8192], sBl[8192];   // 32x256 bf16 hi/lo, frag-ordered

    int tid = threadIdx.x;
    int lane = tid & 63;
    int wid = tid >> 6;
    int m0 = blockIdx.x * 64;

    f32x4 acc[4][4];
#pragma unroll
    for (int i = 0; i < 4; i++)
#pragma unroll
        for (int j = 0; j < 4; j++) acc[i][j] = (f32x4){0.f, 0.f, 0.f, 0.f};

    int nkt = K >> 5;
    for (int kt = 0; kt < nkt; kt++) {
        // ---- stage A: copy pre-split bf16 rows into frag order ----
        {
            int r = tid >> 2, kq = tid & 3;
            int gr = m0 + r;
            short8 h8 = zero8(), l8 = zero8();
            if (gr < M) {
                size_t gb = (size_t)gr * K + kt * 32 + kq * 8;
                h8 = *(const short8*)(Ah + gb);
                l8 = *(const short8*)(Al + gb);
            }
            int off = (r >> 4) * 512 + kq * 128 + (r & 15) * 8;
            *(short8*)&sAh[off] = h8;
            *(short8*)&sAl[off] = l8;
        }
        // ---- stage B: contiguous copy of pre-permuted chunk ----
        {
            const short8* gh = (const short8*)Bh_g + kt * 1024;
            const short8* gl = (const short8*)Bl_g + kt * 1024;
            short8* dh = (short8*)sBh;
            short8* dl = (short8*)sBl;
#pragma unroll
            for (int p = 0; p < 4; p++) {
                dh[tid + p * 256] = gh[tid + p * 256];
                dl[tid + p * 256] = gl[tid + p * 256];
            }
        }
        __syncthreads();

        short8 ah[4], am[4];
#pragma unroll
        for (int mf = 0; mf < 4; mf++) {
            ah[mf] = *(const short8*)&sAh[mf * 512 + lane * 8];
            am[mf] = *(const short8*)&sAl[mf * 512 + lane * 8];
        }
#pragma unroll
        for (int nf = 0; nf < 4; nf++) {
            short8 bh = *(const short8*)&sBh[(wid * 4 + nf) * 512 + lane * 8];
            short8 bl = *(const short8*)&sBl[(wid * 4 + nf) * 512 + lane * 8];
#pragma unroll
            for (int mf = 0; mf < 4; mf++) {
                acc[mf][nf] = __builtin_amdgcn_mfma_f32_16x16x32_bf16(ah[mf], bh, acc[mf][nf], 0, 0, 0);
                acc[mf][nf] = __builtin_amdgcn_mfma_f32_16x16x32_bf16(ah[mf], bl, acc[mf][nf], 0, 0, 0);
                acc[mf][nf] = __builtin_amdgcn_mfma_f32_16x16x32_bf16(am[mf], bh, acc[mf][nf], 0, 0, 0);
            }
        }
        __syncthreads();
    }

    // ---- epilogue: C layout col=lane&15, row=(lane>>4)*4+reg ----
#pragma unroll
    for (int mf = 0; mf < 4; mf++) {
        int row0 = m0 + mf * 16 + (lane >> 4) * 4;
#pragma unroll
        for (int reg = 0; reg < 4; reg++) {
            int row = row0 + reg;
            if (row >= M) continue;
            size_t rb = (size_t)row * HID;
#pragma unroll
            for (int nf = 0; nf < 4; nf++) {
                int col = wid * 64 + nf * 16 + (lane & 15);
                float v = acc[mf][nf][reg];
                if (EPI == 3) {
                    zb[rb + col] = f2bf(v);
                } else if (EPI == 1) {
                    v += add[rb + col] + bias[col];
                    v = (v > 0.f) ? v : expm1f(v);
                    unsigned short hh = f2bf(v);
                    Ch[rb + col] = hh;
                    Cl[rb + col] = f2bf(v - bf2f(hh));
                } else {
                    float s = g[col] * rsqrtf(var[col] + 1e-5f);
                    v = (v + bias[col] - mean[col]) * s + bt[col];
                    v = fmaxf(v, 0.f);
                    unsigned short hh = f2bf(v);
                    Ch[rb + col] = hh;
                    Cl[rb + col] = f2bf(v - bf2f(hh));
                }
            }
        }
    }

    // ---- fused attention scores (EPI==3): wave wid == head wid ----
    if (EPI == 3) {
        float alv[4], arv[4];
#pragma unroll
        for (int nf = 0; nf < 4; nf++) {
            int col = wid * 64 + nf * 16 + (lane & 15);
            alv[nf] = al[col];
            arv[nf] = ar[col];
        }
#pragma unroll
        for (int mf = 0; mf < 4; mf++) {
#pragma unroll
            for (int reg = 0; reg < 4; reg++) {
                float pl = 0.f, pr = 0.f;
#pragma unroll
                for (int nf = 0; nf < 4; nf++) {
                    pl = fmaf(acc[mf][nf][reg], alv[nf], pl);
                    pr = fmaf(acc[mf][nf][reg], arv[nf], pr);
                }
#pragma unroll
                for (int off = 8; off; off >>= 1) {
                    pl += __shfl_xor(pl, off);
                    pr += __shfl_xor(pr, off);
                }
                int row = m0 + mf * 16 + (lane >> 4) * 4 + reg;
                if ((lane & 15) == 0 && row < M) {
                    el[row * 4 + wid] = pl;
                    er[row * 4 + wid] = pr;
                }
            }
        }
    }
}

// ------------------------- GAT aggregate (single pass, bf16 z) ----------
// one wave per dst node; lane owns features [lane*4, lane*4+4) (head = lane>>4)
__global__ __launch_bounds__(256) void aggregate_kernel(
    const int* __restrict__ row_ptr, const int* __restrict__ csr_src,
    const float4* __restrict__ el4, const float4* __restrict__ er4,
    const unsigned short* __restrict__ zb, const float* __restrict__ bias,
    float* __restrict__ out, int n) {
    __shared__ float s_w[4][NH][64];
    __shared__ int s_s[4][64];
    int wid = threadIdx.x >> 6;
    int lane = threadIdx.x & 63;
    int node = blockIdx.x * 4 + wid;
    if (node >= n) return;
    int rb = row_ptr[node];
    int deg = row_ptr[node + 1] - rb;
    float4 ern = er4[node];
    float er_h[NH] = {ern.x, ern.y, ern.z, ern.w};
    int myh = lane >> 4;
    int f0 = lane * 4;

    float4 acc = make_float4(0.f, 0.f, 0.f, 0.f);
    float wsum[NH] = {0.f, 0.f, 0.f, 0.f};

    for (int c = 0; c < deg; c += 64) {
        int i = c + lane;
        int cnt = min(64, deg - c);
        if (i < deg) {
            int s = csr_src[rb + i];
            s_s[wid][lane] = s;
            float4 elv = el4[s];
            float ev[NH] = {elv.x, elv.y, elv.z, elv.w};
#pragma unroll
            for (int h = 0; h < NH; h++) {
                float e = ev[h] + er_h[h];
                e = (e > 0.f) ? e : 0.2f * e;
                float ee = __expf(e);
                s_w[wid][h][lane] = ee;
                wsum[h] += ee;
            }
        }
        __builtin_amdgcn_wave_barrier();
#pragma unroll 2
        for (int e = 0; e < cnt; e++) {
            int s = s_s[wid][e];
            uint2 zv = *(const uint2*)(zb + (size_t)s * HID + f0);
            float wgt = s_w[wid][myh][e];
            union { unsigned u; float f; } a0, a1, a2, a3;
            a0.u = zv.x << 16; a1.u = zv.x & 0xffff0000u;
            a2.u = zv.y << 16; a3.u = zv.y & 0xffff0000u;
            acc.x = fmaf(wgt, a0.f, acc.x);
            acc.y = fmaf(wgt, a1.f, acc.y);
            acc.z = fmaf(wgt, a2.f, acc.z);
            acc.w = fmaf(wgt, a3.f, acc.w);
        }
        __builtin_amdgcn_wave_barrier();
    }
    // reduce per-head denominators across the wave
#pragma unroll
    for (int h = 0; h < NH; h++)
#pragma unroll
        for (int off = 32; off; off >>= 1) wsum[h] += __shfl_xor(wsum[h], off);
    float inv = (wsum[myh] > 0.f) ? 1.f / wsum[myh] : 0.f;
    float4 b4 = *(const float4*)(bias + f0);
    float4 o;
    o.x = acc.x * inv + b4.x;
    o.y = acc.y * inv + b4.y;
    o.z = acc.z * inv + b4.z;
    o.w = acc.w * inv + b4.w;
    *(float4*)(out + (size_t)node * HID + f0) = o;
}

// ------------------------- MFMA head: logits + log_softmax ---------------
__global__ __launch_bounds__(256) void head_kernel(
    const unsigned short* __restrict__ Ah, const unsigned short* __restrict__ Al,
    const unsigned short* __restrict__ Bh_g, const unsigned short* __restrict__ Bl_g,
    const float* __restrict__ b2, float* __restrict__ out, int M) {
    __shared__ short sAh[2048], sAl[2048];    // 64x32
    __shared__ short sBh[16384], sBl[16384];  // 256x64 (all k)
    int tid = threadIdx.x;
    int lane = tid & 63;
    int wid = tid >> 6;
    int m0 = blockIdx.x * 64;

    // stage all of W2 (pre-permuted) once
#pragma unroll
    for (int p = 0; p < 8; p++) {
        ((short8*)sBh)[tid + p * 256] = ((const short8*)Bh_g)[tid + p * 256];
        ((short8*)sBl)[tid + p * 256] = ((const short8*)Bl_g)[tid + p * 256];
    }

    f32x4 acc[4];
#pragma unroll
    for (int nf = 0; nf < 4; nf++) acc[nf] = (f32x4){0.f, 0.f, 0.f, 0.f};

    for (int kt = 0; kt < 8; kt++) {
        {
            int r = tid >> 2, kq = tid & 3;
            int gr = m0 + r;
            short8 h8 = zero8(), l8 = zero8();
            if (gr < M) {
                size_t gb = (size_t)gr * HID + kt * 32 + kq * 8;
                h8 = *(const short8*)(Ah + gb);
                l8 = *(const short8*)(Al + gb);
            }
            int off = (r >> 4) * 512 + kq * 128 + (r & 15) * 8;
            *(short8*)&sAh[off] = h8;
            *(short8*)&sAl[off] = l8;
        }
        __syncthreads();
        short8 ah = *(const short8*)&sAh[wid * 512 + lane * 8];
        short8 am = *(const short8*)&sAl[wid * 512 + lane * 8];
#pragma unroll
        for (int nf = 0; nf < 4; nf++) {
            short8 bh = *(const short8*)&sBh[kt * 2048 + nf * 512 + lane * 8];
            short8 bl = *(const short8*)&sBl[kt * 2048 + nf * 512 + lane * 8];
            acc[nf] = __builtin_amdgcn_mfma_f32_16x16x32_bf16(ah, bh, acc[nf], 0, 0, 0);
            acc[nf] = __builtin_amdgcn_mfma_f32_16x16x32_bf16(ah, bl, acc[nf], 0, 0, 0);
            acc[nf] = __builtin_amdgcn_mfma_f32_16x16x32_bf16(am, bh, acc[nf], 0, 0, 0);
        }
        __syncthreads();
    }

    // fused log-softmax over 47 valid cols; row = m0+wid*16+(lane>>4)*4+reg
    int col0 = lane & 15;
    float bias_[4];
#pragma unroll
    for (int nf = 0; nf < 4; nf++) {
        int col = nf * 16 + col0;
        bias_[nf] = (col < 47) ? b2[col] : 0.f;
    }
#pragma unroll
    for (int reg = 0; reg < 4; reg++) {
        int row = m0 + wid * 16 + (lane >> 4) * 4 + reg;
        float lg[4];
        float mx = -INFINITY;
#pragma unroll
        for (int nf = 0; nf < 4; nf++) {
            int col = nf * 16 + col0;
            float v = acc[nf][reg] + bias_[nf];
            lg[nf] = v;
            if (col < 47) mx = fmaxf(mx, v);
        }
#pragma unroll
        for (int off = 8; off; off >>= 1) mx = fmaxf(mx, __shfl_xor(mx, off));
        float s = 0.f;
#pragma unroll
        for (int nf = 0; nf < 4; nf++) {
            int col = nf * 16 + col0;
            if (col < 47) s += __expf(lg[nf] - mx);
        }
#pragma unroll
        for (int off = 8; off; off >>= 1) s += __shfl_xor(s, off);
        float li = logf(s);
        if (row < M) {
#pragma unroll
            for (int nf = 0; nf < 3; nf++) {
                int col = nf * 16 + col0;
                if (col < 47) out[(size_t)row * 47 + col] = lg[nf] - mx - li;
            }
        }
    }
}

// ------------------------- launch -------------------------
extern "C" void kernel_launch(void* const* d_in, const int* in_sizes, int n_in,
                              void* d_out, int out_size, void* d_ws, size_t ws_size,
                              hipStream_t stream) {
    const float* x        = (const float*)d_in[0];
    const float* conv0_W  = (const float*)d_in[1];
    const float* conv0_al = (const float*)d_in[2];
    const float* conv0_ar = (const float*)d_in[3];
    const float* conv0_b  = (const float*)d_in[4];
    const float* skip0_W  = (const float*)d_in[5];
    const float* skip0_b  = (const float*)d_in[6];
    const float* conv1_W  = (const float*)d_in[7];
    const float* conv1_al = (const float*)d_in[8];
    const float* conv1_ar = (const float*)d_in[9];
    const float* conv1_b  = (const float*)d_in[10];
    const float* skip1_W  = (const float*)d_in[11];
    const float* skip1_b  = (const float*)d_in[12];
    const float* mlp_W1   = (const float*)d_in[13];
    const float* mlp_b1   = (const float*)d_in[14];
    const float* bn_gamma = (const float*)d_in[15];
    const float* bn_beta  = (const float*)d_in[16];
    const float* bn_mean  = (const float*)d_in[17];
    const float* bn_var   = (const float*)d_in[18];
    const float* mlp_W2   = (const float*)d_in[19];
    const float* mlp_b2   = (const float*)d_in[20];
    const int* edge_src   = (const int*)d_in[21];
    const int* edge_dst   = (const int*)d_in[22];
    float* out = (float*)d_out;

    // workspace carve-up (with aliasing)
    char* w = (char*)d_ws;
    size_t off = 0;
    auto alloc = [&](size_t bytes) {
        char* p = w + off;
        off += (bytes + 255) & ~(size_t)255;
        return p;
    };
    int*    row_ptr = (int*)alloc((NN + 1) * sizeof(int));
    int*    cursor  = (int*)alloc(NN * sizeof(int));
    int*    csr_src = (int*)alloc(NE * sizeof(int));
    float*  el      = (float*)alloc((size_t)NN * 4 * sizeof(float));
    float*  er      = (float*)alloc((size_t)NN * 4 * sizeof(float));
    float*  aggbuf  = (float*)alloc((size_t)NN * HID * sizeof(float));          // also ml
    unsigned short* zb   = (unsigned short*)alloc((size_t)NN * HID * 2);        // also mh
    unsigned short* slA  = (unsigned short*)alloc((size_t)NN * HID * 2);        // xh then h2h
    unsigned short* slB  = (unsigned short*)alloc((size_t)NN * HID * 2);        // xl then h2l
    unsigned short* hh   = (unsigned short*)alloc((size_t)NN * HID * 2);
    unsigned short* hl   = (unsigned short*)alloc((size_t)NN * HID * 2);
    unsigned short* c0h = (unsigned short*)alloc(128 * 256 * 2);
    unsigned short* c0l = (unsigned short*)alloc(128 * 256 * 2);
    unsigned short* s0h = (unsigned short*)alloc(128 * 256 * 2);
    unsigned short* s0l = (unsigned short*)alloc(128 * 256 * 2);
    unsigned short* c1h = (unsigned short*)alloc(256 * 256 * 2);
    unsigned short* c1l = (unsigned short*)alloc(256 * 256 * 2);
    unsigned short* s1h = (unsigned short*)alloc(256 * 256 * 2);
    unsigned short* s1l = (unsigned short*)alloc(256 * 256 * 2);
    unsigned short* m1h = (unsigned short*)alloc(256 * 256 * 2);
    unsigned short* m1l = (unsigned short*)alloc(256 * 256 * 2);
    unsigned short* hWh = (unsigned short*)alloc(256 * 64 * 2);
    unsigned short* hWl = (unsigned short*)alloc(256 * 64 * 2);
    (void)ws_size;

    unsigned short* xh = slA;   // 50000x128 (uses half the slab)
    unsigned short* xl = slB;
    unsigned short* h2h = slA;  // alive after x is dead
    unsigned short* h2l = slB;
    unsigned short* mh = zb;    // alive after zb is dead
    unsigned short* ml = (unsigned short*)aggbuf;

    int gemm_grid = cdiv(NN, 64);
    int nodeblocks = cdiv(NN, 4);

    // weight pre-split + x pre-split
    wcast_all_kernel<<<cdiv(278528, 256), 256, 0, stream>>>(
        conv0_W, skip0_W, conv1_W, skip1_W, mlp_W1, mlp_W2,
        c0h, c0l, s0h, s0l, c1h, c1l, s1h, s1l, m1h, m1l, hWh, hWl);
    acast_kernel<<<cdiv(NN * 128 / 4, 256), 256, 0, stream>>>(x, xh, xl, NN * 128 / 4);

    // CSR build (shared by both layers)
    hipMemsetAsync(cursor, 0, NN * sizeof(int), stream);
    hist_kernel<<<cdiv(NE, 256), 256, 0, stream>>>(edge_dst, cursor, NE);
    scan_kernel<<<1, 1024, 0, stream>>>(cursor, row_ptr, NN);
    scatter_kernel<<<cdiv(NE, 256), 256, 0, stream>>>(edge_src, edge_dst, cursor, csr_src, NE);

    // layer 0
    gemm_kernel<3><<<gemm_grid, 256, 0, stream>>>(xh, xl, c0h, c0l, NN, 128,
        nullptr, nullptr, nullptr, nullptr, nullptr, nullptr, nullptr, nullptr,
        zb, conv0_al, conv0_ar, el, er);
    aggregate_kernel<<<nodeblocks, 256, 0, stream>>>(row_ptr, csr_src, (const float4*)el, (const float4*)er,
                                                     zb, conv0_b, aggbuf, NN);
    gemm_kernel<1><<<gemm_grid, 256, 0, stream>>>(xh, xl, s0h, s0l, NN, 128,
        hh, hl, aggbuf, skip0_b, nullptr, nullptr, nullptr, nullptr,
        nullptr, nullptr, nullptr, nullptr, nullptr);

    // layer 1
    gemm_kernel<3><<<gemm_grid, 256, 0, stream>>>(hh, hl, c1h, c1l, NN, 256,
        nullptr, nullptr, nullptr, nullptr, nullptr, nullptr, nullptr, nullptr,
        zb, conv1_al, conv1_ar, el, er);
    aggregate_kernel<<<nodeblocks, 256, 0, stream>>>(row_ptr, csr_src, (const float4*)el, (const float4*)er,
                                                     zb, conv1_b, aggbuf, NN);
    gemm_kernel<1><<<gemm_grid, 256, 0, stream>>>(hh, hl, s1h, s1l, NN, 256,
        h2h, h2l, aggbuf, skip1_b, nullptr, nullptr, nullptr, nullptr,
        nullptr, nullptr, nullptr, nullptr, nullptr);

    // MLP head: m = relu(bn(h2 @ W1 + b1));  (mh/ml alias zb/aggbuf, both dead now)
    gemm_kernel<2><<<gemm_grid, 256, 0, stream>>>(h2h, h2l, m1h, m1l, NN, 256,
        mh, ml, nullptr, mlp_b1, bn_gamma, bn_beta, bn_mean, bn_var,
        nullptr, nullptr, nullptr, nullptr, nullptr);
    head_kernel<<<gemm_grid, 256, 0, stream>>>(mh, ml, hWh, hWl, mlp_b2, out, NN);
}

// Round 5
// 490.143 us; speedup vs baseline: 2.1839x; 1.2024x over previous
//
#include <hip/hip_runtime.h>
#include <math.h>

#define NN 50000
#define NE 800000
#define HID 256
#define NH 4
#define DH 64

static inline int cdiv(int a, int b) { return (a + b - 1) / b; }

typedef __attribute__((ext_vector_type(8))) short short8;
typedef __attribute__((ext_vector_type(4))) short short4v;
typedef __attribute__((ext_vector_type(4))) float f32x4;

// bf16 helpers (round-to-nearest-even)
__device__ inline unsigned short f2bf(float x) {
    union { float f; unsigned u; } v; v.f = x;
    unsigned r = v.u + 0x7FFFu + ((v.u >> 16) & 1u);
    return (unsigned short)(r >> 16);
}
__device__ inline float bf2f(unsigned short h) {
    union { unsigned u; float f; } v; v.u = ((unsigned)h) << 16;
    return v.f;
}
__device__ inline short8 zero8() {
    short8 z;
#pragma unroll
    for (int j = 0; j < 8; j++) z[j] = 0;
    return z;
}

// ------------------------- CSR build -------------------------
__global__ void hist_kernel(const int* __restrict__ dst, int* __restrict__ deg, int e) {
    int i = blockIdx.x * blockDim.x + threadIdx.x;
    if (i < e) atomicAdd(&deg[dst[i]], 1);
}

// two-level parallel exclusive scan over deg[n] (196 blocks x 256)
__global__ void scan1_kernel(const int* __restrict__ deg, int* __restrict__ local,
                             int* __restrict__ bsum, int n) {
    __shared__ int s[256];
    int tid = threadIdx.x;
    int i = blockIdx.x * 256 + tid;
    int v = (i < n) ? deg[i] : 0;
    s[tid] = v;
    __syncthreads();
    for (int off = 1; off < 256; off <<= 1) {
        int t = (tid >= off) ? s[tid - off] : 0;
        __syncthreads();
        s[tid] += t;
        __syncthreads();
    }
    if (i < n) local[i] = s[tid] - v;      // exclusive within block
    if (tid == 255) bsum[blockIdx.x] = s[255];
}

// single small block: exclusive scan of nb block sums (nb <= 256)
__global__ void scan2_kernel(int* __restrict__ bsum, int nb) {
    __shared__ int s[256];
    int tid = threadIdx.x;
    int v = (tid < nb) ? bsum[tid] : 0;
    s[tid] = v;
    __syncthreads();
    for (int off = 1; off < 256; off <<= 1) {
        int t = (tid >= off) ? s[tid - off] : 0;
        __syncthreads();
        s[tid] += t;
        __syncthreads();
    }
    if (tid < nb) bsum[tid] = s[tid] - v;  // exclusive
    if (tid == 255) bsum[nb] = s[255];     // total
}

// add block offsets; emit row_ptr, cursor, row_ptr[n]
__global__ void scan3_kernel(const int* __restrict__ bsum, int* __restrict__ row_ptr,
                             int* __restrict__ cursor, int n, int nb) {
    int i = blockIdx.x * 256 + threadIdx.x;
    if (i < n) {
        int r = row_ptr[i] + bsum[blockIdx.x];
        row_ptr[i] = r;
        cursor[i] = r;
    }
    if (i == 0) row_ptr[n] = bsum[nb];
}

__global__ void scatter_kernel(const int* __restrict__ src, const int* __restrict__ dst,
                               int* __restrict__ cursor, int* __restrict__ csr_src, int e) {
    int i = blockIdx.x * blockDim.x + threadIdx.x;
    if (i < e) {
        int p = atomicAdd(&cursor[dst[i]], 1);
        csr_src[p] = src[i];
    }
}

// ------------------------- weight pre-split (hi/lo bf16, permuted) ------
// 256-col: off = (k>>5)*8192 + (n>>4)*512 + ((k>>3)&3)*128 + (n&15)*8 + (k&7)
// head (64-col padded from 47): off = (k>>5)*2048 + ... same inner
__global__ void wcast_all_kernel(
    const float* __restrict__ c0W, const float* __restrict__ s0W,
    const float* __restrict__ c1W, const float* __restrict__ s1W,
    const float* __restrict__ m1W, const float* __restrict__ W2,
    unsigned short* __restrict__ c0h, unsigned short* __restrict__ c0l,
    unsigned short* __restrict__ s0h, unsigned short* __restrict__ s0l,
    unsigned short* __restrict__ c1h, unsigned short* __restrict__ c1l,
    unsigned short* __restrict__ s1h, unsigned short* __restrict__ s1l,
    unsigned short* __restrict__ m1h, unsigned short* __restrict__ m1l,
    unsigned short* __restrict__ hWh, unsigned short* __restrict__ hWl) {
    int i = blockIdx.x * blockDim.x + threadIdx.x;
    const float* W; unsigned short *H, *L; int base; int head = 0;
    if (i < 32768)        { W = c0W; H = c0h; L = c0l; base = i; }
    else if (i < 65536)   { W = s0W; H = s0h; L = s0l; base = i - 32768; }
    else if (i < 131072)  { W = c1W; H = c1h; L = c1l; base = i - 65536; }
    else if (i < 196608)  { W = s1W; H = s1h; L = s1l; base = i - 131072; }
    else if (i < 262144)  { W = m1W; H = m1h; L = m1l; base = i - 196608; }
    else if (i < 278528)  { W = W2;  H = hWh; L = hWl; base = i - 262144; head = 1; }
    else return;
    float x; int off;
    if (!head) {
        int k = base >> 8, n = base & 255;
        x = W[base];
        off = (k >> 5) * 8192 + (n >> 4) * 512 + ((k >> 3) & 3) * 128 + (n & 15) * 8 + (k & 7);
    } else {
        int k = base >> 6, n = base & 63;
        x = (n < 47) ? W[k * 47 + n] : 0.f;
        off = (k >> 5) * 2048 + (n >> 4) * 512 + ((k >> 3) & 3) * 128 + (n & 15) * 8 + (k & 7);
    }
    unsigned short h = f2bf(x);
    unsigned short l = f2bf(x - bf2f(h));
    H[off] = h;
    L[off] = l;
}

// ------------------------- x pre-split (row-major hi/lo bf16) ------------
__global__ void acast_kernel(const float* __restrict__ in,
                             unsigned short* __restrict__ H,
                             unsigned short* __restrict__ L, int n4) {
    int i = blockIdx.x * blockDim.x + threadIdx.x;
    if (i >= n4) return;
    float4 v = ((const float4*)in)[i];
    float f[4] = {v.x, v.y, v.z, v.w};
    short4v h, l;
#pragma unroll
    for (int j = 0; j < 4; j++) {
        unsigned short hh = f2bf(f[j]);
        h[j] = (short)hh;
        l[j] = (short)f2bf(f[j] - bf2f(hh));
    }
    *(short4v*)&H[i * 4] = h;
    *(short4v*)&L[i * 4] = l;
}

// ------------------------- MFMA GEMM (bf16x3 split, pre-split A) ---------
// C[M,256] = A[M,K] @ W[K,256].  Tile 64 x 256, BK=32, 256 threads (4 waves),
// each wave owns a 64x64 quadrant (4x4 frags of 16x16x32).
// EPI 1: elu(acc+add+bias) -> Ch/Cl bf16 hi/lo
// EPI 2: relu(bn(acc+bias)) -> Ch/Cl bf16 hi/lo
// EPI 3: zb bf16 store + fused attn scores el/er
template <int EPI>
__global__ __launch_bounds__(256) void gemm_kernel(
    const unsigned short* __restrict__ Ah, const unsigned short* __restrict__ Al,
    const unsigned short* __restrict__ Bh_g, const unsigned short* __restrict__ Bl_g,
    int M, int K,
    unsigned short* __restrict__ Ch, unsigned short* __restrict__ Cl,
    const float* __restrict__ add, const float* __restrict__ bias,
    const float* __restrict__ g, const float* __restrict__ bt,
    const float* __restrict__ mean, const float* __restrict__ var,
    unsigned short* __restrict__ zb,
    const float* __restrict__ al, const float* __restrict__ ar,
    float* __restrict__ el, float* __restrict__ er) {
    __shared__ short sAh[2048], sAl[2048];   // 64x32 bf16 hi/lo, frag-ordered
    __shared__ short sBh[8192], sBl[8192];   // 32x256 bf16 hi/lo, frag-ordered

    int tid = threadIdx.x;
    int lane = tid & 63;
    int wid = tid >> 6;
    int m0 = blockIdx.x * 64;

    f32x4 acc[4][4];
#pragma unroll
    for (int i = 0; i < 4; i++)
#pragma unroll
        for (int j = 0; j < 4; j++) acc[i][j] = (f32x4){0.f, 0.f, 0.f, 0.f};

    int nkt = K >> 5;
    for (int kt = 0; kt < nkt; kt++) {
        // ---- stage A: copy pre-split bf16 rows into frag order ----
        {
            int r = tid >> 2, kq = tid & 3;
            int gr = m0 + r;
            short8 h8 = zero8(), l8 = zero8();
            if (gr < M) {
                size_t gb = (size_t)gr * K + kt * 32 + kq * 8;
                h8 = *(const short8*)(Ah + gb);
                l8 = *(const short8*)(Al + gb);
            }
            int off = (r >> 4) * 512 + kq * 128 + (r & 15) * 8;
            *(short8*)&sAh[off] = h8;
            *(short8*)&sAl[off] = l8;
        }
        // ---- stage B: contiguous copy of pre-permuted chunk ----
        {
            const short8* gh = (const short8*)Bh_g + kt * 1024;
            const short8* gl = (const short8*)Bl_g + kt * 1024;
            short8* dh = (short8*)sBh;
            short8* dl = (short8*)sBl;
#pragma unroll
            for (int p = 0; p < 4; p++) {
                dh[tid + p * 256] = gh[tid + p * 256];
                dl[tid + p * 256] = gl[tid + p * 256];
            }
        }
        __syncthreads();

        short8 ah[4], am[4];
#pragma unroll
        for (int mf = 0; mf < 4; mf++) {
            ah[mf] = *(const short8*)&sAh[mf * 512 + lane * 8];
            am[mf] = *(const short8*)&sAl[mf * 512 + lane * 8];
        }
#pragma unroll
        for (int nf = 0; nf < 4; nf++) {
            short8 bh = *(const short8*)&sBh[(wid * 4 + nf) * 512 + lane * 8];
            short8 bl = *(const short8*)&sBl[(wid * 4 + nf) * 512 + lane * 8];
#pragma unroll
            for (int mf = 0; mf < 4; mf++) {
                acc[mf][nf] = __builtin_amdgcn_mfma_f32_16x16x32_bf16(ah[mf], bh, acc[mf][nf], 0, 0, 0);
                acc[mf][nf] = __builtin_amdgcn_mfma_f32_16x16x32_bf16(ah[mf], bl, acc[mf][nf], 0, 0, 0);
                acc[mf][nf] = __builtin_amdgcn_mfma_f32_16x16x32_bf16(am[mf], bh, acc[mf][nf], 0, 0, 0);
            }
        }
        __syncthreads();
    }

    // ---- epilogue: C layout col=lane&15, row=(lane>>4)*4+reg ----
#pragma unroll
    for (int mf = 0; mf < 4; mf++) {
        int row0 = m0 + mf * 16 + (lane >> 4) * 4;
#pragma unroll
        for (int reg = 0; reg < 4; reg++) {
            int row = row0 + reg;
            if (row >= M) continue;
            size_t rb = (size_t)row * HID;
#pragma unroll
            for (int nf = 0; nf < 4; nf++) {
                int col = wid * 64 + nf * 16 + (lane & 15);
                float v = acc[mf][nf][reg];
                if (EPI == 3) {
                    zb[rb + col] = f2bf(v);
                } else if (EPI == 1) {
                    v += add[rb + col] + bias[col];
                    v = (v > 0.f) ? v : expm1f(v);
                    unsigned short hh = f2bf(v);
                    Ch[rb + col] = hh;
                    Cl[rb + col] = f2bf(v - bf2f(hh));
                } else {
                    float s = g[col] * rsqrtf(var[col] + 1e-5f);
                    v = (v + bias[col] - mean[col]) * s + bt[col];
                    v = fmaxf(v, 0.f);
                    unsigned short hh = f2bf(v);
                    Ch[rb + col] = hh;
                    Cl[rb + col] = f2bf(v - bf2f(hh));
                }
            }
        }
    }

    // ---- fused attention scores (EPI==3): wave wid == head wid ----
    if (EPI == 3) {
        float alv[4], arv[4];
#pragma unroll
        for (int nf = 0; nf < 4; nf++) {
            int col = wid * 64 + nf * 16 + (lane & 15);
            alv[nf] = al[col];
            arv[nf] = ar[col];
        }
#pragma unroll
        for (int mf = 0; mf < 4; mf++) {
#pragma unroll
            for (int reg = 0; reg < 4; reg++) {
                float pl = 0.f, pr = 0.f;
#pragma unroll
                for (int nf = 0; nf < 4; nf++) {
                    pl = fmaf(acc[mf][nf][reg], alv[nf], pl);
                    pr = fmaf(acc[mf][nf][reg], arv[nf], pr);
                }
#pragma unroll
                for (int off = 8; off; off >>= 1) {
                    pl += __shfl_xor(pl, off);
                    pr += __shfl_xor(pr, off);
                }
                int row = m0 + mf * 16 + (lane >> 4) * 4 + reg;
                if ((lane & 15) == 0 && row < M) {
                    el[row * 4 + wid] = pl;
                    er[row * 4 + wid] = pr;
                }
            }
        }
    }
}

// ------------------------- GAT aggregate (single pass, bf16 z) ----------
// one wave per dst node; lane owns features [lane*4, lane*4+4) (head = lane>>4)
__global__ __launch_bounds__(256) void aggregate_kernel(
    const int* __restrict__ row_ptr, const int* __restrict__ csr_src,
    const float4* __restrict__ el4, const float4* __restrict__ er4,
    const unsigned short* __restrict__ zb, const float* __restrict__ bias,
    float* __restrict__ out, int n) {
    __shared__ float s_w[4][NH][64];
    __shared__ int s_s[4][64];
    int wid = threadIdx.x >> 6;
    int lane = threadIdx.x & 63;
    int node = blockIdx.x * 4 + wid;
    if (node >= n) return;
    int rb = row_ptr[node];
    int deg = row_ptr[node + 1] - rb;
    float4 ern = er4[node];
    float er_h[NH] = {ern.x, ern.y, ern.z, ern.w};
    int myh = lane >> 4;
    int f0 = lane * 4;

    float4 acc = make_float4(0.f, 0.f, 0.f, 0.f);
    float wsum[NH] = {0.f, 0.f, 0.f, 0.f};

    for (int c = 0; c < deg; c += 64) {
        int i = c + lane;
        int cnt = min(64, deg - c);
        if (i < deg) {
            int s = csr_src[rb + i];
            s_s[wid][lane] = s;
            float4 elv = el4[s];
            float ev[NH] = {elv.x, elv.y, elv.z, elv.w};
#pragma unroll
            for (int h = 0; h < NH; h++) {
                float e = ev[h] + er_h[h];
                e = (e > 0.f) ? e : 0.2f * e;
                float ee = __expf(e);
                s_w[wid][h][lane] = ee;
                wsum[h] += ee;
            }
        }
        __builtin_amdgcn_wave_barrier();
#pragma unroll 2
        for (int e = 0; e < cnt; e++) {
            int s = s_s[wid][e];
            uint2 zv = *(const uint2*)(zb + (size_t)s * HID + f0);
            float wgt = s_w[wid][myh][e];
            union { unsigned u; float f; } a0, a1, a2, a3;
            a0.u = zv.x << 16; a1.u = zv.x & 0xffff0000u;
            a2.u = zv.y << 16; a3.u = zv.y & 0xffff0000u;
            acc.x = fmaf(wgt, a0.f, acc.x);
            acc.y = fmaf(wgt, a1.f, acc.y);
            acc.z = fmaf(wgt, a2.f, acc.z);
            acc.w = fmaf(wgt, a3.f, acc.w);
        }
        __builtin_amdgcn_wave_barrier();
    }
    // reduce per-head denominators across the wave
#pragma unroll
    for (int h = 0; h < NH; h++)
#pragma unroll
        for (int off = 32; off; off >>= 1) wsum[h] += __shfl_xor(wsum[h], off);
    float inv = (wsum[myh] > 0.f) ? 1.f / wsum[myh] : 0.f;
    float4 b4 = *(const float4*)(bias + f0);
    float4 o;
    o.x = acc.x * inv + b4.x;
    o.y = acc.y * inv + b4.y;
    o.z = acc.z * inv + b4.z;
    o.w = acc.w * inv + b4.w;
    *(float4*)(out + (size_t)node * HID + f0) = o;
}

// ------------------------- MFMA head: logits + log_softmax ---------------
__global__ __launch_bounds__(256) void head_kernel(
    const unsigned short* __restrict__ Ah, const unsigned short* __restrict__ Al,
    const unsigned short* __restrict__ Bh_g, const unsigned short* __restrict__ Bl_g,
    const float* __restrict__ b2, float* __restrict__ out, int M) {
    __shared__ short sAh[2048], sAl[2048];    // 64x32
    __shared__ short sBh[16384], sBl[16384];  // 256x64 (all k)
    int tid = threadIdx.x;
    int lane = tid & 63;
    int wid = tid >> 6;
    int m0 = blockIdx.x * 64;

    // stage all of W2 (pre-permuted) once
#pragma unroll
    for (int p = 0; p < 8; p++) {
        ((short8*)sBh)[tid + p * 256] = ((const short8*)Bh_g)[tid + p * 256];
        ((short8*)sBl)[tid + p * 256] = ((const short8*)Bl_g)[tid + p * 256];
    }

    f32x4 acc[4];
#pragma unroll
    for (int nf = 0; nf < 4; nf++) acc[nf] = (f32x4){0.f, 0.f, 0.f, 0.f};

    for (int kt = 0; kt < 8; kt++) {
        {
            int r = tid >> 2, kq = tid & 3;
            int gr = m0 + r;
            short8 h8 = zero8(), l8 = zero8();
            if (gr < M) {
                size_t gb = (size_t)gr * HID + kt * 32 + kq * 8;
                h8 = *(const short8*)(Ah + gb);
                l8 = *(const short8*)(Al + gb);
            }
            int off = (r >> 4) * 512 + kq * 128 + (r & 15) * 8;
            *(short8*)&sAh[off] = h8;
            *(short8*)&sAl[off] = l8;
        }
        __syncthreads();
        short8 ah = *(const short8*)&sAh[wid * 512 + lane * 8];
        short8 am = *(const short8*)&sAl[wid * 512 + lane * 8];
#pragma unroll
        for (int nf = 0; nf < 4; nf++) {
            short8 bh = *(const short8*)&sBh[kt * 2048 + nf * 512 + lane * 8];
            short8 bl = *(const short8*)&sBl[kt * 2048 + nf * 512 + lane * 8];
            acc[nf] = __builtin_amdgcn_mfma_f32_16x16x32_bf16(ah, bh, acc[nf], 0, 0, 0);
            acc[nf] = __builtin_amdgcn_mfma_f32_16x16x32_bf16(ah, bl, acc[nf], 0, 0, 0);
            acc[nf] = __builtin_amdgcn_mfma_f32_16x16x32_bf16(am, bh, acc[nf], 0, 0, 0);
        }
        __syncthreads();
    }

    // fused log-softmax over 47 valid cols; row = m0+wid*16+(lane>>4)*4+reg
    int col0 = lane & 15;
    float bias_[4];
#pragma unroll
    for (int nf = 0; nf < 4; nf++) {
        int col = nf * 16 + col0;
        bias_[nf] = (col < 47) ? b2[col] : 0.f;
    }
#pragma unroll
    for (int reg = 0; reg < 4; reg++) {
        int row = m0 + wid * 16 + (lane >> 4) * 4 + reg;
        float lg[4];
        float mx = -INFINITY;
#pragma unroll
        for (int nf = 0; nf < 4; nf++) {
            int col = nf * 16 + col0;
            float v = acc[nf][reg] + bias_[nf];
            lg[nf] = v;
            if (col < 47) mx = fmaxf(mx, v);
        }
#pragma unroll
        for (int off = 8; off; off >>= 1) mx = fmaxf(mx, __shfl_xor(mx, off));
        float s = 0.f;
#pragma unroll
        for (int nf = 0; nf < 4; nf++) {
            int col = nf * 16 + col0;
            if (col < 47) s += __expf(lg[nf] - mx);
        }
#pragma unroll
        for (int off = 8; off; off >>= 1) s += __shfl_xor(s, off);
        float li = logf(s);
        if (row < M) {
#pragma unroll
            for (int nf = 0; nf < 3; nf++) {
                int col = nf * 16 + col0;
                if (col < 47) out[(size_t)row * 47 + col] = lg[nf] - mx - li;
            }
        }
    }
}

// ------------------------- launch -------------------------
extern "C" void kernel_launch(void* const* d_in, const int* in_sizes, int n_in,
                              void* d_out, int out_size, void* d_ws, size_t ws_size,
                              hipStream_t stream) {
    const float* x        = (const float*)d_in[0];
    const float* conv0_W  = (const float*)d_in[1];
    const float* conv0_al = (const float*)d_in[2];
    const float* conv0_ar = (const float*)d_in[3];
    const float* conv0_b  = (const float*)d_in[4];
    const float* skip0_W  = (const float*)d_in[5];
    const float* skip0_b  = (const float*)d_in[6];
    const float* conv1_W  = (const float*)d_in[7];
    const float* conv1_al = (const float*)d_in[8];
    const float* conv1_ar = (const float*)d_in[9];
    const float* conv1_b  = (const float*)d_in[10];
    const float* skip1_W  = (const float*)d_in[11];
    const float* skip1_b  = (const float*)d_in[12];
    const float* mlp_W1   = (const float*)d_in[13];
    const float* mlp_b1   = (const float*)d_in[14];
    const float* bn_gamma = (const float*)d_in[15];
    const float* bn_beta  = (const float*)d_in[16];
    const float* bn_mean  = (const float*)d_in[17];
    const float* bn_var   = (const float*)d_in[18];
    const float* mlp_W2   = (const float*)d_in[19];
    const float* mlp_b2   = (const float*)d_in[20];
    const int* edge_src   = (const int*)d_in[21];
    const int* edge_dst   = (const int*)d_in[22];
    float* out = (float*)d_out;

    // workspace carve-up (with aliasing)
    char* w = (char*)d_ws;
    size_t off = 0;
    auto alloc = [&](size_t bytes) {
        char* p = w + off;
        off += (bytes + 255) & ~(size_t)255;
        return p;
    };
    int*    row_ptr = (int*)alloc((NN + 1) * sizeof(int));
    int*    cursor  = (int*)alloc(NN * sizeof(int));
    int*    bsum    = (int*)alloc(512 * sizeof(int));
    int*    csr_src = (int*)alloc(NE * sizeof(int));
    float*  el      = (float*)alloc((size_t)NN * 4 * sizeof(float));
    float*  er      = (float*)alloc((size_t)NN * 4 * sizeof(float));
    float*  aggbuf  = (float*)alloc((size_t)NN * HID * sizeof(float));          // also ml
    unsigned short* zb   = (unsigned short*)alloc((size_t)NN * HID * 2);        // also mh
    unsigned short* slA  = (unsigned short*)alloc((size_t)NN * HID * 2);        // xh then h2h
    unsigned short* slB  = (unsigned short*)alloc((size_t)NN * HID * 2);        // xl then h2l
    unsigned short* hh   = (unsigned short*)alloc((size_t)NN * HID * 2);
    unsigned short* hl   = (unsigned short*)alloc((size_t)NN * HID * 2);
    unsigned short* c0h = (unsigned short*)alloc(128 * 256 * 2);
    unsigned short* c0l = (unsigned short*)alloc(128 * 256 * 2);
    unsigned short* s0h = (unsigned short*)alloc(128 * 256 * 2);
    unsigned short* s0l = (unsigned short*)alloc(128 * 256 * 2);
    unsigned short* c1h = (unsigned short*)alloc(256 * 256 * 2);
    unsigned short* c1l = (unsigned short*)alloc(256 * 256 * 2);
    unsigned short* s1h = (unsigned short*)alloc(256 * 256 * 2);
    unsigned short* s1l = (unsigned short*)alloc(256 * 256 * 2);
    unsigned short* m1h = (unsigned short*)alloc(256 * 256 * 2);
    unsigned short* m1l = (unsigned short*)alloc(256 * 256 * 2);
    unsigned short* hWh = (unsigned short*)alloc(256 * 64 * 2);
    unsigned short* hWl = (unsigned short*)alloc(256 * 64 * 2);
    (void)ws_size;

    unsigned short* xh = slA;   // 50000x128 (uses half the slab)
    unsigned short* xl = slB;
    unsigned short* h2h = slA;  // alive after x is dead
    unsigned short* h2l = slB;
    unsigned short* mh = zb;    // alive after zb is dead
    unsigned short* ml = (unsigned short*)aggbuf;

    int gemm_grid = cdiv(NN, 64);
    int nodeblocks = cdiv(NN, 4);
    int scan_blocks = cdiv(NN, 256);   // 196

    // weight pre-split + x pre-split
    wcast_all_kernel<<<cdiv(278528, 256), 256, 0, stream>>>(
        conv0_W, skip0_W, conv1_W, skip1_W, mlp_W1, mlp_W2,
        c0h, c0l, s0h, s0l, c1h, c1l, s1h, s1l, m1h, m1l, hWh, hWl);
    acast_kernel<<<cdiv(NN * 128 / 4, 256), 256, 0, stream>>>(x, xh, xl, NN * 128 / 4);

    // CSR build (shared by both layers) — parallel two-level scan
    hipMemsetAsync(cursor, 0, NN * sizeof(int), stream);
    hist_kernel<<<cdiv(NE, 256), 256, 0, stream>>>(edge_dst, cursor, NE);
    scan1_kernel<<<scan_blocks, 256, 0, stream>>>(cursor, row_ptr, bsum, NN);
    scan2_kernel<<<1, 256, 0, stream>>>(bsum, scan_blocks);
    scan3_kernel<<<scan_blocks, 256, 0, stream>>>(bsum, row_ptr, cursor, NN, scan_blocks);
    scatter_kernel<<<cdiv(NE, 256), 256, 0, stream>>>(edge_src, edge_dst, cursor, csr_src, NE);

    // layer 0
    gemm_kernel<3><<<gemm_grid, 256, 0, stream>>>(xh, xl, c0h, c0l, NN, 128,
        nullptr, nullptr, nullptr, nullptr, nullptr, nullptr, nullptr, nullptr,
        zb, conv0_al, conv0_ar, el, er);
    aggregate_kernel<<<nodeblocks, 256, 0, stream>>>(row_ptr, csr_src, (const float4*)el, (const float4*)er,
                                                     zb, conv0_b, aggbuf, NN);
    gemm_kernel<1><<<gemm_grid, 256, 0, stream>>>(xh, xl, s0h, s0l, NN, 128,
        hh, hl, aggbuf, skip0_b, nullptr, nullptr, nullptr, nullptr,
        nullptr, nullptr, nullptr, nullptr, nullptr);

    // layer 1
    gemm_kernel<3><<<gemm_grid, 256, 0, stream>>>(hh, hl, c1h, c1l, NN, 256,
        nullptr, nullptr, nullptr, nullptr, nullptr, nullptr, nullptr, nullptr,
        zb, conv1_al, conv1_ar, el, er);
    aggregate_kernel<<<nodeblocks, 256, 0, stream>>>(row_ptr, csr_src, (const float4*)el, (const float4*)er,
                                                     zb, conv1_b, aggbuf, NN);
    gemm_kernel<1><<<gemm_grid, 256, 0, stream>>>(hh, hl, s1h, s1l, NN, 256,
        h2h, h2l, aggbuf, skip1_b, nullptr, nullptr, nullptr, nullptr,
        nullptr, nullptr, nullptr, nullptr, nullptr);

    // MLP head: m = relu(bn(h2 @ W1 + b1));  (mh/ml alias zb/aggbuf, both dead now)
    gemm_kernel<2><<<gemm_grid, 256, 0, stream>>>(h2h, h2l, m1h, m1l, NN, 256,
        mh, ml, nullptr, mlp_b1, bn_gamma, bn_beta, bn_mean, bn_var,
        nullptr, nullptr, nullptr, nullptr, nullptr);
    head_kernel<<<gemm_grid, 256, 0, stream>>>(mh, ml, hWh, hWl, mlp_b2, out, NN);
}

// Round 6
// 440.804 us; speedup vs baseline: 2.4283x; 1.1119x over previous
//
#include <hip/hip_runtime.h>
#include <math.h>

#define NN 50000
#define NE 800000
#define HID 256
#define NH 4
#define DH 64

static inline int cdiv(int a, int b) { return (a + b - 1) / b; }

typedef __attribute__((ext_vector_type(8))) short short8;
typedef __attribute__((ext_vector_type(4))) short short4v;
typedef __attribute__((ext_vector_type(4))) float f32x4;

// bf16 helpers (round-to-nearest-even)
__device__ inline unsigned short f2bf(float x) {
    union { float f; unsigned u; } v; v.f = x;
    unsigned r = v.u + 0x7FFFu + ((v.u >> 16) & 1u);
    return (unsigned short)(r >> 16);
}
__device__ inline float bf2f(unsigned short h) {
    union { unsigned u; float f; } v; v.u = ((unsigned)h) << 16;
    return v.f;
}
__device__ inline short8 zero8() {
    short8 z;
#pragma unroll
    for (int j = 0; j < 8; j++) z[j] = 0;
    return z;
}

// ------------------------- CSR build -------------------------
__global__ void hist_kernel(const int* __restrict__ dst, int* __restrict__ deg, int e) {
    int i = blockIdx.x * blockDim.x + threadIdx.x;
    if (i < e) atomicAdd(&deg[dst[i]], 1);
}

// two-level parallel exclusive scan over deg[n]
__global__ void scan1_kernel(const int* __restrict__ deg, int* __restrict__ local,
                             int* __restrict__ bsum, int n) {
    __shared__ int s[256];
    int tid = threadIdx.x;
    int i = blockIdx.x * 256 + tid;
    int v = (i < n) ? deg[i] : 0;
    s[tid] = v;
    __syncthreads();
    for (int off = 1; off < 256; off <<= 1) {
        int t = (tid >= off) ? s[tid - off] : 0;
        __syncthreads();
        s[tid] += t;
        __syncthreads();
    }
    if (i < n) local[i] = s[tid] - v;      // exclusive within block
    if (tid == 255) bsum[blockIdx.x] = s[255];
}

__global__ void scan2_kernel(int* __restrict__ bsum, int nb) {
    __shared__ int s[256];
    int tid = threadIdx.x;
    int v = (tid < nb) ? bsum[tid] : 0;
    s[tid] = v;
    __syncthreads();
    for (int off = 1; off < 256; off <<= 1) {
        int t = (tid >= off) ? s[tid - off] : 0;
        __syncthreads();
        s[tid] += t;
        __syncthreads();
    }
    if (tid < nb) bsum[tid] = s[tid] - v;  // exclusive
    if (tid == 255) bsum[nb] = s[255];     // total
}

__global__ void scan3_kernel(const int* __restrict__ bsum, int* __restrict__ row_ptr,
                             int* __restrict__ cursor, int n, int nb) {
    int i = blockIdx.x * 256 + threadIdx.x;
    if (i < n) {
        int r = row_ptr[i] + bsum[blockIdx.x];
        row_ptr[i] = r;
        cursor[i] = r;
    }
    if (i == 0) row_ptr[n] = bsum[nb];
}

__global__ void scatter_kernel(const int* __restrict__ src, const int* __restrict__ dst,
                               int* __restrict__ cursor, int* __restrict__ csr_src, int e) {
    int i = blockIdx.x * blockDim.x + threadIdx.x;
    if (i < e) {
        int p = atomicAdd(&cursor[dst[i]], 1);
        csr_src[p] = src[i];
    }
}

// ------------------------- weight pre-split (hi/lo bf16, permuted) ------
// 256-col: off = (k>>5)*8192 + (n>>4)*512 + ((k>>3)&3)*128 + (n&15)*8 + (k&7)
// head (64-col padded from 47): off = (k>>5)*2048 + same inner
__global__ void wcast_all_kernel(
    const float* __restrict__ c0W, const float* __restrict__ s0W,
    const float* __restrict__ c1W, const float* __restrict__ s1W,
    const float* __restrict__ m1W, const float* __restrict__ W2,
    unsigned short* __restrict__ c0h, unsigned short* __restrict__ c0l,
    unsigned short* __restrict__ s0h, unsigned short* __restrict__ s0l,
    unsigned short* __restrict__ c1h, unsigned short* __restrict__ c1l,
    unsigned short* __restrict__ s1h, unsigned short* __restrict__ s1l,
    unsigned short* __restrict__ m1h, unsigned short* __restrict__ m1l,
    unsigned short* __restrict__ hWh, unsigned short* __restrict__ hWl) {
    int i = blockIdx.x * blockDim.x + threadIdx.x;
    const float* W; unsigned short *H, *L; int base; int head = 0;
    if (i < 32768)        { W = c0W; H = c0h; L = c0l; base = i; }
    else if (i < 65536)   { W = s0W; H = s0h; L = s0l; base = i - 32768; }
    else if (i < 131072)  { W = c1W; H = c1h; L = c1l; base = i - 65536; }
    else if (i < 196608)  { W = s1W; H = s1h; L = s1l; base = i - 131072; }
    else if (i < 262144)  { W = m1W; H = m1h; L = m1l; base = i - 196608; }
    else if (i < 278528)  { W = W2;  H = hWh; L = hWl; base = i - 262144; head = 1; }
    else return;
    float x; int off;
    if (!head) {
        int k = base >> 8, n = base & 255;
        x = W[base];
        off = (k >> 5) * 8192 + (n >> 4) * 512 + ((k >> 3) & 3) * 128 + (n & 15) * 8 + (k & 7);
    } else {
        int k = base >> 6, n = base & 63;
        x = (n < 47) ? W[k * 47 + n] : 0.f;
        off = (k >> 5) * 2048 + (n >> 4) * 512 + ((k >> 3) & 3) * 128 + (n & 15) * 8 + (k & 7);
    }
    unsigned short h = f2bf(x);
    unsigned short l = f2bf(x - bf2f(h));
    H[off] = h;
    L[off] = l;
}

// ------------------------- x pre-split (row-major hi/lo bf16) ------------
__global__ void acast_kernel(const float* __restrict__ in,
                             unsigned short* __restrict__ H,
                             unsigned short* __restrict__ L, int n4) {
    int i = blockIdx.x * blockDim.x + threadIdx.x;
    if (i >= n4) return;
    float4 v = ((const float4*)in)[i];
    float f[4] = {v.x, v.y, v.z, v.w};
    short4v h, l;
#pragma unroll
    for (int j = 0; j < 4; j++) {
        unsigned short hh = f2bf(f[j]);
        h[j] = (short)hh;
        l[j] = (short)f2bf(f[j] - bf2f(hh));
    }
    *(short4v*)&H[i * 4] = h;
    *(short4v*)&L[i * 4] = l;
}

// ------------------------- MFMA GEMM (bf16x3, B direct from L2) ----------
// C[M,256] = A[M,K] @ W[K,256].  Tile 32 x 256, 256 threads (4 waves),
// wave wid owns 32 rows x cols [wid*64, wid*64+64) (2x4 frags of 16x16x32).
// A: LDS double-buffered (8 KB total), reg-staged prefetch, 1 barrier/K-step.
// B: per-lane direct global loads of the pre-permuted fragments (L2-resident).
// EPI 1: elu(acc+add+bias) -> Ch/Cl ; EPI 2: relu(bn(acc+bias)) -> Ch/Cl
// EPI 3: zb bf16 store + fused attn scores el/er
template <int EPI>
__global__ __launch_bounds__(256) void gemm_kernel(
    const unsigned short* __restrict__ Ah, const unsigned short* __restrict__ Al,
    const unsigned short* __restrict__ Bh_g, const unsigned short* __restrict__ Bl_g,
    int M, int K,
    unsigned short* __restrict__ Ch, unsigned short* __restrict__ Cl,
    const float* __restrict__ add, const float* __restrict__ bias,
    const float* __restrict__ g, const float* __restrict__ bt,
    const float* __restrict__ mean, const float* __restrict__ var,
    unsigned short* __restrict__ zb,
    const float* __restrict__ al, const float* __restrict__ ar,
    float* __restrict__ el, float* __restrict__ er) {
    __shared__ short sAh[2][1024], sAl[2][1024];   // 32x32 bf16 hi/lo, frag-ordered, dbuf

    int tid = threadIdx.x;
    int lane = tid & 63;
    int wid = tid >> 6;
    int m0 = blockIdx.x * 32;

    f32x4 acc[2][4];
#pragma unroll
    for (int i = 0; i < 2; i++)
#pragma unroll
        for (int j = 0; j < 4; j++) acc[i][j] = (f32x4){0.f, 0.f, 0.f, 0.f};

    // A stage mapping: threads 0..127 stage hi, 128..255 stage lo
    int half = tid >> 7;
    int t7 = tid & 127;
    int r = t7 >> 2, kq = t7 & 3;
    int gr = m0 + r;
    const unsigned short* Asrc = half ? Al : Ah;
    size_t abase = (size_t)gr * K + kq * 8;
    int aoff = (r >> 4) * 512 + kq * 128 + (r & 15) * 8;
    short* d0 = half ? &sAl[0][0] : &sAh[0][0];
    short* d1 = half ? &sAl[1][0] : &sAh[1][0];

    int nkt = K >> 5;
    // preload K-step 0
    {
        short8 sreg = zero8();
        if (gr < M) sreg = *(const short8*)(Asrc + abase);
        *(short8*)(d0 + aoff) = sreg;
    }
    __syncthreads();

    const unsigned short* bhp = Bh_g + (wid * 4) * 512 + lane * 8;
    const unsigned short* blp = Bl_g + (wid * 4) * 512 + lane * 8;

    for (int kt = 0; kt < nkt; kt++) {
        // prefetch next A chunk into regs (hides HBM latency under MFMA)
        short8 nreg = zero8();
        if (kt + 1 < nkt && gr < M)
            nreg = *(const short8*)(Asrc + abase + (size_t)(kt + 1) * 32);
        // B fragments direct from global (L2-hit; same addrs for all blocks)
        short8 bh[4], bl[4];
#pragma unroll
        for (int nf = 0; nf < 4; nf++) {
            bh[nf] = *(const short8*)(bhp + kt * 8192 + nf * 512);
            bl[nf] = *(const short8*)(blp + kt * 8192 + nf * 512);
        }
        const short* curh = (kt & 1) ? &sAh[1][0] : &sAh[0][0];
        const short* curl = (kt & 1) ? &sAl[1][0] : &sAl[0][0];
        short8 ah[2], am[2];
#pragma unroll
        for (int mf = 0; mf < 2; mf++) {
            ah[mf] = *(const short8*)(curh + mf * 512 + lane * 8);
            am[mf] = *(const short8*)(curl + mf * 512 + lane * 8);
        }
#pragma unroll
        for (int nf = 0; nf < 4; nf++)
#pragma unroll
            for (int mf = 0; mf < 2; mf++) {
                acc[mf][nf] = __builtin_amdgcn_mfma_f32_16x16x32_bf16(ah[mf], bh[nf], acc[mf][nf], 0, 0, 0);
                acc[mf][nf] = __builtin_amdgcn_mfma_f32_16x16x32_bf16(ah[mf], bl[nf], acc[mf][nf], 0, 0, 0);
                acc[mf][nf] = __builtin_amdgcn_mfma_f32_16x16x32_bf16(am[mf], bh[nf], acc[mf][nf], 0, 0, 0);
            }
        if (kt + 1 < nkt) {
            short* nxt = ((kt + 1) & 1) ? d1 : d0;
            *(short8*)(nxt + aoff) = nreg;
        }
        __syncthreads();
    }

    // ---- epilogue: C layout col=lane&15, row=(lane>>4)*4+reg ----
#pragma unroll
    for (int mf = 0; mf < 2; mf++) {
        int row0 = m0 + mf * 16 + (lane >> 4) * 4;
#pragma unroll
        for (int reg = 0; reg < 4; reg++) {
            int row = row0 + reg;
            if (row >= M) continue;
            size_t rb = (size_t)row * HID;
#pragma unroll
            for (int nf = 0; nf < 4; nf++) {
                int col = wid * 64 + nf * 16 + (lane & 15);
                float v = acc[mf][nf][reg];
                if (EPI == 3) {
                    zb[rb + col] = f2bf(v);
                } else if (EPI == 1) {
                    v += add[rb + col] + bias[col];
                    v = (v > 0.f) ? v : expm1f(v);
                    unsigned short hh = f2bf(v);
                    Ch[rb + col] = hh;
                    Cl[rb + col] = f2bf(v - bf2f(hh));
                } else {
                    float s = g[col] * rsqrtf(var[col] + 1e-5f);
                    v = (v + bias[col] - mean[col]) * s + bt[col];
                    v = fmaxf(v, 0.f);
                    unsigned short hh = f2bf(v);
                    Ch[rb + col] = hh;
                    Cl[rb + col] = f2bf(v - bf2f(hh));
                }
            }
        }
    }

    // ---- fused attention scores (EPI==3): wave wid == head wid ----
    if (EPI == 3) {
        float alv[4], arv[4];
#pragma unroll
        for (int nf = 0; nf < 4; nf++) {
            int col = wid * 64 + nf * 16 + (lane & 15);
            alv[nf] = al[col];
            arv[nf] = ar[col];
        }
#pragma unroll
        for (int mf = 0; mf < 2; mf++) {
#pragma unroll
            for (int reg = 0; reg < 4; reg++) {
                float pl = 0.f, pr = 0.f;
#pragma unroll
                for (int nf = 0; nf < 4; nf++) {
                    pl = fmaf(acc[mf][nf][reg], alv[nf], pl);
                    pr = fmaf(acc[mf][nf][reg], arv[nf], pr);
                }
#pragma unroll
                for (int off = 8; off; off >>= 1) {
                    pl += __shfl_xor(pl, off);
                    pr += __shfl_xor(pr, off);
                }
                int row = m0 + mf * 16 + (lane >> 4) * 4 + reg;
                if ((lane & 15) == 0 && row < M) {
                    el[row * 4 + wid] = pl;
                    er[row * 4 + wid] = pr;
                }
            }
        }
    }
}

// ------------------------- GAT aggregate (single pass, bf16 z) ----------
// one wave per dst node; lane owns features [lane*4, lane*4+4) (head = lane>>4)
__global__ __launch_bounds__(256) void aggregate_kernel(
    const int* __restrict__ row_ptr, const int* __restrict__ csr_src,
    const float4* __restrict__ el4, const float4* __restrict__ er4,
    const unsigned short* __restrict__ zb, const float* __restrict__ bias,
    float* __restrict__ out, int n) {
    __shared__ float s_w[4][NH][64];
    __shared__ int s_s[4][64];
    int wid = threadIdx.x >> 6;
    int lane = threadIdx.x & 63;
    int node = blockIdx.x * 4 + wid;
    if (node >= n) return;
    int rb = row_ptr[node];
    int deg = row_ptr[node + 1] - rb;
    float4 ern = er4[node];
    float er_h[NH] = {ern.x, ern.y, ern.z, ern.w};
    int myh = lane >> 4;
    int f0 = lane * 4;

    float4 acc = make_float4(0.f, 0.f, 0.f, 0.f);
    float wsum[NH] = {0.f, 0.f, 0.f, 0.f};

    for (int c = 0; c < deg; c += 64) {
        int i = c + lane;
        int cnt = min(64, deg - c);
        if (i < deg) {
            int s = csr_src[rb + i];
            s_s[wid][lane] = s;
            float4 elv = el4[s];
            float ev[NH] = {elv.x, elv.y, elv.z, elv.w};
#pragma unroll
            for (int h = 0; h < NH; h++) {
                float e = ev[h] + er_h[h];
                e = (e > 0.f) ? e : 0.2f * e;
                float ee = __expf(e);
                s_w[wid][h][lane] = ee;
                wsum[h] += ee;
            }
        }
        __builtin_amdgcn_wave_barrier();
#pragma unroll 2
        for (int e = 0; e < cnt; e++) {
            int s = s_s[wid][e];
            uint2 zv = *(const uint2*)(zb + (size_t)s * HID + f0);
            float wgt = s_w[wid][myh][e];
            union { unsigned u; float f; } a0, a1, a2, a3;
            a0.u = zv.x << 16; a1.u = zv.x & 0xffff0000u;
            a2.u = zv.y << 16; a3.u = zv.y & 0xffff0000u;
            acc.x = fmaf(wgt, a0.f, acc.x);
            acc.y = fmaf(wgt, a1.f, acc.y);
            acc.z = fmaf(wgt, a2.f, acc.z);
            acc.w = fmaf(wgt, a3.f, acc.w);
        }
        __builtin_amdgcn_wave_barrier();
    }
    // reduce per-head denominators across the wave
#pragma unroll
    for (int h = 0; h < NH; h++)
#pragma unroll
        for (int off = 32; off; off >>= 1) wsum[h] += __shfl_xor(wsum[h], off);
    float inv = (wsum[myh] > 0.f) ? 1.f / wsum[myh] : 0.f;
    float4 b4 = *(const float4*)(bias + f0);
    float4 o;
    o.x = acc.x * inv + b4.x;
    o.y = acc.y * inv + b4.y;
    o.z = acc.z * inv + b4.z;
    o.w = acc.w * inv + b4.w;
    *(float4*)(out + (size_t)node * HID + f0) = o;
}

// ------------------------- MFMA head: logits + log_softmax ---------------
// Tile 64 rows, K=256; wave w = rows [w*16,w*16+16) x all 64 cols.
// B direct from global (L2-resident, 32 KB total).
__global__ __launch_bounds__(256) void head_kernel(
    const unsigned short* __restrict__ Ah, const unsigned short* __restrict__ Al,
    const unsigned short* __restrict__ Bh_g, const unsigned short* __restrict__ Bl_g,
    const float* __restrict__ b2, float* __restrict__ out, int M) {
    __shared__ short sAh[2048], sAl[2048];    // 64x32
    int tid = threadIdx.x;
    int lane = tid & 63;
    int wid = tid >> 6;
    int m0 = blockIdx.x * 64;

    f32x4 acc[4];
#pragma unroll
    for (int nf = 0; nf < 4; nf++) acc[nf] = (f32x4){0.f, 0.f, 0.f, 0.f};

    for (int kt = 0; kt < 8; kt++) {
        {
            int r = tid >> 2, kq = tid & 3;
            int gr = m0 + r;
            short8 h8 = zero8(), l8 = zero8();
            if (gr < M) {
                size_t gb = (size_t)gr * HID + kt * 32 + kq * 8;
                h8 = *(const short8*)(Ah + gb);
                l8 = *(const short8*)(Al + gb);
            }
            int off = (r >> 4) * 512 + kq * 128 + (r & 15) * 8;
            *(short8*)&sAh[off] = h8;
            *(short8*)&sAl[off] = l8;
        }
        __syncthreads();
        short8 ah = *(const short8*)&sAh[wid * 512 + lane * 8];
        short8 am = *(const short8*)&sAl[wid * 512 + lane * 8];
#pragma unroll
        for (int nf = 0; nf < 4; nf++) {
            short8 bh = *(const short8*)(Bh_g + kt * 2048 + nf * 512 + lane * 8);
            short8 bl = *(const short8*)(Bl_g + kt * 2048 + nf * 512 + lane * 8);
            acc[nf] = __builtin_amdgcn_mfma_f32_16x16x32_bf16(ah, bh, acc[nf], 0, 0, 0);
            acc[nf] = __builtin_amdgcn_mfma_f32_16x16x32_bf16(ah, bl, acc[nf], 0, 0, 0);
            acc[nf] = __builtin_amdgcn_mfma_f32_16x16x32_bf16(am, bh, acc[nf], 0, 0, 0);
        }
        __syncthreads();
    }

    // fused log-softmax over 47 valid cols; row = m0+wid*16+(lane>>4)*4+reg
    int col0 = lane & 15;
    float bias_[4];
#pragma unroll
    for (int nf = 0; nf < 4; nf++) {
        int col = nf * 16 + col0;
        bias_[nf] = (col < 47) ? b2[col] : 0.f;
    }
#pragma unroll
    for (int reg = 0; reg < 4; reg++) {
        int row = m0 + wid * 16 + (lane >> 4) * 4 + reg;
        float lg[4];
        float mx = -INFINITY;
#pragma unroll
        for (int nf = 0; nf < 4; nf++) {
            int col = nf * 16 + col0;
            float v = acc[nf][reg] + bias_[nf];
            lg[nf] = v;
            if (col < 47) mx = fmaxf(mx, v);
        }
#pragma unroll
        for (int off = 8; off; off >>= 1) mx = fmaxf(mx, __shfl_xor(mx, off));
        float s = 0.f;
#pragma unroll
        for (int nf = 0; nf < 4; nf++) {
            int col = nf * 16 + col0;
            if (col < 47) s += __expf(lg[nf] - mx);
        }
#pragma unroll
        for (int off = 8; off; off >>= 1) s += __shfl_xor(s, off);
        float li = logf(s);
        if (row < M) {
#pragma unroll
            for (int nf = 0; nf < 3; nf++) {
                int col = nf * 16 + col0;
                if (col < 47) out[(size_t)row * 47 + col] = lg[nf] - mx - li;
            }
        }
    }
}

// ------------------------- launch -------------------------
extern "C" void kernel_launch(void* const* d_in, const int* in_sizes, int n_in,
                              void* d_out, int out_size, void* d_ws, size_t ws_size,
                              hipStream_t stream) {
    const float* x        = (const float*)d_in[0];
    const float* conv0_W  = (const float*)d_in[1];
    const float* conv0_al = (const float*)d_in[2];
    const float* conv0_ar = (const float*)d_in[3];
    const float* conv0_b  = (const float*)d_in[4];
    const float* skip0_W  = (const float*)d_in[5];
    const float* skip0_b  = (const float*)d_in[6];
    const float* conv1_W  = (const float*)d_in[7];
    const float* conv1_al = (const float*)d_in[8];
    const float* conv1_ar = (const float*)d_in[9];
    const float* conv1_b  = (const float*)d_in[10];
    const float* skip1_W  = (const float*)d_in[11];
    const float* skip1_b  = (const float*)d_in[12];
    const float* mlp_W1   = (const float*)d_in[13];
    const float* mlp_b1   = (const float*)d_in[14];
    const float* bn_gamma = (const float*)d_in[15];
    const float* bn_beta  = (const float*)d_in[16];
    const float* bn_mean  = (const float*)d_in[17];
    const float* bn_var   = (const float*)d_in[18];
    const float* mlp_W2   = (const float*)d_in[19];
    const float* mlp_b2   = (const float*)d_in[20];
    const int* edge_src   = (const int*)d_in[21];
    const int* edge_dst   = (const int*)d_in[22];
    float* out = (float*)d_out;

    // workspace carve-up (with aliasing)
    char* w = (char*)d_ws;
    size_t off = 0;
    auto alloc = [&](size_t bytes) {
        char* p = w + off;
        off += (bytes + 255) & ~(size_t)255;
        return p;
    };
    int*    row_ptr = (int*)alloc((NN + 1) * sizeof(int));
    int*    cursor  = (int*)alloc(NN * sizeof(int));
    int*    bsum    = (int*)alloc(512 * sizeof(int));
    int*    csr_src = (int*)alloc(NE * sizeof(int));
    float*  el      = (float*)alloc((size_t)NN * 4 * sizeof(float));
    float*  er      = (float*)alloc((size_t)NN * 4 * sizeof(float));
    float*  aggbuf  = (float*)alloc((size_t)NN * HID * sizeof(float));          // also ml
    unsigned short* zb   = (unsigned short*)alloc((size_t)NN * HID * 2);        // also mh
    unsigned short* slA  = (unsigned short*)alloc((size_t)NN * HID * 2);        // xh then h2h
    unsigned short* slB  = (unsigned short*)alloc((size_t)NN * HID * 2);        // xl then h2l
    unsigned short* hh   = (unsigned short*)alloc((size_t)NN * HID * 2);
    unsigned short* hl   = (unsigned short*)alloc((size_t)NN * HID * 2);
    unsigned short* c0h = (unsigned short*)alloc(128 * 256 * 2);
    unsigned short* c0l = (unsigned short*)alloc(128 * 256 * 2);
    unsigned short* s0h = (unsigned short*)alloc(128 * 256 * 2);
    unsigned short* s0l = (unsigned short*)alloc(128 * 256 * 2);
    unsigned short* c1h = (unsigned short*)alloc(256 * 256 * 2);
    unsigned short* c1l = (unsigned short*)alloc(256 * 256 * 2);
    unsigned short* s1h = (unsigned short*)alloc(256 * 256 * 2);
    unsigned short* s1l = (unsigned short*)alloc(256 * 256 * 2);
    unsigned short* m1h = (unsigned short*)alloc(256 * 256 * 2);
    unsigned short* m1l = (unsigned short*)alloc(256 * 256 * 2);
    unsigned short* hWh = (unsigned short*)alloc(256 * 64 * 2);
    unsigned short* hWl = (unsigned short*)alloc(256 * 64 * 2);
    (void)ws_size;

    unsigned short* xh = slA;   // 50000x128 (uses half the slab)
    unsigned short* xl = slB;
    unsigned short* h2h = slA;  // alive after x is dead
    unsigned short* h2l = slB;
    unsigned short* mh = zb;    // alive after zb is dead
    unsigned short* ml = (unsigned short*)aggbuf;

    int gemm_grid = cdiv(NN, 32);      // 1563 blocks, 32-row tiles
    int head_grid = cdiv(NN, 64);
    int nodeblocks = cdiv(NN, 4);
    int scan_blocks = cdiv(NN, 256);

    // weight pre-split + x pre-split
    wcast_all_kernel<<<cdiv(278528, 256), 256, 0, stream>>>(
        conv0_W, skip0_W, conv1_W, skip1_W, mlp_W1, mlp_W2,
        c0h, c0l, s0h, s0l, c1h, c1l, s1h, s1l, m1h, m1l, hWh, hWl);
    acast_kernel<<<cdiv(NN * 128 / 4, 256), 256, 0, stream>>>(x, xh, xl, NN * 128 / 4);

    // CSR build (shared by both layers) — parallel two-level scan
    hipMemsetAsync(cursor, 0, NN * sizeof(int), stream);
    hist_kernel<<<cdiv(NE, 256), 256, 0, stream>>>(edge_dst, cursor, NE);
    scan1_kernel<<<scan_blocks, 256, 0, stream>>>(cursor, row_ptr, bsum, NN);
    scan2_kernel<<<1, 256, 0, stream>>>(bsum, scan_blocks);
    scan3_kernel<<<scan_blocks, 256, 0, stream>>>(bsum, row_ptr, cursor, NN, scan_blocks);
    scatter_kernel<<<cdiv(NE, 256), 256, 0, stream>>>(edge_src, edge_dst, cursor, csr_src, NE);

    // layer 0
    gemm_kernel<3><<<gemm_grid, 256, 0, stream>>>(xh, xl, c0h, c0l, NN, 128,
        nullptr, nullptr, nullptr, nullptr, nullptr, nullptr, nullptr, nullptr,
        zb, conv0_al, conv0_ar, el, er);
    aggregate_kernel<<<nodeblocks, 256, 0, stream>>>(row_ptr, csr_src, (const float4*)el, (const float4*)er,
                                                     zb, conv0_b, aggbuf, NN);
    gemm_kernel<1><<<gemm_grid, 256, 0, stream>>>(xh, xl, s0h, s0l, NN, 128,
        hh, hl, aggbuf, skip0_b, nullptr, nullptr, nullptr, nullptr,
        nullptr, nullptr, nullptr, nullptr, nullptr);

    // layer 1
    gemm_kernel<3><<<gemm_grid, 256, 0, stream>>>(hh, hl, c1h, c1l, NN, 256,
        nullptr, nullptr, nullptr, nullptr, nullptr, nullptr, nullptr, nullptr,
        zb, conv1_al, conv1_ar, el, er);
    aggregate_kernel<<<nodeblocks, 256, 0, stream>>>(row_ptr, csr_src, (const float4*)el, (const float4*)er,
                                                     zb, conv1_b, aggbuf, NN);
    gemm_kernel<1><<<gemm_grid, 256, 0, stream>>>(hh, hl, s1h, s1l, NN, 256,
        h2h, h2l, aggbuf, skip1_b, nullptr, nullptr, nullptr, nullptr,
        nullptr, nullptr, nullptr, nullptr, nullptr);

    // MLP head: m = relu(bn(h2 @ W1 + b1));  (mh/ml alias zb/aggbuf, both dead now)
    gemm_kernel<2><<<gemm_grid, 256, 0, stream>>>(h2h, h2l, m1h, m1l, NN, 256,
        mh, ml, nullptr, mlp_b1, bn_gamma, bn_beta, bn_mean, bn_var,
        nullptr, nullptr, nullptr, nullptr, nullptr);
    head_kernel<<<head_grid, 256, 0, stream>>>(mh, ml, hWh, hWl, mlp_b2, out, NN);
}

// Round 7
// 416.831 us; speedup vs baseline: 2.5680x; 1.0575x over previous
//
#include <hip/hip_runtime.h>
#include <math.h>

#define NN 50000
#define NE 800000
#define HID 256
#define NH 4
#define DH 64

static inline int cdiv(int a, int b) { return (a + b - 1) / b; }

typedef __attribute__((ext_vector_type(8))) short short8;
typedef __attribute__((ext_vector_type(4))) short short4v;
typedef __attribute__((ext_vector_type(4))) float f32x4;

// bf16 helpers (round-to-nearest-even)
__device__ inline unsigned short f2bf(float x) {
    union { float f; unsigned u; } v; v.f = x;
    unsigned r = v.u + 0x7FFFu + ((v.u >> 16) & 1u);
    return (unsigned short)(r >> 16);
}
__device__ inline float bf2f(unsigned short h) {
    union { unsigned u; float f; } v; v.u = ((unsigned)h) << 16;
    return v.f;
}
__device__ inline short8 zero8() {
    short8 z;
#pragma unroll
    for (int j = 0; j < 8; j++) z[j] = 0;
    return z;
}

// ------------------------- CSR build -------------------------
__global__ void hist_kernel(const int* __restrict__ dst, int* __restrict__ deg, int e) {
    int i = blockIdx.x * blockDim.x + threadIdx.x;
    if (i < e) atomicAdd(&deg[dst[i]], 1);
}

__global__ void scan1_kernel(const int* __restrict__ deg, int* __restrict__ local,
                             int* __restrict__ bsum, int n) {
    __shared__ int s[256];
    int tid = threadIdx.x;
    int i = blockIdx.x * 256 + tid;
    int v = (i < n) ? deg[i] : 0;
    s[tid] = v;
    __syncthreads();
    for (int off = 1; off < 256; off <<= 1) {
        int t = (tid >= off) ? s[tid - off] : 0;
        __syncthreads();
        s[tid] += t;
        __syncthreads();
    }
    if (i < n) local[i] = s[tid] - v;      // exclusive within block
    if (tid == 255) bsum[blockIdx.x] = s[255];
}

__global__ void scan2_kernel(int* __restrict__ bsum, int nb) {
    __shared__ int s[256];
    int tid = threadIdx.x;
    int v = (tid < nb) ? bsum[tid] : 0;
    s[tid] = v;
    __syncthreads();
    for (int off = 1; off < 256; off <<= 1) {
        int t = (tid >= off) ? s[tid - off] : 0;
        __syncthreads();
        s[tid] += t;
        __syncthreads();
    }
    if (tid < nb) bsum[tid] = s[tid] - v;  // exclusive
    if (tid == 255) bsum[nb] = s[255];     // total
}

__global__ void scan3_kernel(const int* __restrict__ bsum, int* __restrict__ row_ptr,
                             int* __restrict__ cursor, int n, int nb) {
    int i = blockIdx.x * 256 + threadIdx.x;
    if (i < n) {
        int r = row_ptr[i] + bsum[blockIdx.x];
        row_ptr[i] = r;
        cursor[i] = r;
    }
    if (i == 0) row_ptr[n] = bsum[nb];
}

__global__ void scatter_kernel(const int* __restrict__ src, const int* __restrict__ dst,
                               int* __restrict__ cursor, int* __restrict__ csr_src, int e) {
    int i = blockIdx.x * blockDim.x + threadIdx.x;
    if (i < e) {
        int p = atomicAdd(&cursor[dst[i]], 1);
        csr_src[p] = src[i];
    }
}

// ------------------------- weight pre-split (hi/lo bf16, permuted) ------
// 256-col: off = (k>>5)*8192 + (n>>4)*512 + ((k>>3)&3)*128 + (n&15)*8 + (k&7)
// head (64-col padded from 47): off = (k>>5)*2048 + same inner
__global__ void wcast_all_kernel(
    const float* __restrict__ c0W, const float* __restrict__ s0W,
    const float* __restrict__ c1W, const float* __restrict__ s1W,
    const float* __restrict__ m1W, const float* __restrict__ W2,
    unsigned short* __restrict__ c0h, unsigned short* __restrict__ c0l,
    unsigned short* __restrict__ s0h, unsigned short* __restrict__ s0l,
    unsigned short* __restrict__ c1h, unsigned short* __restrict__ c1l,
    unsigned short* __restrict__ s1h, unsigned short* __restrict__ s1l,
    unsigned short* __restrict__ m1h, unsigned short* __restrict__ m1l,
    unsigned short* __restrict__ hWh, unsigned short* __restrict__ hWl) {
    int i = blockIdx.x * blockDim.x + threadIdx.x;
    const float* W; unsigned short *H, *L; int base; int head = 0;
    if (i < 32768)        { W = c0W; H = c0h; L = c0l; base = i; }
    else if (i < 65536)   { W = s0W; H = s0h; L = s0l; base = i - 32768; }
    else if (i < 131072)  { W = c1W; H = c1h; L = c1l; base = i - 65536; }
    else if (i < 196608)  { W = s1W; H = s1h; L = s1l; base = i - 131072; }
    else if (i < 262144)  { W = m1W; H = m1h; L = m1l; base = i - 196608; }
    else if (i < 278528)  { W = W2;  H = hWh; L = hWl; base = i - 262144; head = 1; }
    else return;
    float x; int off;
    if (!head) {
        int k = base >> 8, n = base & 255;
        x = W[base];
        off = (k >> 5) * 8192 + (n >> 4) * 512 + ((k >> 3) & 3) * 128 + (n & 15) * 8 + (k & 7);
    } else {
        int k = base >> 6, n = base & 63;
        x = (n < 47) ? W[k * 47 + n] : 0.f;
        off = (k >> 5) * 2048 + (n >> 4) * 512 + ((k >> 3) & 3) * 128 + (n & 15) * 8 + (k & 7);
    }
    unsigned short h = f2bf(x);
    unsigned short l = f2bf(x - bf2f(h));
    H[off] = h;
    L[off] = l;
}

// ------------------------- x cast (row-major bf16) -----------------------
__global__ void acast_kernel(const float* __restrict__ in,
                             unsigned short* __restrict__ H, int n4) {
    int i = blockIdx.x * blockDim.x + threadIdx.x;
    if (i >= n4) return;
    float4 v = ((const float4*)in)[i];
    short4v h;
    h[0] = (short)f2bf(v.x); h[1] = (short)f2bf(v.y);
    h[2] = (short)f2bf(v.z); h[3] = (short)f2bf(v.w);
    *(short4v*)&H[i * 4] = h;
}

// ------------------------- MFMA GEMM (bf16x2: A bf16, B hi+lo) ----------
// C[M,256] = A[M,K] @ W[K,256].  Tile 32 x 256, 256 threads (4 waves),
// wave wid owns 32 rows x cols [wid*64, wid*64+64) (2x4 frags of 16x16x32).
// A: LDS double-buffered, reg-staged prefetch (threads 0..127), 1 barrier/K-step.
// B: per-lane direct global loads of pre-permuted fragments (L2-resident).
// EPI 1: elu(acc + add(bf16) + bias) -> C bf16
// EPI 2: relu(bn(acc + bias)) -> C bf16
// EPI 3: C bf16 + fused attn scores el/er
template <int EPI>
__global__ __launch_bounds__(256) void gemm_kernel(
    const unsigned short* __restrict__ Ah,
    const unsigned short* __restrict__ Bh_g, const unsigned short* __restrict__ Bl_g,
    int M, int K,
    unsigned short* __restrict__ C,
    const unsigned short* __restrict__ add, const float* __restrict__ bias,
    const float* __restrict__ g, const float* __restrict__ bt,
    const float* __restrict__ mean, const float* __restrict__ var,
    const float* __restrict__ al, const float* __restrict__ ar,
    float* __restrict__ el, float* __restrict__ er) {
    __shared__ short sA[2][1024];   // 32x32 bf16, frag-ordered, dbuf

    int tid = threadIdx.x;
    int lane = tid & 63;
    int wid = tid >> 6;
    int m0 = blockIdx.x * 32;

    f32x4 acc[2][4];
#pragma unroll
    for (int i = 0; i < 2; i++)
#pragma unroll
        for (int j = 0; j < 4; j++) acc[i][j] = (f32x4){0.f, 0.f, 0.f, 0.f};

    // A stage mapping: threads 0..127 stage (32 rows x 4 k-chunks)
    bool stager = (tid < 128);
    int t7 = tid & 127;
    int r = t7 >> 2, kq = t7 & 3;
    int gr = m0 + r;
    size_t abase = (size_t)gr * K + kq * 8;
    int aoff = (r >> 4) * 512 + kq * 128 + (r & 15) * 8;

    int nkt = K >> 5;
    if (stager) {
        short8 sreg = zero8();
        if (gr < M) sreg = *(const short8*)(Ah + abase);
        *(short8*)(&sA[0][0] + aoff) = sreg;
    }
    __syncthreads();

    const unsigned short* bhp = Bh_g + (wid * 4) * 512 + lane * 8;
    const unsigned short* blp = Bl_g + (wid * 4) * 512 + lane * 8;

    for (int kt = 0; kt < nkt; kt++) {
        // prefetch next A chunk into regs (hides HBM latency under MFMA)
        short8 nreg = zero8();
        if (stager && kt + 1 < nkt && gr < M)
            nreg = *(const short8*)(Ah + abase + (size_t)(kt + 1) * 32);
        // B fragments direct from global (L2-hit; same addrs for all blocks)
        short8 bh[4], bl[4];
#pragma unroll
        for (int nf = 0; nf < 4; nf++) {
            bh[nf] = *(const short8*)(bhp + kt * 8192 + nf * 512);
            bl[nf] = *(const short8*)(blp + kt * 8192 + nf * 512);
        }
        const short* cur = &sA[kt & 1][0];
        short8 ah[2];
#pragma unroll
        for (int mf = 0; mf < 2; mf++)
            ah[mf] = *(const short8*)(cur + mf * 512 + lane * 8);
#pragma unroll
        for (int nf = 0; nf < 4; nf++)
#pragma unroll
            for (int mf = 0; mf < 2; mf++) {
                acc[mf][nf] = __builtin_amdgcn_mfma_f32_16x16x32_bf16(ah[mf], bh[nf], acc[mf][nf], 0, 0, 0);
                acc[mf][nf] = __builtin_amdgcn_mfma_f32_16x16x32_bf16(ah[mf], bl[nf], acc[mf][nf], 0, 0, 0);
            }
        if (stager && kt + 1 < nkt)
            *(short8*)(&sA[(kt + 1) & 1][0] + aoff) = nreg;
        __syncthreads();
    }

    // ---- epilogue: C layout col=lane&15, row=(lane>>4)*4+reg ----
#pragma unroll
    for (int mf = 0; mf < 2; mf++) {
        int row0 = m0 + mf * 16 + (lane >> 4) * 4;
#pragma unroll
        for (int reg = 0; reg < 4; reg++) {
            int row = row0 + reg;
            if (row >= M) continue;
            size_t rb = (size_t)row * HID;
#pragma unroll
            for (int nf = 0; nf < 4; nf++) {
                int col = wid * 64 + nf * 16 + (lane & 15);
                float v = acc[mf][nf][reg];
                if (EPI == 3) {
                    C[rb + col] = f2bf(v);
                } else if (EPI == 1) {
                    v += bf2f(add[rb + col]) + bias[col];
                    v = (v > 0.f) ? v : expm1f(v);
                    C[rb + col] = f2bf(v);
                } else {
                    float s = g[col] * rsqrtf(var[col] + 1e-5f);
                    v = (v + bias[col] - mean[col]) * s + bt[col];
                    C[rb + col] = f2bf(fmaxf(v, 0.f));
                }
            }
        }
    }

    // ---- fused attention scores (EPI==3): wave wid == head wid ----
    if (EPI == 3) {
        float alv[4], arv[4];
#pragma unroll
        for (int nf = 0; nf < 4; nf++) {
            int col = wid * 64 + nf * 16 + (lane & 15);
            alv[nf] = al[col];
            arv[nf] = ar[col];
        }
#pragma unroll
        for (int mf = 0; mf < 2; mf++) {
#pragma unroll
            for (int reg = 0; reg < 4; reg++) {
                float pl = 0.f, pr = 0.f;
#pragma unroll
                for (int nf = 0; nf < 4; nf++) {
                    pl = fmaf(acc[mf][nf][reg], alv[nf], pl);
                    pr = fmaf(acc[mf][nf][reg], arv[nf], pr);
                }
#pragma unroll
                for (int off = 8; off; off >>= 1) {
                    pl += __shfl_xor(pl, off);
                    pr += __shfl_xor(pr, off);
                }
                int row = m0 + mf * 16 + (lane >> 4) * 4 + reg;
                if ((lane & 15) == 0 && row < M) {
                    el[row * 4 + wid] = pl;
                    er[row * 4 + wid] = pr;
                }
            }
        }
    }
}

// ------------------------- GAT aggregate (single pass, bf16 z/out) -------
// one wave per dst node; lane owns features [lane*4, lane*4+4) (head = lane>>4)
__global__ __launch_bounds__(256) void aggregate_kernel(
    const int* __restrict__ row_ptr, const int* __restrict__ csr_src,
    const float4* __restrict__ el4, const float4* __restrict__ er4,
    const unsigned short* __restrict__ zb, const float* __restrict__ bias,
    unsigned short* __restrict__ out, int n) {
    __shared__ float s_w[4][NH][64];
    __shared__ int s_s[4][64];
    int wid = threadIdx.x >> 6;
    int lane = threadIdx.x & 63;
    int node = blockIdx.x * 4 + wid;
    if (node >= n) return;
    int rb = row_ptr[node];
    int deg = row_ptr[node + 1] - rb;
    float4 ern = er4[node];
    float er_h[NH] = {ern.x, ern.y, ern.z, ern.w};
    int myh = lane >> 4;
    int f0 = lane * 4;

    float4 acc = make_float4(0.f, 0.f, 0.f, 0.f);
    float wsum[NH] = {0.f, 0.f, 0.f, 0.f};

    for (int c = 0; c < deg; c += 64) {
        int i = c + lane;
        int cnt = min(64, deg - c);
        if (i < deg) {
            int s = csr_src[rb + i];
            s_s[wid][lane] = s;
            float4 elv = el4[s];
            float ev[NH] = {elv.x, elv.y, elv.z, elv.w};
#pragma unroll
            for (int h = 0; h < NH; h++) {
                float e = ev[h] + er_h[h];
                e = (e > 0.f) ? e : 0.2f * e;
                float ee = __expf(e);
                s_w[wid][h][lane] = ee;
                wsum[h] += ee;
            }
        }
        __builtin_amdgcn_wave_barrier();
#pragma unroll 2
        for (int e = 0; e < cnt; e++) {
            int s = s_s[wid][e];
            uint2 zv = *(const uint2*)(zb + (size_t)s * HID + f0);
            float wgt = s_w[wid][myh][e];
            union { unsigned u; float f; } a0, a1, a2, a3;
            a0.u = zv.x << 16; a1.u = zv.x & 0xffff0000u;
            a2.u = zv.y << 16; a3.u = zv.y & 0xffff0000u;
            acc.x = fmaf(wgt, a0.f, acc.x);
            acc.y = fmaf(wgt, a1.f, acc.y);
            acc.z = fmaf(wgt, a2.f, acc.z);
            acc.w = fmaf(wgt, a3.f, acc.w);
        }
        __builtin_amdgcn_wave_barrier();
    }
    // reduce per-head denominators across the wave
#pragma unroll
    for (int h = 0; h < NH; h++)
#pragma unroll
        for (int off = 32; off; off >>= 1) wsum[h] += __shfl_xor(wsum[h], off);
    float inv = (wsum[myh] > 0.f) ? 1.f / wsum[myh] : 0.f;
    float4 b4 = *(const float4*)(bias + f0);
    short4v o;
    o[0] = (short)f2bf(acc.x * inv + b4.x);
    o[1] = (short)f2bf(acc.y * inv + b4.y);
    o[2] = (short)f2bf(acc.z * inv + b4.z);
    o[3] = (short)f2bf(acc.w * inv + b4.w);
    *(short4v*)(out + (size_t)node * HID + f0) = o;
}

// ------------------------- MFMA head: logits + log_softmax ---------------
// Tile 64 rows, K=256; wave w = rows [w*16,w*16+16) x all 64 cols.
// A bf16, B hi+lo direct from global (L2-resident, 64 KB total).
__global__ __launch_bounds__(256) void head_kernel(
    const unsigned short* __restrict__ Ah,
    const unsigned short* __restrict__ Bh_g, const unsigned short* __restrict__ Bl_g,
    const float* __restrict__ b2, float* __restrict__ out, int M) {
    __shared__ short sA[2048];    // 64x32
    int tid = threadIdx.x;
    int lane = tid & 63;
    int wid = tid >> 6;
    int m0 = blockIdx.x * 64;

    f32x4 acc[4];
#pragma unroll
    for (int nf = 0; nf < 4; nf++) acc[nf] = (f32x4){0.f, 0.f, 0.f, 0.f};

    for (int kt = 0; kt < 8; kt++) {
        {
            int r = tid >> 2, kq = tid & 3;
            int gr = m0 + r;
            short8 h8 = zero8();
            if (gr < M) h8 = *(const short8*)(Ah + (size_t)gr * HID + kt * 32 + kq * 8);
            int off = (r >> 4) * 512 + kq * 128 + (r & 15) * 8;
            *(short8*)&sA[off] = h8;
        }
        __syncthreads();
        short8 ah = *(const short8*)&sA[wid * 512 + lane * 8];
#pragma unroll
        for (int nf = 0; nf < 4; nf++) {
            short8 bh = *(const short8*)(Bh_g + kt * 2048 + nf * 512 + lane * 8);
            short8 bl = *(const short8*)(Bl_g + kt * 2048 + nf * 512 + lane * 8);
            acc[nf] = __builtin_amdgcn_mfma_f32_16x16x32_bf16(ah, bh, acc[nf], 0, 0, 0);
            acc[nf] = __builtin_amdgcn_mfma_f32_16x16x32_bf16(ah, bl, acc[nf], 0, 0, 0);
        }
        __syncthreads();
    }

    // fused log-softmax over 47 valid cols; row = m0+wid*16+(lane>>4)*4+reg
    int col0 = lane & 15;
    float bias_[4];
#pragma unroll
    for (int nf = 0; nf < 4; nf++) {
        int col = nf * 16 + col0;
        bias_[nf] = (col < 47) ? b2[col] : 0.f;
    }
#pragma unroll
    for (int reg = 0; reg < 4; reg++) {
        int row = m0 + wid * 16 + (lane >> 4) * 4 + reg;
        float lg[4];
        float mx = -INFINITY;
#pragma unroll
        for (int nf = 0; nf < 4; nf++) {
            int col = nf * 16 + col0;
            float v = acc[nf][reg] + bias_[nf];
            lg[nf] = v;
            if (col < 47) mx = fmaxf(mx, v);
        }
#pragma unroll
        for (int off = 8; off; off >>= 1) mx = fmaxf(mx, __shfl_xor(mx, off));
        float s = 0.f;
#pragma unroll
        for (int nf = 0; nf < 4; nf++) {
            int col = nf * 16 + col0;
            if (col < 47) s += __expf(lg[nf] - mx);
        }
#pragma unroll
        for (int off = 8; off; off >>= 1) s += __shfl_xor(s, off);
        float li = logf(s);
        if (row < M) {
#pragma unroll
            for (int nf = 0; nf < 3; nf++) {
                int col = nf * 16 + col0;
                if (col < 47) out[(size_t)row * 47 + col] = lg[nf] - mx - li;
            }
        }
    }
}

// ------------------------- launch -------------------------
extern "C" void kernel_launch(void* const* d_in, const int* in_sizes, int n_in,
                              void* d_out, int out_size, void* d_ws, size_t ws_size,
                              hipStream_t stream) {
    const float* x        = (const float*)d_in[0];
    const float* conv0_W  = (const float*)d_in[1];
    const float* conv0_al = (const float*)d_in[2];
    const float* conv0_ar = (const float*)d_in[3];
    const float* conv0_b  = (const float*)d_in[4];
    const float* skip0_W  = (const float*)d_in[5];
    const float* skip0_b  = (const float*)d_in[6];
    const float* conv1_W  = (const float*)d_in[7];
    const float* conv1_al = (const float*)d_in[8];
    const float* conv1_ar = (const float*)d_in[9];
    const float* conv1_b  = (const float*)d_in[10];
    const float* skip1_W  = (const float*)d_in[11];
    const float* skip1_b  = (const float*)d_in[12];
    const float* mlp_W1   = (const float*)d_in[13];
    const float* mlp_b1   = (const float*)d_in[14];
    const float* bn_gamma = (const float*)d_in[15];
    const float* bn_beta  = (const float*)d_in[16];
    const float* bn_mean  = (const float*)d_in[17];
    const float* bn_var   = (const float*)d_in[18];
    const float* mlp_W2   = (const float*)d_in[19];
    const float* mlp_b2   = (const float*)d_in[20];
    const int* edge_src   = (const int*)d_in[21];
    const int* edge_dst   = (const int*)d_in[22];
    float* out = (float*)d_out;

    // workspace carve-up (with aliasing)
    char* w = (char*)d_ws;
    size_t off = 0;
    auto alloc = [&](size_t bytes) {
        char* p = w + off;
        off += (bytes + 255) & ~(size_t)255;
        return p;
    };
    int*    row_ptr = (int*)alloc((NN + 1) * sizeof(int));
    int*    cursor  = (int*)alloc(NN * sizeof(int));
    int*    bsum    = (int*)alloc(512 * sizeof(int));
    int*    csr_src = (int*)alloc(NE * sizeof(int));
    float*  el      = (float*)alloc((size_t)NN * 4 * sizeof(float));
    float*  er      = (float*)alloc((size_t)NN * 4 * sizeof(float));
    unsigned short* aggbuf = (unsigned short*)alloc((size_t)NN * HID * 2);   // bf16
    unsigned short* zb   = (unsigned short*)alloc((size_t)NN * HID * 2);     // also mh
    unsigned short* slA  = (unsigned short*)alloc((size_t)NN * HID * 2);     // xh then h2h
    unsigned short* hh   = (unsigned short*)alloc((size_t)NN * HID * 2);
    unsigned short* c0h = (unsigned short*)alloc(128 * 256 * 2);
    unsigned short* c0l = (unsigned short*)alloc(128 * 256 * 2);
    unsigned short* s0h = (unsigned short*)alloc(128 * 256 * 2);
    unsigned short* s0l = (unsigned short*)alloc(128 * 256 * 2);
    unsigned short* c1h = (unsigned short*)alloc(256 * 256 * 2);
    unsigned short* c1l = (unsigned short*)alloc(256 * 256 * 2);
    unsigned short* s1h = (unsigned short*)alloc(256 * 256 * 2);
    unsigned short* s1l = (unsigned short*)alloc(256 * 256 * 2);
    unsigned short* m1h = (unsigned short*)alloc(256 * 256 * 2);
    unsigned short* m1l = (unsigned short*)alloc(256 * 256 * 2);
    unsigned short* hWh = (unsigned short*)alloc(256 * 64 * 2);
    unsigned short* hWl = (unsigned short*)alloc(256 * 64 * 2);
    (void)ws_size;

    unsigned short* xh  = slA;   // 50000x128 (half the slab)
    unsigned short* h2h = slA;   // alive after x is dead
    unsigned short* mh  = zb;    // alive after zb is dead

    int gemm_grid = cdiv(NN, 32);      // 1563 blocks, 32-row tiles
    int head_grid = cdiv(NN, 64);
    int nodeblocks = cdiv(NN, 4);
    int scan_blocks = cdiv(NN, 256);

    // weight pre-split + x cast
    wcast_all_kernel<<<cdiv(278528, 256), 256, 0, stream>>>(
        conv0_W, skip0_W, conv1_W, skip1_W, mlp_W1, mlp_W2,
        c0h, c0l, s0h, s0l, c1h, c1l, s1h, s1l, m1h, m1l, hWh, hWl);
    acast_kernel<<<cdiv(NN * 128 / 4, 256), 256, 0, stream>>>(x, xh, NN * 128 / 4);

    // CSR build (shared by both layers) — parallel two-level scan
    hipMemsetAsync(cursor, 0, NN * sizeof(int), stream);
    hist_kernel<<<cdiv(NE, 256), 256, 0, stream>>>(edge_dst, cursor, NE);
    scan1_kernel<<<scan_blocks, 256, 0, stream>>>(cursor, row_ptr, bsum, NN);
    scan2_kernel<<<1, 256, 0, stream>>>(bsum, scan_blocks);
    scan3_kernel<<<scan_blocks, 256, 0, stream>>>(bsum, row_ptr, cursor, NN, scan_blocks);
    scatter_kernel<<<cdiv(NE, 256), 256, 0, stream>>>(edge_src, edge_dst, cursor, csr_src, NE);

    // layer 0
    gemm_kernel<3><<<gemm_grid, 256, 0, stream>>>(xh, c0h, c0l, NN, 128,
        zb, nullptr, nullptr, nullptr, nullptr, nullptr, nullptr,
        conv0_al, conv0_ar, el, er);
    aggregate_kernel<<<nodeblocks, 256, 0, stream>>>(row_ptr, csr_src, (const float4*)el, (const float4*)er,
                                                     zb, conv0_b, aggbuf, NN);
    gemm_kernel<1><<<gemm_grid, 256, 0, stream>>>(xh, s0h, s0l, NN, 128,
        hh, aggbuf, skip0_b, nullptr, nullptr, nullptr, nullptr,
        nullptr, nullptr, nullptr, nullptr);

    // layer 1
    gemm_kernel<3><<<gemm_grid, 256, 0, stream>>>(hh, c1h, c1l, NN, 256,
        zb, nullptr, nullptr, nullptr, nullptr, nullptr, nullptr,
        conv1_al, conv1_ar, el, er);
    aggregate_kernel<<<nodeblocks, 256, 0, stream>>>(row_ptr, csr_src, (const float4*)el, (const float4*)er,
                                                     zb, conv1_b, aggbuf, NN);
    gemm_kernel<1><<<gemm_grid, 256, 0, stream>>>(hh, s1h, s1l, NN, 256,
        h2h, aggbuf, skip1_b, nullptr, nullptr, nullptr, nullptr,
        nullptr, nullptr, nullptr, nullptr);

    // MLP head: m = relu(bn(h2 @ W1 + b1));  (mh aliases zb, dead now)
    gemm_kernel<2><<<gemm_grid, 256, 0, stream>>>(h2h, m1h, m1l, NN, 256,
        mh, nullptr, mlp_b1, bn_gamma, bn_beta, bn_mean, bn_var,
        nullptr, nullptr, nullptr, nullptr);
    head_kernel<<<head_grid, 256, 0, stream>>>(mh, hWh, hWl, mlp_b2, out, NN);
}

// Round 8
// 343.249 us; speedup vs baseline: 3.1185x; 1.2144x over previous
//
#include <hip/hip_runtime.h>
#include <math.h>

#define NN 50000
#define NE 800000
#define HID 256
#define NH 4
#define DH 64

static inline int cdiv(int a, int b) { return (a + b - 1) / b; }

typedef __attribute__((ext_vector_type(8))) short short8;
typedef __attribute__((ext_vector_type(4))) short short4v;
typedef __attribute__((ext_vector_type(4))) float f32x4;

// bf16 helpers (round-to-nearest-even)
__device__ inline unsigned short f2bf(float x) {
    union { float f; unsigned u; } v; v.f = x;
    unsigned r = v.u + 0x7FFFu + ((v.u >> 16) & 1u);
    return (unsigned short)(r >> 16);
}
__device__ inline float bf2f(unsigned short h) {
    union { unsigned u; float f; } v; v.u = ((unsigned)h) << 16;
    return v.f;
}
__device__ inline short8 zero8() {
    short8 z;
#pragma unroll
    for (int j = 0; j < 8; j++) z[j] = 0;
    return z;
}

// ------------------------- CSR build -------------------------
__global__ void hist_kernel(const int* __restrict__ dst, int* __restrict__ deg, int e) {
    int i = blockIdx.x * blockDim.x + threadIdx.x;
    if (i < e) atomicAdd(&deg[dst[i]], 1);
}

__global__ void scan1_kernel(const int* __restrict__ deg, int* __restrict__ local,
                             int* __restrict__ bsum, int n) {
    __shared__ int s[256];
    int tid = threadIdx.x;
    int i = blockIdx.x * 256 + tid;
    int v = (i < n) ? deg[i] : 0;
    s[tid] = v;
    __syncthreads();
    for (int off = 1; off < 256; off <<= 1) {
        int t = (tid >= off) ? s[tid - off] : 0;
        __syncthreads();
        s[tid] += t;
        __syncthreads();
    }
    if (i < n) local[i] = s[tid] - v;      // exclusive within block
    if (tid == 255) bsum[blockIdx.x] = s[255];
}

__global__ void scan2_kernel(int* __restrict__ bsum, int nb) {
    __shared__ int s[256];
    int tid = threadIdx.x;
    int v = (tid < nb) ? bsum[tid] : 0;
    s[tid] = v;
    __syncthreads();
    for (int off = 1; off < 256; off <<= 1) {
        int t = (tid >= off) ? s[tid - off] : 0;
        __syncthreads();
        s[tid] += t;
        __syncthreads();
    }
    if (tid < nb) bsum[tid] = s[tid] - v;  // exclusive
    if (tid == 255) bsum[nb] = s[255];     // total
}

__global__ void scan3_kernel(const int* __restrict__ bsum, int* __restrict__ row_ptr,
                             int* __restrict__ cursor, int n, int nb) {
    int i = blockIdx.x * 256 + threadIdx.x;
    if (i < n) {
        int r = row_ptr[i] + bsum[blockIdx.x];
        row_ptr[i] = r;
        cursor[i] = r;
    }
    if (i == 0) row_ptr[n] = bsum[nb];
}

__global__ void scatter_kernel(const int* __restrict__ src, const int* __restrict__ dst,
                               int* __restrict__ cursor, int* __restrict__ csr_src, int e) {
    int i = blockIdx.x * blockDim.x + threadIdx.x;
    if (i < e) {
        int p = atomicAdd(&cursor[dst[i]], 1);
        csr_src[p] = src[i];
    }
}

// ------------------------- weight cast (bf16, permuted frag order) ------
// 256-col: off = (k>>5)*8192 + (n>>4)*512 + ((k>>3)&3)*128 + (n&15)*8 + (k&7)
// head (64-col padded from 47): off = (k>>5)*2048 + same inner
__global__ void wcast_all_kernel(
    const float* __restrict__ c0W, const float* __restrict__ s0W,
    const float* __restrict__ c1W, const float* __restrict__ s1W,
    const float* __restrict__ m1W, const float* __restrict__ W2,
    unsigned short* __restrict__ c0h, unsigned short* __restrict__ s0h,
    unsigned short* __restrict__ c1h, unsigned short* __restrict__ s1h,
    unsigned short* __restrict__ m1h, unsigned short* __restrict__ hWh) {
    int i = blockIdx.x * blockDim.x + threadIdx.x;
    const float* W; unsigned short* H; int base; int head = 0;
    if (i < 32768)        { W = c0W; H = c0h; base = i; }
    else if (i < 65536)   { W = s0W; H = s0h; base = i - 32768; }
    else if (i < 131072)  { W = c1W; H = c1h; base = i - 65536; }
    else if (i < 196608)  { W = s1W; H = s1h; base = i - 131072; }
    else if (i < 262144)  { W = m1W; H = m1h; base = i - 196608; }
    else if (i < 278528)  { W = W2;  H = hWh; base = i - 262144; head = 1; }
    else return;
    float x; int off;
    if (!head) {
        int k = base >> 8, n = base & 255;
        x = W[base];
        off = (k >> 5) * 8192 + (n >> 4) * 512 + ((k >> 3) & 3) * 128 + (n & 15) * 8 + (k & 7);
    } else {
        int k = base >> 6, n = base & 63;
        x = (n < 47) ? W[k * 47 + n] : 0.f;
        off = (k >> 5) * 2048 + (n >> 4) * 512 + ((k >> 3) & 3) * 128 + (n & 15) * 8 + (k & 7);
    }
    H[off] = f2bf(x);
}

// ------------------------- x cast (row-major bf16) -----------------------
__global__ void acast_kernel(const float* __restrict__ in,
                             unsigned short* __restrict__ H, int n4) {
    int i = blockIdx.x * blockDim.x + threadIdx.x;
    if (i >= n4) return;
    float4 v = ((const float4*)in)[i];
    short4v h;
    h[0] = (short)f2bf(v.x); h[1] = (short)f2bf(v.y);
    h[2] = (short)f2bf(v.z); h[3] = (short)f2bf(v.w);
    *(short4v*)&H[i * 4] = h;
}

// ------------- fused conv+skip GEMM (plain bf16, B direct from L2) -------
// zb = A@Wc (bf16 out, + fused attn scores), sraw = A@Ws (bf16 out).
// Tile 32 x 256, 4 waves; wave wid owns 32 rows x cols [wid*64,+64).
// A: LDS double-buffered, reg prefetch (threads 0..127), 1 barrier/K-step.
__global__ __launch_bounds__(256) void gemm_fused_kernel(
    const unsigned short* __restrict__ Ah,
    const unsigned short* __restrict__ Wc, const unsigned short* __restrict__ Ws,
    int M, int K,
    unsigned short* __restrict__ zb, unsigned short* __restrict__ sraw,
    const float* __restrict__ al, const float* __restrict__ ar,
    float* __restrict__ el, float* __restrict__ er) {
    __shared__ short sA[2][1024];   // 32x32 bf16, frag-ordered, dbuf

    int tid = threadIdx.x;
    int lane = tid & 63;
    int wid = tid >> 6;
    int m0 = blockIdx.x * 32;

    f32x4 accc[2][4], accs[2][4];
#pragma unroll
    for (int i = 0; i < 2; i++)
#pragma unroll
        for (int j = 0; j < 4; j++) {
            accc[i][j] = (f32x4){0.f, 0.f, 0.f, 0.f};
            accs[i][j] = (f32x4){0.f, 0.f, 0.f, 0.f};
        }

    bool stager = (tid < 128);
    int t7 = tid & 127;
    int r = t7 >> 2, kq = t7 & 3;
    int gr = m0 + r;
    size_t abase = (size_t)gr * K + kq * 8;
    int aoff = (r >> 4) * 512 + kq * 128 + (r & 15) * 8;

    int nkt = K >> 5;
    if (stager) {
        short8 sreg = zero8();
        if (gr < M) sreg = *(const short8*)(Ah + abase);
        *(short8*)(&sA[0][0] + aoff) = sreg;
    }
    __syncthreads();

    const unsigned short* bcp = Wc + (wid * 4) * 512 + lane * 8;
    const unsigned short* bsp = Ws + (wid * 4) * 512 + lane * 8;

    for (int kt = 0; kt < nkt; kt++) {
        short8 nreg = zero8();
        if (stager && kt + 1 < nkt && gr < M)
            nreg = *(const short8*)(Ah + abase + (size_t)(kt + 1) * 32);
        short8 bc[4], bs[4];
#pragma unroll
        for (int nf = 0; nf < 4; nf++) {
            bc[nf] = *(const short8*)(bcp + kt * 8192 + nf * 512);
            bs[nf] = *(const short8*)(bsp + kt * 8192 + nf * 512);
        }
        const short* cur = &sA[kt & 1][0];
        short8 ah[2];
#pragma unroll
        for (int mf = 0; mf < 2; mf++)
            ah[mf] = *(const short8*)(cur + mf * 512 + lane * 8);
#pragma unroll
        for (int nf = 0; nf < 4; nf++)
#pragma unroll
            for (int mf = 0; mf < 2; mf++) {
                accc[mf][nf] = __builtin_amdgcn_mfma_f32_16x16x32_bf16(ah[mf], bc[nf], accc[mf][nf], 0, 0, 0);
                accs[mf][nf] = __builtin_amdgcn_mfma_f32_16x16x32_bf16(ah[mf], bs[nf], accs[mf][nf], 0, 0, 0);
            }
        if (stager && kt + 1 < nkt)
            *(short8*)(&sA[(kt + 1) & 1][0] + aoff) = nreg;
        __syncthreads();
    }

    // ---- epilogue: C layout col=lane&15, row=(lane>>4)*4+reg ----
#pragma unroll
    for (int mf = 0; mf < 2; mf++) {
        int row0 = m0 + mf * 16 + (lane >> 4) * 4;
#pragma unroll
        for (int reg = 0; reg < 4; reg++) {
            int row = row0 + reg;
            if (row >= M) continue;
            size_t rb = (size_t)row * HID;
#pragma unroll
            for (int nf = 0; nf < 4; nf++) {
                int col = wid * 64 + nf * 16 + (lane & 15);
                zb[rb + col] = f2bf(accc[mf][nf][reg]);
                sraw[rb + col] = f2bf(accs[mf][nf][reg]);
            }
        }
    }

    // ---- fused attention scores: wave wid == head wid ----
    {
        float alv[4], arv[4];
#pragma unroll
        for (int nf = 0; nf < 4; nf++) {
            int col = wid * 64 + nf * 16 + (lane & 15);
            alv[nf] = al[col];
            arv[nf] = ar[col];
        }
#pragma unroll
        for (int mf = 0; mf < 2; mf++) {
#pragma unroll
            for (int reg = 0; reg < 4; reg++) {
                float pl = 0.f, pr = 0.f;
#pragma unroll
                for (int nf = 0; nf < 4; nf++) {
                    pl = fmaf(accc[mf][nf][reg], alv[nf], pl);
                    pr = fmaf(accc[mf][nf][reg], arv[nf], pr);
                }
#pragma unroll
                for (int off = 8; off; off >>= 1) {
                    pl += __shfl_xor(pl, off);
                    pr += __shfl_xor(pr, off);
                }
                int row = m0 + mf * 16 + (lane >> 4) * 4 + reg;
                if ((lane & 15) == 0 && row < M) {
                    el[row * 4 + wid] = pl;
                    er[row * 4 + wid] = pr;
                }
            }
        }
    }
}

// ---------- GAT aggregate + fused skip/ELU (single pass, bf16) ----------
// one wave per dst node; lane owns features [lane*4, lane*4+4) (head = lane>>4)
// h = elu(agg_avg + conv_b + sraw + skip_b) -> bf16
__global__ __launch_bounds__(256) void aggregate_kernel(
    const int* __restrict__ row_ptr, const int* __restrict__ csr_src,
    const float4* __restrict__ el4, const float4* __restrict__ er4,
    const unsigned short* __restrict__ zb, const float* __restrict__ conv_b,
    const unsigned short* __restrict__ sraw, const float* __restrict__ skip_b,
    unsigned short* __restrict__ outh, int n) {
    __shared__ float s_w[4][NH][64];
    __shared__ int s_s[4][64];
    int wid = threadIdx.x >> 6;
    int lane = threadIdx.x & 63;
    int node = blockIdx.x * 4 + wid;
    if (node >= n) return;
    int rb = row_ptr[node];
    int deg = row_ptr[node + 1] - rb;
    float4 ern = er4[node];
    float er_h[NH] = {ern.x, ern.y, ern.z, ern.w};
    int myh = lane >> 4;
    int f0 = lane * 4;

    float4 acc = make_float4(0.f, 0.f, 0.f, 0.f);
    float wsum[NH] = {0.f, 0.f, 0.f, 0.f};

    for (int c = 0; c < deg; c += 64) {
        int i = c + lane;
        int cnt = min(64, deg - c);
        if (i < deg) {
            int s = csr_src[rb + i];
            s_s[wid][lane] = s;
            float4 elv = el4[s];
            float ev[NH] = {elv.x, elv.y, elv.z, elv.w};
#pragma unroll
            for (int h = 0; h < NH; h++) {
                float e = ev[h] + er_h[h];
                e = (e > 0.f) ? e : 0.2f * e;
                float ee = __expf(e);
                s_w[wid][h][lane] = ee;
                wsum[h] += ee;
            }
        }
        __builtin_amdgcn_wave_barrier();
#pragma unroll 2
        for (int e = 0; e < cnt; e++) {
            int s = s_s[wid][e];
            uint2 zv = *(const uint2*)(zb + (size_t)s * HID + f0);
            float wgt = s_w[wid][myh][e];
            union { unsigned u; float f; } a0, a1, a2, a3;
            a0.u = zv.x << 16; a1.u = zv.x & 0xffff0000u;
            a2.u = zv.y << 16; a3.u = zv.y & 0xffff0000u;
            acc.x = fmaf(wgt, a0.f, acc.x);
            acc.y = fmaf(wgt, a1.f, acc.y);
            acc.z = fmaf(wgt, a2.f, acc.z);
            acc.w = fmaf(wgt, a3.f, acc.w);
        }
        __builtin_amdgcn_wave_barrier();
    }
    // reduce per-head denominators across the wave
#pragma unroll
    for (int h = 0; h < NH; h++)
#pragma unroll
        for (int off = 32; off; off >>= 1) wsum[h] += __shfl_xor(wsum[h], off);
    float inv = (wsum[myh] > 0.f) ? 1.f / wsum[myh] : 0.f;
    float4 cb = *(const float4*)(conv_b + f0);
    float4 sb = *(const float4*)(skip_b + f0);
    uint2 sv = *(const uint2*)(sraw + (size_t)node * HID + f0);
    union { unsigned u; float f; } s0, s1, s2, s3;
    s0.u = sv.x << 16; s1.u = sv.x & 0xffff0000u;
    s2.u = sv.y << 16; s3.u = sv.y & 0xffff0000u;
    float v0 = acc.x * inv + cb.x + s0.f + sb.x;
    float v1 = acc.y * inv + cb.y + s1.f + sb.y;
    float v2 = acc.z * inv + cb.z + s2.f + sb.z;
    float v3 = acc.w * inv + cb.w + s3.f + sb.w;
    v0 = (v0 > 0.f) ? v0 : expm1f(v0);
    v1 = (v1 > 0.f) ? v1 : expm1f(v1);
    v2 = (v2 > 0.f) ? v2 : expm1f(v2);
    v3 = (v3 > 0.f) ? v3 : expm1f(v3);
    short4v o;
    o[0] = (short)f2bf(v0); o[1] = (short)f2bf(v1);
    o[2] = (short)f2bf(v2); o[3] = (short)f2bf(v3);
    *(short4v*)(outh + (size_t)node * HID + f0) = o;
}

// ------------------------- MLP GEMM (plain bf16): relu(bn(A@W1+b1)) ------
__global__ __launch_bounds__(256) void gemm_bn_kernel(
    const unsigned short* __restrict__ Ah, const unsigned short* __restrict__ Bh_g,
    int M, int K, unsigned short* __restrict__ C,
    const float* __restrict__ bias, const float* __restrict__ g,
    const float* __restrict__ bt, const float* __restrict__ mean,
    const float* __restrict__ var) {
    __shared__ short sA[2][1024];
    int tid = threadIdx.x;
    int lane = tid & 63;
    int wid = tid >> 6;
    int m0 = blockIdx.x * 32;

    f32x4 acc[2][4];
#pragma unroll
    for (int i = 0; i < 2; i++)
#pragma unroll
        for (int j = 0; j < 4; j++) acc[i][j] = (f32x4){0.f, 0.f, 0.f, 0.f};

    bool stager = (tid < 128);
    int t7 = tid & 127;
    int r = t7 >> 2, kq = t7 & 3;
    int gr = m0 + r;
    size_t abase = (size_t)gr * K + kq * 8;
    int aoff = (r >> 4) * 512 + kq * 128 + (r & 15) * 8;

    int nkt = K >> 5;
    if (stager) {
        short8 sreg = zero8();
        if (gr < M) sreg = *(const short8*)(Ah + abase);
        *(short8*)(&sA[0][0] + aoff) = sreg;
    }
    __syncthreads();

    const unsigned short* bhp = Bh_g + (wid * 4) * 512 + lane * 8;

    for (int kt = 0; kt < nkt; kt++) {
        short8 nreg = zero8();
        if (stager && kt + 1 < nkt && gr < M)
            nreg = *(const short8*)(Ah + abase + (size_t)(kt + 1) * 32);
        short8 bh[4];
#pragma unroll
        for (int nf = 0; nf < 4; nf++)
            bh[nf] = *(const short8*)(bhp + kt * 8192 + nf * 512);
        const short* cur = &sA[kt & 1][0];
        short8 ah[2];
#pragma unroll
        for (int mf = 0; mf < 2; mf++)
            ah[mf] = *(const short8*)(cur + mf * 512 + lane * 8);
#pragma unroll
        for (int nf = 0; nf < 4; nf++)
#pragma unroll
            for (int mf = 0; mf < 2; mf++)
                acc[mf][nf] = __builtin_amdgcn_mfma_f32_16x16x32_bf16(ah[mf], bh[nf], acc[mf][nf], 0, 0, 0);
        if (stager && kt + 1 < nkt)
            *(short8*)(&sA[(kt + 1) & 1][0] + aoff) = nreg;
        __syncthreads();
    }

#pragma unroll
    for (int mf = 0; mf < 2; mf++) {
        int row0 = m0 + mf * 16 + (lane >> 4) * 4;
#pragma unroll
        for (int reg = 0; reg < 4; reg++) {
            int row = row0 + reg;
            if (row >= M) continue;
            size_t rb = (size_t)row * HID;
#pragma unroll
            for (int nf = 0; nf < 4; nf++) {
                int col = wid * 64 + nf * 16 + (lane & 15);
                float v = acc[mf][nf][reg];
                float s = g[col] * rsqrtf(var[col] + 1e-5f);
                v = (v + bias[col] - mean[col]) * s + bt[col];
                C[rb + col] = f2bf(fmaxf(v, 0.f));
            }
        }
    }
}

// ------------------------- MFMA head: logits + log_softmax ---------------
// Tile 64 rows, K=256; wave w = rows [w*16,w*16+16) x all 64 cols.
__global__ __launch_bounds__(256) void head_kernel(
    const unsigned short* __restrict__ Ah, const unsigned short* __restrict__ Bh_g,
    const float* __restrict__ b2, float* __restrict__ out, int M) {
    __shared__ short sA[2048];    // 64x32
    int tid = threadIdx.x;
    int lane = tid & 63;
    int wid = tid >> 6;
    int m0 = blockIdx.x * 64;

    f32x4 acc[4];
#pragma unroll
    for (int nf = 0; nf < 4; nf++) acc[nf] = (f32x4){0.f, 0.f, 0.f, 0.f};

    for (int kt = 0; kt < 8; kt++) {
        {
            int r = tid >> 2, kq = tid & 3;
            int gr = m0 + r;
            short8 h8 = zero8();
            if (gr < M) h8 = *(const short8*)(Ah + (size_t)gr * HID + kt * 32 + kq * 8);
            int off = (r >> 4) * 512 + kq * 128 + (r & 15) * 8;
            *(short8*)&sA[off] = h8;
        }
        __syncthreads();
        short8 ah = *(const short8*)&sA[wid * 512 + lane * 8];
#pragma unroll
        for (int nf = 0; nf < 4; nf++) {
            short8 bh = *(const short8*)(Bh_g + kt * 2048 + nf * 512 + lane * 8);
            acc[nf] = __builtin_amdgcn_mfma_f32_16x16x32_bf16(ah, bh, acc[nf], 0, 0, 0);
        }
        __syncthreads();
    }

    // fused log-softmax over 47 valid cols; row = m0+wid*16+(lane>>4)*4+reg
    int col0 = lane & 15;
    float bias_[4];
#pragma unroll
    for (int nf = 0; nf < 4; nf++) {
        int col = nf * 16 + col0;
        bias_[nf] = (col < 47) ? b2[col] : 0.f;
    }
#pragma unroll
    for (int reg = 0; reg < 4; reg++) {
        int row = m0 + wid * 16 + (lane >> 4) * 4 + reg;
        float lg[4];
        float mx = -INFINITY;
#pragma unroll
        for (int nf = 0; nf < 4; nf++) {
            int col = nf * 16 + col0;
            float v = acc[nf][reg] + bias_[nf];
            lg[nf] = v;
            if (col < 47) mx = fmaxf(mx, v);
        }
#pragma unroll
        for (int off = 8; off; off >>= 1) mx = fmaxf(mx, __shfl_xor(mx, off));
        float s = 0.f;
#pragma unroll
        for (int nf = 0; nf < 4; nf++) {
            int col = nf * 16 + col0;
            if (col < 47) s += __expf(lg[nf] - mx);
        }
#pragma unroll
        for (int off = 8; off; off >>= 1) s += __shfl_xor(s, off);
        float li = logf(s);
        if (row < M) {
#pragma unroll
            for (int nf = 0; nf < 3; nf++) {
                int col = nf * 16 + col0;
                if (col < 47) out[(size_t)row * 47 + col] = lg[nf] - mx - li;
            }
        }
    }
}

// ------------------------- launch -------------------------
extern "C" void kernel_launch(void* const* d_in, const int* in_sizes, int n_in,
                              void* d_out, int out_size, void* d_ws, size_t ws_size,
                              hipStream_t stream) {
    const float* x        = (const float*)d_in[0];
    const float* conv0_W  = (const float*)d_in[1];
    const float* conv0_al = (const float*)d_in[2];
    const float* conv0_ar = (const float*)d_in[3];
    const float* conv0_b  = (const float*)d_in[4];
    const float* skip0_W  = (const float*)d_in[5];
    const float* skip0_b  = (const float*)d_in[6];
    const float* conv1_W  = (const float*)d_in[7];
    const float* conv1_al = (const float*)d_in[8];
    const float* conv1_ar = (const float*)d_in[9];
    const float* conv1_b  = (const float*)d_in[10];
    const float* skip1_W  = (const float*)d_in[11];
    const float* skip1_b  = (const float*)d_in[12];
    const float* mlp_W1   = (const float*)d_in[13];
    const float* mlp_b1   = (const float*)d_in[14];
    const float* bn_gamma = (const float*)d_in[15];
    const float* bn_beta  = (const float*)d_in[16];
    const float* bn_mean  = (const float*)d_in[17];
    const float* bn_var   = (const float*)d_in[18];
    const float* mlp_W2   = (const float*)d_in[19];
    const float* mlp_b2   = (const float*)d_in[20];
    const int* edge_src   = (const int*)d_in[21];
    const int* edge_dst   = (const int*)d_in[22];
    float* out = (float*)d_out;

    // workspace carve-up (with aliasing)
    char* w = (char*)d_ws;
    size_t off = 0;
    auto alloc = [&](size_t bytes) {
        char* p = w + off;
        off += (bytes + 255) & ~(size_t)255;
        return p;
    };
    int*    row_ptr = (int*)alloc((NN + 1) * sizeof(int));
    int*    cursor  = (int*)alloc(NN * sizeof(int));
    int*    bsum    = (int*)alloc(512 * sizeof(int));
    int*    csr_src = (int*)alloc(NE * sizeof(int));
    float*  el      = (float*)alloc((size_t)NN * 4 * sizeof(float));
    float*  er      = (float*)alloc((size_t)NN * 4 * sizeof(float));
    unsigned short* zb   = (unsigned short*)alloc((size_t)NN * HID * 2);  // z; later m
    unsigned short* sraw = (unsigned short*)alloc((size_t)NN * HID * 2);  // skip raw
    unsigned short* slA  = (unsigned short*)alloc((size_t)NN * HID * 2);  // xh then h2h
    unsigned short* hh   = (unsigned short*)alloc((size_t)NN * HID * 2);  // h
    unsigned short* c0h = (unsigned short*)alloc(128 * 256 * 2);
    unsigned short* s0h = (unsigned short*)alloc(128 * 256 * 2);
    unsigned short* c1h = (unsigned short*)alloc(256 * 256 * 2);
    unsigned short* s1h = (unsigned short*)alloc(256 * 256 * 2);
    unsigned short* m1h = (unsigned short*)alloc(256 * 256 * 2);
    unsigned short* hWh = (unsigned short*)alloc(256 * 64 * 2);
    (void)ws_size;

    unsigned short* xh  = slA;   // 50000x128 (half the slab)
    unsigned short* h2h = slA;   // alive after x is dead (layer-0 GEMM is x's last use... layer0 fused gemm)
    unsigned short* mh  = zb;    // alive after zb is dead

    int gemm_grid = cdiv(NN, 32);      // 1563 blocks, 32-row tiles
    int head_grid = cdiv(NN, 64);
    int nodeblocks = cdiv(NN, 4);
    int scan_blocks = cdiv(NN, 256);

    // weight cast + x cast
    wcast_all_kernel<<<cdiv(278528, 256), 256, 0, stream>>>(
        conv0_W, skip0_W, conv1_W, skip1_W, mlp_W1, mlp_W2,
        c0h, s0h, c1h, s1h, m1h, hWh);
    acast_kernel<<<cdiv(NN * 128 / 4, 256), 256, 0, stream>>>(x, xh, NN * 128 / 4);

    // CSR build (shared by both layers) — parallel two-level scan
    hipMemsetAsync(cursor, 0, NN * sizeof(int), stream);
    hist_kernel<<<cdiv(NE, 256), 256, 0, stream>>>(edge_dst, cursor, NE);
    scan1_kernel<<<scan_blocks, 256, 0, stream>>>(cursor, row_ptr, bsum, NN);
    scan2_kernel<<<1, 256, 0, stream>>>(bsum, scan_blocks);
    scan3_kernel<<<scan_blocks, 256, 0, stream>>>(bsum, row_ptr, cursor, NN, scan_blocks);
    scatter_kernel<<<cdiv(NE, 256), 256, 0, stream>>>(edge_src, edge_dst, cursor, csr_src, NE);

    // layer 0: fused conv+skip GEMM, then aggregate(+skip+ELU) -> h
    gemm_fused_kernel<<<gemm_grid, 256, 0, stream>>>(xh, c0h, s0h, NN, 128,
        zb, sraw, conv0_al, conv0_ar, el, er);
    aggregate_kernel<<<nodeblocks, 256, 0, stream>>>(row_ptr, csr_src,
        (const float4*)el, (const float4*)er, zb, conv0_b, sraw, skip0_b, hh, NN);

    // layer 1 (h2h aliases slA; xh dead after layer-0 gemm)
    gemm_fused_kernel<<<gemm_grid, 256, 0, stream>>>(hh, c1h, s1h, NN, 256,
        zb, sraw, conv1_al, conv1_ar, el, er);
    aggregate_kernel<<<nodeblocks, 256, 0, stream>>>(row_ptr, csr_src,
        (const float4*)el, (const float4*)er, zb, conv1_b, sraw, skip1_b, h2h, NN);

    // MLP head: m = relu(bn(h2 @ W1 + b1));  (mh aliases zb, dead now)
    gemm_bn_kernel<<<gemm_grid, 256, 0, stream>>>(h2h, m1h, NN, 256,
        mh, mlp_b1, bn_gamma, bn_beta, bn_mean, bn_var);
    head_kernel<<<head_grid, 256, 0, stream>>>(mh, hWh, mlp_b2, out, NN);
}

// Round 9
// 303.920 us; speedup vs baseline: 3.5220x; 1.1294x over previous
//
#include <hip/hip_runtime.h>
#include <math.h>

#define NN 50000
#define NE 800000
#define HID 256
#define NH 4
#define DH 64

static inline int cdiv(int a, int b) { return (a + b - 1) / b; }

typedef __attribute__((ext_vector_type(8))) short short8;
typedef __attribute__((ext_vector_type(4))) short short4v;
typedef __attribute__((ext_vector_type(4))) float f32x4;
typedef __attribute__((ext_vector_type(2))) float f32x2;

// bf16 helpers (round-to-nearest-even)
__device__ inline unsigned short f2bf(float x) {
    union { float f; unsigned u; } v; v.f = x;
    unsigned r = v.u + 0x7FFFu + ((v.u >> 16) & 1u);
    return (unsigned short)(r >> 16);
}
__device__ inline float bf2f(unsigned short h) {
    union { unsigned u; float f; } v; v.u = ((unsigned)h) << 16;
    return v.f;
}
__device__ inline short8 zero8() {
    short8 z;
#pragma unroll
    for (int j = 0; j < 8; j++) z[j] = 0;
    return z;
}
// fp8 e4m3 (OCP) encode via HW convert
__device__ inline unsigned char f2fp8(float x) {
    int p = __builtin_amdgcn_cvt_pk_fp8_f32(x, 0.f, 0, false);
    return (unsigned char)(p & 0xff);
}

// ------------------------- CSR build -------------------------
__global__ void hist_kernel(const int* __restrict__ dst, int* __restrict__ deg, int e) {
    int i = blockIdx.x * blockDim.x + threadIdx.x;
    if (i < e) atomicAdd(&deg[dst[i]], 1);
}

__global__ void scan1_kernel(const int* __restrict__ deg, int* __restrict__ local,
                             int* __restrict__ bsum, int n) {
    __shared__ int s[256];
    int tid = threadIdx.x;
    int i = blockIdx.x * 256 + tid;
    int v = (i < n) ? deg[i] : 0;
    s[tid] = v;
    __syncthreads();
    for (int off = 1; off < 256; off <<= 1) {
        int t = (tid >= off) ? s[tid - off] : 0;
        __syncthreads();
        s[tid] += t;
        __syncthreads();
    }
    if (i < n) local[i] = s[tid] - v;      // exclusive within block
    if (tid == 255) bsum[blockIdx.x] = s[255];
}

__global__ void scan2_kernel(int* __restrict__ bsum, int nb) {
    __shared__ int s[256];
    int tid = threadIdx.x;
    int v = (tid < nb) ? bsum[tid] : 0;
    s[tid] = v;
    __syncthreads();
    for (int off = 1; off < 256; off <<= 1) {
        int t = (tid >= off) ? s[tid - off] : 0;
        __syncthreads();
        s[tid] += t;
        __syncthreads();
    }
    if (tid < nb) bsum[tid] = s[tid] - v;  // exclusive
    if (tid == 255) bsum[nb] = s[255];     // total
}

__global__ void scan3_kernel(const int* __restrict__ bsum, int* __restrict__ row_ptr,
                             int* __restrict__ cursor, int n, int nb) {
    int i = blockIdx.x * 256 + threadIdx.x;
    if (i < n) {
        int r = row_ptr[i] + bsum[blockIdx.x];
        row_ptr[i] = r;
        cursor[i] = r;
    }
    if (i == 0) row_ptr[n] = bsum[nb];
}

__global__ void scatter_kernel(const int* __restrict__ src, const int* __restrict__ dst,
                               int* __restrict__ cursor, int* __restrict__ csr_src, int e) {
    int i = blockIdx.x * blockDim.x + threadIdx.x;
    if (i < e) {
        int p = atomicAdd(&cursor[dst[i]], 1);
        csr_src[p] = src[i];
    }
}

// ------------- weight cast (bf16, permuted frag order) + x cast ---------
// 256-col: off = (k>>5)*8192 + (n>>4)*512 + ((k>>3)&3)*128 + (n&15)*8 + (k&7)
// head (64-col padded from 47): off = (k>>5)*2048 + same inner
// tail region: x[NN*128] f32 -> bf16 row-major (float4 granularity)
__global__ void wcast_all_kernel(
    const float* __restrict__ c0W, const float* __restrict__ s0W,
    const float* __restrict__ c1W, const float* __restrict__ s1W,
    const float* __restrict__ m1W, const float* __restrict__ W2,
    const float* __restrict__ x,
    unsigned short* __restrict__ c0h, unsigned short* __restrict__ s0h,
    unsigned short* __restrict__ c1h, unsigned short* __restrict__ s1h,
    unsigned short* __restrict__ m1h, unsigned short* __restrict__ hWh,
    unsigned short* __restrict__ xh) {
    int i = blockIdx.x * blockDim.x + threadIdx.x;
    if (i >= 278528) {
        int j = i - 278528;               // float4 index into x
        if (j >= NN * 128 / 4) return;
        float4 v = ((const float4*)x)[j];
        short4v h;
        h[0] = (short)f2bf(v.x); h[1] = (short)f2bf(v.y);
        h[2] = (short)f2bf(v.z); h[3] = (short)f2bf(v.w);
        *(short4v*)&xh[j * 4] = h;
        return;
    }
    const float* W; unsigned short* H; int base; int head = 0;
    if (i < 32768)        { W = c0W; H = c0h; base = i; }
    else if (i < 65536)   { W = s0W; H = s0h; base = i - 32768; }
    else if (i < 131072)  { W = c1W; H = c1h; base = i - 65536; }
    else if (i < 196608)  { W = s1W; H = s1h; base = i - 131072; }
    else if (i < 262144)  { W = m1W; H = m1h; base = i - 196608; }
    else                  { W = W2;  H = hWh; base = i - 262144; head = 1; }
    float x_; int off;
    if (!head) {
        int k = base >> 8, n = base & 255;
        x_ = W[base];
        off = (k >> 5) * 8192 + (n >> 4) * 512 + ((k >> 3) & 3) * 128 + (n & 15) * 8 + (k & 7);
    } else {
        int k = base >> 6, n = base & 63;
        x_ = (n < 47) ? W[k * 47 + n] : 0.f;
        off = (k >> 5) * 2048 + (n >> 4) * 512 + ((k >> 3) & 3) * 128 + (n & 15) * 8 + (k & 7);
    }
    H[off] = f2bf(x_);
}

// ------------- fused conv+skip GEMM (plain bf16, B direct from L2) -------
// zb = fp8(A@Wc) (+ fused attn scores), sraw = bf16(A@Ws).
// Tile 32 x 256, 4 waves; wave wid owns 32 rows x cols [wid*64,+64).
// A: LDS double-buffered, reg prefetch (threads 0..127), 1 barrier/K-step.
__global__ __launch_bounds__(256) void gemm_fused_kernel(
    const unsigned short* __restrict__ Ah,
    const unsigned short* __restrict__ Wc, const unsigned short* __restrict__ Ws,
    int M, int K,
    unsigned char* __restrict__ zb, unsigned short* __restrict__ sraw,
    const float* __restrict__ al, const float* __restrict__ ar,
    float* __restrict__ el, float* __restrict__ er) {
    __shared__ short sA[2][1024];   // 32x32 bf16, frag-ordered, dbuf

    int tid = threadIdx.x;
    int lane = tid & 63;
    int wid = tid >> 6;
    int m0 = blockIdx.x * 32;

    f32x4 accc[2][4], accs[2][4];
#pragma unroll
    for (int i = 0; i < 2; i++)
#pragma unroll
        for (int j = 0; j < 4; j++) {
            accc[i][j] = (f32x4){0.f, 0.f, 0.f, 0.f};
            accs[i][j] = (f32x4){0.f, 0.f, 0.f, 0.f};
        }

    bool stager = (tid < 128);
    int t7 = tid & 127;
    int r = t7 >> 2, kq = t7 & 3;
    int gr = m0 + r;
    size_t abase = (size_t)gr * K + kq * 8;
    int aoff = (r >> 4) * 512 + kq * 128 + (r & 15) * 8;

    int nkt = K >> 5;
    if (stager) {
        short8 sreg = zero8();
        if (gr < M) sreg = *(const short8*)(Ah + abase);
        *(short8*)(&sA[0][0] + aoff) = sreg;
    }
    __syncthreads();

    const unsigned short* bcp = Wc + (wid * 4) * 512 + lane * 8;
    const unsigned short* bsp = Ws + (wid * 4) * 512 + lane * 8;

    for (int kt = 0; kt < nkt; kt++) {
        short8 nreg = zero8();
        if (stager && kt + 1 < nkt && gr < M)
            nreg = *(const short8*)(Ah + abase + (size_t)(kt + 1) * 32);
        short8 bc[4], bs[4];
#pragma unroll
        for (int nf = 0; nf < 4; nf++) {
            bc[nf] = *(const short8*)(bcp + kt * 8192 + nf * 512);
            bs[nf] = *(const short8*)(bsp + kt * 8192 + nf * 512);
        }
        const short* cur = &sA[kt & 1][0];
        short8 ah[2];
#pragma unroll
        for (int mf = 0; mf < 2; mf++)
            ah[mf] = *(const short8*)(cur + mf * 512 + lane * 8);
#pragma unroll
        for (int nf = 0; nf < 4; nf++)
#pragma unroll
            for (int mf = 0; mf < 2; mf++) {
                accc[mf][nf] = __builtin_amdgcn_mfma_f32_16x16x32_bf16(ah[mf], bc[nf], accc[mf][nf], 0, 0, 0);
                accs[mf][nf] = __builtin_amdgcn_mfma_f32_16x16x32_bf16(ah[mf], bs[nf], accs[mf][nf], 0, 0, 0);
            }
        if (stager && kt + 1 < nkt)
            *(short8*)(&sA[(kt + 1) & 1][0] + aoff) = nreg;
        __syncthreads();
    }

    // ---- epilogue: C layout col=lane&15, row=(lane>>4)*4+reg ----
#pragma unroll
    for (int mf = 0; mf < 2; mf++) {
        int row0 = m0 + mf * 16 + (lane >> 4) * 4;
#pragma unroll
        for (int reg = 0; reg < 4; reg++) {
            int row = row0 + reg;
            if (row >= M) continue;
            size_t rb = (size_t)row * HID;
#pragma unroll
            for (int nf = 0; nf < 4; nf++) {
                int col = wid * 64 + nf * 16 + (lane & 15);
                zb[rb + col] = f2fp8(accc[mf][nf][reg]);
                sraw[rb + col] = f2bf(accs[mf][nf][reg]);
            }
        }
    }

    // ---- fused attention scores: wave wid == head wid ----
    {
        float alv[4], arv[4];
#pragma unroll
        for (int nf = 0; nf < 4; nf++) {
            int col = wid * 64 + nf * 16 + (lane & 15);
            alv[nf] = al[col];
            arv[nf] = ar[col];
        }
#pragma unroll
        for (int mf = 0; mf < 2; mf++) {
#pragma unroll
            for (int reg = 0; reg < 4; reg++) {
                float pl = 0.f, pr = 0.f;
#pragma unroll
                for (int nf = 0; nf < 4; nf++) {
                    pl = fmaf(accc[mf][nf][reg], alv[nf], pl);
                    pr = fmaf(accc[mf][nf][reg], arv[nf], pr);
                }
#pragma unroll
                for (int off = 8; off; off >>= 1) {
                    pl += __shfl_xor(pl, off);
                    pr += __shfl_xor(pr, off);
                }
                int row = m0 + mf * 16 + (lane >> 4) * 4 + reg;
                if ((lane & 15) == 0 && row < M) {
                    el[row * 4 + wid] = pl;
                    er[row * 4 + wid] = pr;
                }
            }
        }
    }
}

// ---------- GAT aggregate + fused skip/ELU (single pass, fp8 z) ----------
// one wave per dst node; lane owns features [lane*4, lane*4+4) (head = lane>>4)
// h = elu(agg_avg + conv_b + sraw + skip_b) -> bf16
__global__ __launch_bounds__(256) void aggregate_kernel(
    const int* __restrict__ row_ptr, const int* __restrict__ csr_src,
    const float4* __restrict__ el4, const float4* __restrict__ er4,
    const unsigned char* __restrict__ zb, const float* __restrict__ conv_b,
    const unsigned short* __restrict__ sraw, const float* __restrict__ skip_b,
    unsigned short* __restrict__ outh, int n) {
    __shared__ float s_w[4][NH][64];
    __shared__ int s_s[4][64];
    int wid = threadIdx.x >> 6;
    int lane = threadIdx.x & 63;
    int node = blockIdx.x * 4 + wid;
    if (node >= n) return;
    int rb = row_ptr[node];
    int deg = row_ptr[node + 1] - rb;
    float4 ern = er4[node];
    float er_h[NH] = {ern.x, ern.y, ern.z, ern.w};
    int myh = lane >> 4;
    int f0 = lane * 4;

    float4 acc = make_float4(0.f, 0.f, 0.f, 0.f);
    float wsum[NH] = {0.f, 0.f, 0.f, 0.f};

    for (int c = 0; c < deg; c += 64) {
        int i = c + lane;
        int cnt = min(64, deg - c);
        if (i < deg) {
            int s = csr_src[rb + i];
            s_s[wid][lane] = s;
            float4 elv = el4[s];
            float ev[NH] = {elv.x, elv.y, elv.z, elv.w};
#pragma unroll
            for (int h = 0; h < NH; h++) {
                float e = ev[h] + er_h[h];
                e = (e > 0.f) ? e : 0.2f * e;
                float ee = __expf(e);
                s_w[wid][h][lane] = ee;
                wsum[h] += ee;
            }
        }
        __builtin_amdgcn_wave_barrier();
#pragma unroll 2
        for (int e = 0; e < cnt; e++) {
            int s = s_s[wid][e];
            unsigned zu = *(const unsigned*)(zb + (size_t)s * HID + f0);
            float wgt = s_w[wid][myh][e];
            f32x2 lo = __builtin_amdgcn_cvt_pk_f32_fp8((int)zu, false);
            f32x2 hi = __builtin_amdgcn_cvt_pk_f32_fp8((int)zu, true);
            acc.x = fmaf(wgt, lo[0], acc.x);
            acc.y = fmaf(wgt, lo[1], acc.y);
            acc.z = fmaf(wgt, hi[0], acc.z);
            acc.w = fmaf(wgt, hi[1], acc.w);
        }
        __builtin_amdgcn_wave_barrier();
    }
    // reduce per-head denominators across the wave
#pragma unroll
    for (int h = 0; h < NH; h++)
#pragma unroll
        for (int off = 32; off; off >>= 1) wsum[h] += __shfl_xor(wsum[h], off);
    float inv = (wsum[myh] > 0.f) ? 1.f / wsum[myh] : 0.f;
    float4 cb = *(const float4*)(conv_b + f0);
    float4 sb = *(const float4*)(skip_b + f0);
    uint2 sv = *(const uint2*)(sraw + (size_t)node * HID + f0);
    union { unsigned u; float f; } s0, s1, s2, s3;
    s0.u = sv.x << 16; s1.u = sv.x & 0xffff0000u;
    s2.u = sv.y << 16; s3.u = sv.y & 0xffff0000u;
    float v0 = acc.x * inv + cb.x + s0.f + sb.x;
    float v1 = acc.y * inv + cb.y + s1.f + sb.y;
    float v2 = acc.z * inv + cb.z + s2.f + sb.z;
    float v3 = acc.w * inv + cb.w + s3.f + sb.w;
    v0 = (v0 > 0.f) ? v0 : expm1f(v0);
    v1 = (v1 > 0.f) ? v1 : expm1f(v1);
    v2 = (v2 > 0.f) ? v2 : expm1f(v2);
    v3 = (v3 > 0.f) ? v3 : expm1f(v3);
    short4v o;
    o[0] = (short)f2bf(v0); o[1] = (short)f2bf(v1);
    o[2] = (short)f2bf(v2); o[3] = (short)f2bf(v3);
    *(short4v*)(outh + (size_t)node * HID + f0) = o;
}

// ------------------------- MLP GEMM (plain bf16): relu(bn(A@W1+b1)) ------
__global__ __launch_bounds__(256) void gemm_bn_kernel(
    const unsigned short* __restrict__ Ah, const unsigned short* __restrict__ Bh_g,
    int M, int K, unsigned short* __restrict__ C,
    const float* __restrict__ bias, const float* __restrict__ g,
    const float* __restrict__ bt, const float* __restrict__ mean,
    const float* __restrict__ var) {
    __shared__ short sA[2][1024];
    int tid = threadIdx.x;
    int lane = tid & 63;
    int wid = tid >> 6;
    int m0 = blockIdx.x * 32;

    f32x4 acc[2][4];
#pragma unroll
    for (int i = 0; i < 2; i++)
#pragma unroll
        for (int j = 0; j < 4; j++) acc[i][j] = (f32x4){0.f, 0.f, 0.f, 0.f};

    bool stager = (tid < 128);
    int t7 = tid & 127;
    int r = t7 >> 2, kq = t7 & 3;
    int gr = m0 + r;
    size_t abase = (size_t)gr * K + kq * 8;
    int aoff = (r >> 4) * 512 + kq * 128 + (r & 15) * 8;

    int nkt = K >> 5;
    if (stager) {
        short8 sreg = zero8();
        if (gr < M) sreg = *(const short8*)(Ah + abase);
        *(short8*)(&sA[0][0] + aoff) = sreg;
    }
    __syncthreads();

    const unsigned short* bhp = Bh_g + (wid * 4) * 512 + lane * 8;

    for (int kt = 0; kt < nkt; kt++) {
        short8 nreg = zero8();
        if (stager && kt + 1 < nkt && gr < M)
            nreg = *(const short8*)(Ah + abase + (size_t)(kt + 1) * 32);
        short8 bh[4];
#pragma unroll
        for (int nf = 0; nf < 4; nf++)
            bh[nf] = *(const short8*)(bhp + kt * 8192 + nf * 512);
        const short* cur = &sA[kt & 1][0];
        short8 ah[2];
#pragma unroll
        for (int mf = 0; mf < 2; mf++)
            ah[mf] = *(const short8*)(cur + mf * 512 + lane * 8);
#pragma unroll
        for (int nf = 0; nf < 4; nf++)
#pragma unroll
            for (int mf = 0; mf < 2; mf++)
                acc[mf][nf] = __builtin_amdgcn_mfma_f32_16x16x32_bf16(ah[mf], bh[nf], acc[mf][nf], 0, 0, 0);
        if (stager && kt + 1 < nkt)
            *(short8*)(&sA[(kt + 1) & 1][0] + aoff) = nreg;
        __syncthreads();
    }

#pragma unroll
    for (int mf = 0; mf < 2; mf++) {
        int row0 = m0 + mf * 16 + (lane >> 4) * 4;
#pragma unroll
        for (int reg = 0; reg < 4; reg++) {
            int row = row0 + reg;
            if (row >= M) continue;
            size_t rb = (size_t)row * HID;
#pragma unroll
            for (int nf = 0; nf < 4; nf++) {
                int col = wid * 64 + nf * 16 + (lane & 15);
                float v = acc[mf][nf][reg];
                float s = g[col] * rsqrtf(var[col] + 1e-5f);
                v = (v + bias[col] - mean[col]) * s + bt[col];
                C[rb + col] = f2bf(fmaxf(v, 0.f));
            }
        }
    }
}

// ------------------------- MFMA head: logits + log_softmax ---------------
// Tile 64 rows, K=256; wave w = rows [w*16,w*16+16) x all 64 cols.
__global__ __launch_bounds__(256) void head_kernel(
    const unsigned short* __restrict__ Ah, const unsigned short* __restrict__ Bh_g,
    const float* __restrict__ b2, float* __restrict__ out, int M) {
    __shared__ short sA[2048];    // 64x32
    int tid = threadIdx.x;
    int lane = tid & 63;
    int wid = tid >> 6;
    int m0 = blockIdx.x * 64;

    f32x4 acc[4];
#pragma unroll
    for (int nf = 0; nf < 4; nf++) acc[nf] = (f32x4){0.f, 0.f, 0.f, 0.f};

    for (int kt = 0; kt < 8; kt++) {
        {
            int r = tid >> 2, kq = tid & 3;
            int gr = m0 + r;
            short8 h8 = zero8();
            if (gr < M) h8 = *(const short8*)(Ah + (size_t)gr * HID + kt * 32 + kq * 8);
            int off = (r >> 4) * 512 + kq * 128 + (r & 15) * 8;
            *(short8*)&sA[off] = h8;
        }
        __syncthreads();
        short8 ah = *(const short8*)&sA[wid * 512 + lane * 8];
#pragma unroll
        for (int nf = 0; nf < 4; nf++) {
            short8 bh = *(const short8*)(Bh_g + kt * 2048 + nf * 512 + lane * 8);
            acc[nf] = __builtin_amdgcn_mfma_f32_16x16x32_bf16(ah, bh, acc[nf], 0, 0, 0);
        }
        __syncthreads();
    }

    // fused log-softmax over 47 valid cols; row = m0+wid*16+(lane>>4)*4+reg
    int col0 = lane & 15;
    float bias_[4];
#pragma unroll
    for (int nf = 0; nf < 4; nf++) {
        int col = nf * 16 + col0;
        bias_[nf] = (col < 47) ? b2[col] : 0.f;
    }
#pragma unroll
    for (int reg = 0; reg < 4; reg++) {
        int row = m0 + wid * 16 + (lane >> 4) * 4 + reg;
        float lg[4];
        float mx = -INFINITY;
#pragma unroll
        for (int nf = 0; nf < 4; nf++) {
            int col = nf * 16 + col0;
            float v = acc[nf][reg] + bias_[nf];
            lg[nf] = v;
            if (col < 47) mx = fmaxf(mx, v);
        }
#pragma unroll
        for (int off = 8; off; off >>= 1) mx = fmaxf(mx, __shfl_xor(mx, off));
        float s = 0.f;
#pragma unroll
        for (int nf = 0; nf < 4; nf++) {
            int col = nf * 16 + col0;
            if (col < 47) s += __expf(lg[nf] - mx);
        }
#pragma unroll
        for (int off = 8; off; off >>= 1) s += __shfl_xor(s, off);
        float li = logf(s);
        if (row < M) {
#pragma unroll
            for (int nf = 0; nf < 3; nf++) {
                int col = nf * 16 + col0;
                if (col < 47) out[(size_t)row * 47 + col] = lg[nf] - mx - li;
            }
        }
    }
}

// ------------------------- launch -------------------------
extern "C" void kernel_launch(void* const* d_in, const int* in_sizes, int n_in,
                              void* d_out, int out_size, void* d_ws, size_t ws_size,
                              hipStream_t stream) {
    const float* x        = (const float*)d_in[0];
    const float* conv0_W  = (const float*)d_in[1];
    const float* conv0_al = (const float*)d_in[2];
    const float* conv0_ar = (const float*)d_in[3];
    const float* conv0_b  = (const float*)d_in[4];
    const float* skip0_W  = (const float*)d_in[5];
    const float* skip0_b  = (const float*)d_in[6];
    const float* conv1_W  = (const float*)d_in[7];
    const float* conv1_al = (const float*)d_in[8];
    const float* conv1_ar = (const float*)d_in[9];
    const float* conv1_b  = (const float*)d_in[10];
    const float* skip1_W  = (const float*)d_in[11];
    const float* skip1_b  = (const float*)d_in[12];
    const float* mlp_W1   = (const float*)d_in[13];
    const float* mlp_b1   = (const float*)d_in[14];
    const float* bn_gamma = (const float*)d_in[15];
    const float* bn_beta  = (const float*)d_in[16];
    const float* bn_mean  = (const float*)d_in[17];
    const float* bn_var   = (const float*)d_in[18];
    const float* mlp_W2   = (const float*)d_in[19];
    const float* mlp_b2   = (const float*)d_in[20];
    const int* edge_src   = (const int*)d_in[21];
    const int* edge_dst   = (const int*)d_in[22];
    float* out = (float*)d_out;

    // workspace carve-up (with aliasing)
    char* w = (char*)d_ws;
    size_t off = 0;
    auto alloc = [&](size_t bytes) {
        char* p = w + off;
        off += (bytes + 255) & ~(size_t)255;
        return p;
    };
    int*    row_ptr = (int*)alloc((NN + 1) * sizeof(int));
    int*    cursor  = (int*)alloc(NN * sizeof(int));
    int*    bsum    = (int*)alloc(512 * sizeof(int));
    int*    csr_src = (int*)alloc(NE * sizeof(int));
    float*  el      = (float*)alloc((size_t)NN * 4 * sizeof(float));
    float*  er      = (float*)alloc((size_t)NN * 4 * sizeof(float));
    unsigned char*  zb   = (unsigned char*)alloc((size_t)NN * HID * 2);   // fp8 z; later m (bf16)
    unsigned short* sraw = (unsigned short*)alloc((size_t)NN * HID * 2);  // skip raw bf16
    unsigned short* slA  = (unsigned short*)alloc((size_t)NN * HID * 2);  // xh then h2h
    unsigned short* hh   = (unsigned short*)alloc((size_t)NN * HID * 2);  // h
    unsigned short* c0h = (unsigned short*)alloc(128 * 256 * 2);
    unsigned short* s0h = (unsigned short*)alloc(128 * 256 * 2);
    unsigned short* c1h = (unsigned short*)alloc(256 * 256 * 2);
    unsigned short* s1h = (unsigned short*)alloc(256 * 256 * 2);
    unsigned short* m1h = (unsigned short*)alloc(256 * 256 * 2);
    unsigned short* hWh = (unsigned short*)alloc(256 * 64 * 2);
    (void)ws_size;

    unsigned short* xh  = slA;   // 50000x128 (half the slab)
    unsigned short* h2h = slA;   // alive after x is dead
    unsigned short* mh  = (unsigned short*)zb;  // alive after zb is dead

    int gemm_grid = cdiv(NN, 32);      // 1563 blocks, 32-row tiles
    int head_grid = cdiv(NN, 64);
    int nodeblocks = cdiv(NN, 4);
    int scan_blocks = cdiv(NN, 256);

    // weight cast + x cast (single launch)
    wcast_all_kernel<<<cdiv(278528 + NN * 128 / 4, 256), 256, 0, stream>>>(
        conv0_W, skip0_W, conv1_W, skip1_W, mlp_W1, mlp_W2, x,
        c0h, s0h, c1h, s1h, m1h, hWh, xh);

    // CSR build (shared by both layers) — parallel two-level scan
    hipMemsetAsync(cursor, 0, NN * sizeof(int), stream);
    hist_kernel<<<cdiv(NE, 256), 256, 0, stream>>>(edge_dst, cursor, NE);
    scan1_kernel<<<scan_blocks, 256, 0, stream>>>(cursor, row_ptr, bsum, NN);
    scan2_kernel<<<1, 256, 0, stream>>>(bsum, scan_blocks);
    scan3_kernel<<<scan_blocks, 256, 0, stream>>>(bsum, row_ptr, cursor, NN, scan_blocks);
    scatter_kernel<<<cdiv(NE, 256), 256, 0, stream>>>(edge_src, edge_dst, cursor, csr_src, NE);

    // layer 0: fused conv+skip GEMM, then aggregate(+skip+ELU) -> h
    gemm_fused_kernel<<<gemm_grid, 256, 0, stream>>>(xh, c0h, s0h, NN, 128,
        zb, sraw, conv0_al, conv0_ar, el, er);
    aggregate_kernel<<<nodeblocks, 256, 0, stream>>>(row_ptr, csr_src,
        (const float4*)el, (const float4*)er, zb, conv0_b, sraw, skip0_b, hh, NN);

    // layer 1 (h2h aliases slA; xh dead after layer-0 gemm)
    gemm_fused_kernel<<<gemm_grid, 256, 0, stream>>>(hh, c1h, s1h, NN, 256,
        zb, sraw, conv1_al, conv1_ar, el, er);
    aggregate_kernel<<<nodeblocks, 256, 0, stream>>>(row_ptr, csr_src,
        (const float4*)el, (const float4*)er, zb, conv1_b, sraw, skip1_b, h2h, NN);

    // MLP head: m = relu(bn(h2 @ W1 + b1));  (mh aliases zb, dead now)
    gemm_bn_kernel<<<gemm_grid, 256, 0, stream>>>(h2h, m1h, NN, 256,
        mh, mlp_b1, bn_gamma, bn_beta, bn_mean, bn_var);
    head_kernel<<<head_grid, 256, 0, stream>>>(mh, hWh, mlp_b2, out, NN);
}

// Round 10
// 246.356 us; speedup vs baseline: 4.3450x; 1.2337x over previous
//
#include <hip/hip_runtime.h>
#include <math.h>

#define NN 50000
#define NE 800000
#define HID 256
#define NH 4
#define DH 64
#define NB 196          // dst buckets (dst >> 8), 256 dst each
#define CHUNK 4082      // cdiv(NE, NB)

static inline int cdiv(int a, int b) { return (a + b - 1) / b; }

typedef __attribute__((ext_vector_type(8))) short short8;
typedef __attribute__((ext_vector_type(4))) short short4v;
typedef __attribute__((ext_vector_type(4))) float f32x4;
typedef __attribute__((ext_vector_type(2))) float f32x2;

// bf16 helpers (round-to-nearest-even)
__device__ inline unsigned short f2bf(float x) {
    union { float f; unsigned u; } v; v.f = x;
    unsigned r = v.u + 0x7FFFu + ((v.u >> 16) & 1u);
    return (unsigned short)(r >> 16);
}
__device__ inline float bf2f(unsigned short h) {
    union { unsigned u; float f; } v; v.u = ((unsigned)h) << 16;
    return v.f;
}
__device__ inline short8 zero8() {
    short8 z;
#pragma unroll
    for (int j = 0; j < 8; j++) z[j] = 0;
    return z;
}
// fp8 e4m3 (OCP) encode via HW convert
__device__ inline unsigned char f2fp8(float x) {
    int p = __builtin_amdgcn_cvt_pk_fp8_f32(x, 0.f, 0, false);
    return (unsigned char)(p & 0xff);
}

// ------------------- CSR build: bucketed, XCD-local writes ---------------
// P1: bucket histogram (bucket = dst>>8)
__global__ __launch_bounds__(256) void p1_bucket_hist(const int* __restrict__ dst,
                                                      int* __restrict__ bcount) {
    __shared__ int h[NB];
    int tid = threadIdx.x;
    for (int i = tid; i < NB; i += 256) h[i] = 0;
    __syncthreads();
    int i0 = blockIdx.x * CHUNK;
    int n = min(CHUNK, NE - i0);
    for (int i = tid; i < n; i += 256) atomicAdd(&h[dst[i0 + i] >> 8], 1);
    __syncthreads();
    for (int i = tid; i < NB; i += 256)
        if (h[i]) atomicAdd(&bcount[i], h[i]);
}

// P2: exclusive scan of bucket counts -> bbase[NB+1]; init gcur
__global__ __launch_bounds__(256) void p2_bucket_scan(const int* __restrict__ bcount,
                                                      int* __restrict__ bbase,
                                                      int* __restrict__ gcur) {
    __shared__ int s[256];
    int tid = threadIdx.x;
    int v = (tid < NB) ? bcount[tid] : 0;
    s[tid] = v;
    __syncthreads();
    for (int off = 1; off < 256; off <<= 1) {
        int t = (tid >= off) ? s[tid - off] : 0;
        __syncthreads();
        s[tid] += t;
        __syncthreads();
    }
    int ex = s[tid] - v;
    if (tid < NB) { bbase[tid] = ex; gcur[tid] = ex; }
    if (tid == NB - 1) bbase[NB] = s[tid];   // == NE
}

// P3: partition edges into bucket-major ebuf[(src,dst)] with coalesced runs
__global__ __launch_bounds__(256) void p3_partition(
    const int* __restrict__ src, const int* __restrict__ dst,
    int* __restrict__ gcur, uint2* __restrict__ ebuf) {
    __shared__ int cnt[NB], loff[NB], cur[NB], gpos[NB];
    __shared__ int s[256];
    __shared__ uint2 buf[CHUNK];
    int tid = threadIdx.x;
    int i0 = blockIdx.x * CHUNK;
    int n = min(CHUNK, NE - i0);
    for (int i = tid; i < NB; i += 256) cnt[i] = 0;
    __syncthreads();
    for (int i = tid; i < n; i += 256) atomicAdd(&cnt[dst[i0 + i] >> 8], 1);
    __syncthreads();
    // exclusive scan of cnt -> loff; reserve global ranges
    int v = (tid < NB) ? cnt[tid] : 0;
    s[tid] = v;
    __syncthreads();
    for (int off = 1; off < 256; off <<= 1) {
        int t = (tid >= off) ? s[tid - off] : 0;
        __syncthreads();
        s[tid] += t;
        __syncthreads();
    }
    if (tid < NB) {
        int ex = s[tid] - v;
        loff[tid] = ex;
        cur[tid] = ex;
        gpos[tid] = v ? atomicAdd(&gcur[tid], v) : 0;
    }
    __syncthreads();
    // bucket-group edges into LDS
    for (int i = tid; i < n; i += 256) {
        int d = dst[i0 + i];
        int sv = src[i0 + i];
        int p = atomicAdd(&cur[d >> 8], 1);
        buf[p] = make_uint2((unsigned)sv, (unsigned)d);
    }
    __syncthreads();
    // copy out: contiguous per-bucket runs
    for (int i = tid; i < n; i += 256) {
        uint2 e = buf[i];
        int b = (int)(e.y >> 8);
        ebuf[gpos[b] + (i - loff[b])] = e;
    }
}

// P4: per-bucket local CSR (LDS hist+scan), block-exclusive csr region
__global__ __launch_bounds__(256) void p4_bucket_csr(
    const uint2* __restrict__ ebuf, const int* __restrict__ bbase,
    int* __restrict__ row_ptr, int* __restrict__ csr_src) {
    __shared__ int hist[256], cur[256], s[256];
    int b = blockIdx.x;
    int tid = threadIdx.x;
    int e0 = bbase[b], e1 = bbase[b + 1];
    hist[tid] = 0;
    __syncthreads();
    for (int i = e0 + tid; i < e1; i += 256)
        atomicAdd(&hist[ebuf[i].y & 255], 1);
    __syncthreads();
    int v = hist[tid];
    s[tid] = v;
    __syncthreads();
    for (int off = 1; off < 256; off <<= 1) {
        int t = (tid >= off) ? s[tid - off] : 0;
        __syncthreads();
        s[tid] += t;
        __syncthreads();
    }
    int pre = s[tid] - v;
    cur[tid] = pre;
    int d = b * 256 + tid;
    if (d < NN) row_ptr[d] = e0 + pre;
    if (b == NB - 1 && tid == 0) row_ptr[NN] = NE;
    __syncthreads();
    for (int i = e0 + tid; i < e1; i += 256) {
        uint2 e = ebuf[i];
        int p = atomicAdd(&cur[e.y & 255], 1);
        csr_src[e0 + p] = (int)e.x;
    }
}

// ------------- weight cast (bf16, permuted frag order) + x cast ---------
// 256-col: off = (k>>5)*8192 + (n>>4)*512 + ((k>>3)&3)*128 + (n&15)*8 + (k&7)
// head (64-col padded from 47): off = (k>>5)*2048 + same inner
// tail region: x[NN*128] f32 -> bf16 row-major (float4 granularity)
__global__ void wcast_all_kernel(
    const float* __restrict__ c0W, const float* __restrict__ s0W,
    const float* __restrict__ c1W, const float* __restrict__ s1W,
    const float* __restrict__ m1W, const float* __restrict__ W2,
    const float* __restrict__ x,
    unsigned short* __restrict__ c0h, unsigned short* __restrict__ s0h,
    unsigned short* __restrict__ c1h, unsigned short* __restrict__ s1h,
    unsigned short* __restrict__ m1h, unsigned short* __restrict__ hWh,
    unsigned short* __restrict__ xh) {
    int i = blockIdx.x * blockDim.x + threadIdx.x;
    if (i >= 278528) {
        int j = i - 278528;               // float4 index into x
        if (j >= NN * 128 / 4) return;
        float4 v = ((const float4*)x)[j];
        short4v h;
        h[0] = (short)f2bf(v.x); h[1] = (short)f2bf(v.y);
        h[2] = (short)f2bf(v.z); h[3] = (short)f2bf(v.w);
        *(short4v*)&xh[j * 4] = h;
        return;
    }
    const float* W; unsigned short* H; int base; int head = 0;
    if (i < 32768)        { W = c0W; H = c0h; base = i; }
    else if (i < 65536)   { W = s0W; H = s0h; base = i - 32768; }
    else if (i < 131072)  { W = c1W; H = c1h; base = i - 65536; }
    else if (i < 196608)  { W = s1W; H = s1h; base = i - 131072; }
    else if (i < 262144)  { W = m1W; H = m1h; base = i - 196608; }
    else                  { W = W2;  H = hWh; base = i - 262144; head = 1; }
    float x_; int off;
    if (!head) {
        int k = base >> 8, n = base & 255;
        x_ = W[base];
        off = (k >> 5) * 8192 + (n >> 4) * 512 + ((k >> 3) & 3) * 128 + (n & 15) * 8 + (k & 7);
    } else {
        int k = base >> 6, n = base & 63;
        x_ = (n < 47) ? W[k * 47 + n] : 0.f;
        off = (k >> 5) * 2048 + (n >> 4) * 512 + ((k >> 3) & 3) * 128 + (n & 15) * 8 + (k & 7);
    }
    H[off] = f2bf(x_);
}

// ------------- fused conv+skip GEMM (plain bf16, B direct from L2) -------
// zb = fp8(A@Wc) (+ fused attn scores), sraw = bf16(A@Ws).
// Tile 32 x 256, 4 waves; wave wid owns 32 rows x cols [wid*64,+64).
// A: LDS double-buffered, reg prefetch (threads 0..127), 1 barrier/K-step.
__global__ __launch_bounds__(256) void gemm_fused_kernel(
    const unsigned short* __restrict__ Ah,
    const unsigned short* __restrict__ Wc, const unsigned short* __restrict__ Ws,
    int M, int K,
    unsigned char* __restrict__ zb, unsigned short* __restrict__ sraw,
    const float* __restrict__ al, const float* __restrict__ ar,
    float* __restrict__ el, float* __restrict__ er) {
    __shared__ short sA[2][1024];   // 32x32 bf16, frag-ordered, dbuf

    int tid = threadIdx.x;
    int lane = tid & 63;
    int wid = tid >> 6;
    int m0 = blockIdx.x * 32;

    f32x4 accc[2][4], accs[2][4];
#pragma unroll
    for (int i = 0; i < 2; i++)
#pragma unroll
        for (int j = 0; j < 4; j++) {
            accc[i][j] = (f32x4){0.f, 0.f, 0.f, 0.f};
            accs[i][j] = (f32x4){0.f, 0.f, 0.f, 0.f};
        }

    bool stager = (tid < 128);
    int t7 = tid & 127;
    int r = t7 >> 2, kq = t7 & 3;
    int gr = m0 + r;
    size_t abase = (size_t)gr * K + kq * 8;
    int aoff = (r >> 4) * 512 + kq * 128 + (r & 15) * 8;

    int nkt = K >> 5;
    if (stager) {
        short8 sreg = zero8();
        if (gr < M) sreg = *(const short8*)(Ah + abase);
        *(short8*)(&sA[0][0] + aoff) = sreg;
    }
    __syncthreads();

    const unsigned short* bcp = Wc + (wid * 4) * 512 + lane * 8;
    const unsigned short* bsp = Ws + (wid * 4) * 512 + lane * 8;

    for (int kt = 0; kt < nkt; kt++) {
        short8 nreg = zero8();
        if (stager && kt + 1 < nkt && gr < M)
            nreg = *(const short8*)(Ah + abase + (size_t)(kt + 1) * 32);
        short8 bc[4], bs[4];
#pragma unroll
        for (int nf = 0; nf < 4; nf++) {
            bc[nf] = *(const short8*)(bcp + kt * 8192 + nf * 512);
            bs[nf] = *(const short8*)(bsp + kt * 8192 + nf * 512);
        }
        const short* cur = &sA[kt & 1][0];
        short8 ah[2];
#pragma unroll
        for (int mf = 0; mf < 2; mf++)
            ah[mf] = *(const short8*)(cur + mf * 512 + lane * 8);
#pragma unroll
        for (int nf = 0; nf < 4; nf++)
#pragma unroll
            for (int mf = 0; mf < 2; mf++) {
                accc[mf][nf] = __builtin_amdgcn_mfma_f32_16x16x32_bf16(ah[mf], bc[nf], accc[mf][nf], 0, 0, 0);
                accs[mf][nf] = __builtin_amdgcn_mfma_f32_16x16x32_bf16(ah[mf], bs[nf], accs[mf][nf], 0, 0, 0);
            }
        if (stager && kt + 1 < nkt)
            *(short8*)(&sA[(kt + 1) & 1][0] + aoff) = nreg;
        __syncthreads();
    }

    // ---- epilogue: C layout col=lane&15, row=(lane>>4)*4+reg ----
#pragma unroll
    for (int mf = 0; mf < 2; mf++) {
        int row0 = m0 + mf * 16 + (lane >> 4) * 4;
#pragma unroll
        for (int reg = 0; reg < 4; reg++) {
            int row = row0 + reg;
            if (row >= M) continue;
            size_t rb = (size_t)row * HID;
#pragma unroll
            for (int nf = 0; nf < 4; nf++) {
                int col = wid * 64 + nf * 16 + (lane & 15);
                zb[rb + col] = f2fp8(accc[mf][nf][reg]);
                sraw[rb + col] = f2bf(accs[mf][nf][reg]);
            }
        }
    }

    // ---- fused attention scores: wave wid == head wid ----
    {
        float alv[4], arv[4];
#pragma unroll
        for (int nf = 0; nf < 4; nf++) {
            int col = wid * 64 + nf * 16 + (lane & 15);
            alv[nf] = al[col];
            arv[nf] = ar[col];
        }
#pragma unroll
        for (int mf = 0; mf < 2; mf++) {
#pragma unroll
            for (int reg = 0; reg < 4; reg++) {
                float pl = 0.f, pr = 0.f;
#pragma unroll
                for (int nf = 0; nf < 4; nf++) {
                    pl = fmaf(accc[mf][nf][reg], alv[nf], pl);
                    pr = fmaf(accc[mf][nf][reg], arv[nf], pr);
                }
#pragma unroll
                for (int off = 8; off; off >>= 1) {
                    pl += __shfl_xor(pl, off);
                    pr += __shfl_xor(pr, off);
                }
                int row = m0 + mf * 16 + (lane >> 4) * 4 + reg;
                if ((lane & 15) == 0 && row < M) {
                    el[row * 4 + wid] = pl;
                    er[row * 4 + wid] = pr;
                }
            }
        }
    }
}

// ---------- GAT aggregate + fused skip/ELU (single pass, fp8 z) ----------
// one wave per dst node; lane owns features [lane*4, lane*4+4) (head = lane>>4)
// h = elu(agg_avg + conv_b + sraw + skip_b) -> bf16
__global__ __launch_bounds__(256) void aggregate_kernel(
    const int* __restrict__ row_ptr, const int* __restrict__ csr_src,
    const float4* __restrict__ el4, const float4* __restrict__ er4,
    const unsigned char* __restrict__ zb, const float* __restrict__ conv_b,
    const unsigned short* __restrict__ sraw, const float* __restrict__ skip_b,
    unsigned short* __restrict__ outh, int n) {
    __shared__ float s_w[4][NH][64];
    __shared__ int s_s[4][64];
    int wid = threadIdx.x >> 6;
    int lane = threadIdx.x & 63;
    int node = blockIdx.x * 4 + wid;
    if (node >= n) return;
    int rb = row_ptr[node];
    int deg = row_ptr[node + 1] - rb;
    float4 ern = er4[node];
    float er_h[NH] = {ern.x, ern.y, ern.z, ern.w};
    int myh = lane >> 4;
    int f0 = lane * 4;

    float4 acc = make_float4(0.f, 0.f, 0.f, 0.f);
    float wsum[NH] = {0.f, 0.f, 0.f, 0.f};

    for (int c = 0; c < deg; c += 64) {
        int i = c + lane;
        int cnt = min(64, deg - c);
        if (i < deg) {
            int s = csr_src[rb + i];
            s_s[wid][lane] = s;
            float4 elv = el4[s];
            float ev[NH] = {elv.x, elv.y, elv.z, elv.w};
#pragma unroll
            for (int h = 0; h < NH; h++) {
                float e = ev[h] + er_h[h];
                e = (e > 0.f) ? e : 0.2f * e;
                float ee = __expf(e);
                s_w[wid][h][lane] = ee;
                wsum[h] += ee;
            }
        }
        __builtin_amdgcn_wave_barrier();
#pragma unroll 2
        for (int e = 0; e < cnt; e++) {
            int s = s_s[wid][e];
            unsigned zu = *(const unsigned*)(zb + (size_t)s * HID + f0);
            float wgt = s_w[wid][myh][e];
            f32x2 lo = __builtin_amdgcn_cvt_pk_f32_fp8((int)zu, false);
            f32x2 hi = __builtin_amdgcn_cvt_pk_f32_fp8((int)zu, true);
            acc.x = fmaf(wgt, lo[0], acc.x);
            acc.y = fmaf(wgt, lo[1], acc.y);
            acc.z = fmaf(wgt, hi[0], acc.z);
            acc.w = fmaf(wgt, hi[1], acc.w);
        }
        __builtin_amdgcn_wave_barrier();
    }
    // reduce per-head denominators across the wave
#pragma unroll
    for (int h = 0; h < NH; h++)
#pragma unroll
        for (int off = 32; off; off >>= 1) wsum[h] += __shfl_xor(wsum[h], off);
    float inv = (wsum[myh] > 0.f) ? 1.f / wsum[myh] : 0.f;
    float4 cb = *(const float4*)(conv_b + f0);
    float4 sb = *(const float4*)(skip_b + f0);
    uint2 sv = *(const uint2*)(sraw + (size_t)node * HID + f0);
    union { unsigned u; float f; } s0, s1, s2, s3;
    s0.u = sv.x << 16; s1.u = sv.x & 0xffff0000u;
    s2.u = sv.y << 16; s3.u = sv.y & 0xffff0000u;
    float v0 = acc.x * inv + cb.x + s0.f + sb.x;
    float v1 = acc.y * inv + cb.y + s1.f + sb.y;
    float v2 = acc.z * inv + cb.z + s2.f + sb.z;
    float v3 = acc.w * inv + cb.w + s3.f + sb.w;
    v0 = (v0 > 0.f) ? v0 : expm1f(v0);
    v1 = (v1 > 0.f) ? v1 : expm1f(v1);
    v2 = (v2 > 0.f) ? v2 : expm1f(v2);
    v3 = (v3 > 0.f) ? v3 : expm1f(v3);
    short4v o;
    o[0] = (short)f2bf(v0); o[1] = (short)f2bf(v1);
    o[2] = (short)f2bf(v2); o[3] = (short)f2bf(v3);
    *(short4v*)(outh + (size_t)node * HID + f0) = o;
}

// ------------------------- MLP GEMM (plain bf16): relu(bn(A@W1+b1)) ------
__global__ __launch_bounds__(256) void gemm_bn_kernel(
    const unsigned short* __restrict__ Ah, const unsigned short* __restrict__ Bh_g,
    int M, int K, unsigned short* __restrict__ C,
    const float* __restrict__ bias, const float* __restrict__ g,
    const float* __restrict__ bt, const float* __restrict__ mean,
    const float* __restrict__ var) {
    __shared__ short sA[2][1024];
    int tid = threadIdx.x;
    int lane = tid & 63;
    int wid = tid >> 6;
    int m0 = blockIdx.x * 32;

    f32x4 acc[2][4];
#pragma unroll
    for (int i = 0; i < 2; i++)
#pragma unroll
        for (int j = 0; j < 4; j++) acc[i][j] = (f32x4){0.f, 0.f, 0.f, 0.f};

    bool stager = (tid < 128);
    int t7 = tid & 127;
    int r = t7 >> 2, kq = t7 & 3;
    int gr = m0 + r;
    size_t abase = (size_t)gr * K + kq * 8;
    int aoff = (r >> 4) * 512 + kq * 128 + (r & 15) * 8;

    int nkt = K >> 5;
    if (stager) {
        short8 sreg = zero8();
        if (gr < M) sreg = *(const short8*)(Ah + abase);
        *(short8*)(&sA[0][0] + aoff) = sreg;
    }
    __syncthreads();

    const unsigned short* bhp = Bh_g + (wid * 4) * 512 + lane * 8;

    for (int kt = 0; kt < nkt; kt++) {
        short8 nreg = zero8();
        if (stager && kt + 1 < nkt && gr < M)
            nreg = *(const short8*)(Ah + abase + (size_t)(kt + 1) * 32);
        short8 bh[4];
#pragma unroll
        for (int nf = 0; nf < 4; nf++)
            bh[nf] = *(const short8*)(bhp + kt * 8192 + nf * 512);
        const short* cur = &sA[kt & 1][0];
        short8 ah[2];
#pragma unroll
        for (int mf = 0; mf < 2; mf++)
            ah[mf] = *(const short8*)(cur + mf * 512 + lane * 8);
#pragma unroll
        for (int nf = 0; nf < 4; nf++)
#pragma unroll
            for (int mf = 0; mf < 2; mf++)
                acc[mf][nf] = __builtin_amdgcn_mfma_f32_16x16x32_bf16(ah[mf], bh[nf], acc[mf][nf], 0, 0, 0);
        if (stager && kt + 1 < nkt)
            *(short8*)(&sA[(kt + 1) & 1][0] + aoff) = nreg;
        __syncthreads();
    }

#pragma unroll
    for (int mf = 0; mf < 2; mf++) {
        int row0 = m0 + mf * 16 + (lane >> 4) * 4;
#pragma unroll
        for (int reg = 0; reg < 4; reg++) {
            int row = row0 + reg;
            if (row >= M) continue;
            size_t rb = (size_t)row * HID;
#pragma unroll
            for (int nf = 0; nf < 4; nf++) {
                int col = wid * 64 + nf * 16 + (lane & 15);
                float v = acc[mf][nf][reg];
                float s = g[col] * rsqrtf(var[col] + 1e-5f);
                v = (v + bias[col] - mean[col]) * s + bt[col];
                C[rb + col] = f2bf(fmaxf(v, 0.f));
            }
        }
    }
}

// ------------------------- MFMA head: logits + log_softmax ---------------
// Tile 64 rows, K=256; wave w = rows [w*16,w*16+16) x all 64 cols.
__global__ __launch_bounds__(256) void head_kernel(
    const unsigned short* __restrict__ Ah, const unsigned short* __restrict__ Bh_g,
    const float* __restrict__ b2, float* __restrict__ out, int M) {
    __shared__ short sA[2048];    // 64x32
    int tid = threadIdx.x;
    int lane = tid & 63;
    int wid = tid >> 6;
    int m0 = blockIdx.x * 64;

    f32x4 acc[4];
#pragma unroll
    for (int nf = 0; nf < 4; nf++) acc[nf] = (f32x4){0.f, 0.f, 0.f, 0.f};

    for (int kt = 0; kt < 8; kt++) {
        {
            int r = tid >> 2, kq = tid & 3;
            int gr = m0 + r;
            short8 h8 = zero8();
            if (gr < M) h8 = *(const short8*)(Ah + (size_t)gr * HID + kt * 32 + kq * 8);
            int off = (r >> 4) * 512 + kq * 128 + (r & 15) * 8;
            *(short8*)&sA[off] = h8;
        }
        __syncthreads();
        short8 ah = *(const short8*)&sA[wid * 512 + lane * 8];
#pragma unroll
        for (int nf = 0; nf < 4; nf++) {
            short8 bh = *(const short8*)(Bh_g + kt * 2048 + nf * 512 + lane * 8);
            acc[nf] = __builtin_amdgcn_mfma_f32_16x16x32_bf16(ah, bh, acc[nf], 0, 0, 0);
        }
        __syncthreads();
    }

    // fused log-softmax over 47 valid cols; row = m0+wid*16+(lane>>4)*4+reg
    int col0 = lane & 15;
    float bias_[4];
#pragma unroll
    for (int nf = 0; nf < 4; nf++) {
        int col = nf * 16 + col0;
        bias_[nf] = (col < 47) ? b2[col] : 0.f;
    }
#pragma unroll
    for (int reg = 0; reg < 4; reg++) {
        int row = m0 + wid * 16 + (lane >> 4) * 4 + reg;
        float lg[4];
        float mx = -INFINITY;
#pragma unroll
        for (int nf = 0; nf < 4; nf++) {
            int col = nf * 16 + col0;
            float v = acc[nf][reg] + bias_[nf];
            lg[nf] = v;
            if (col < 47) mx = fmaxf(mx, v);
        }
#pragma unroll
        for (int off = 8; off; off >>= 1) mx = fmaxf(mx, __shfl_xor(mx, off));
        float s = 0.f;
#pragma unroll
        for (int nf = 0; nf < 4; nf++) {
            int col = nf * 16 + col0;
            if (col < 47) s += __expf(lg[nf] - mx);
        }
#pragma unroll
        for (int off = 8; off; off >>= 1) s += __shfl_xor(s, off);
        float li = logf(s);
        if (row < M) {
#pragma unroll
            for (int nf = 0; nf < 3; nf++) {
                int col = nf * 16 + col0;
                if (col < 47) out[(size_t)row * 47 + col] = lg[nf] - mx - li;
            }
        }
    }
}

// ------------------------- launch -------------------------
extern "C" void kernel_launch(void* const* d_in, const int* in_sizes, int n_in,
                              void* d_out, int out_size, void* d_ws, size_t ws_size,
                              hipStream_t stream) {
    const float* x        = (const float*)d_in[0];
    const float* conv0_W  = (const float*)d_in[1];
    const float* conv0_al = (const float*)d_in[2];
    const float* conv0_ar = (const float*)d_in[3];
    const float* conv0_b  = (const float*)d_in[4];
    const float* skip0_W  = (const float*)d_in[5];
    const float* skip0_b  = (const float*)d_in[6];
    const float* conv1_W  = (const float*)d_in[7];
    const float* conv1_al = (const float*)d_in[8];
    const float* conv1_ar = (const float*)d_in[9];
    const float* conv1_b  = (const float*)d_in[10];
    const float* skip1_W  = (const float*)d_in[11];
    const float* skip1_b  = (const float*)d_in[12];
    const float* mlp_W1   = (const float*)d_in[13];
    const float* mlp_b1   = (const float*)d_in[14];
    const float* bn_gamma = (const float*)d_in[15];
    const float* bn_beta  = (const float*)d_in[16];
    const float* bn_mean  = (const float*)d_in[17];
    const float* bn_var   = (const float*)d_in[18];
    const float* mlp_W2   = (const float*)d_in[19];
    const float* mlp_b2   = (const float*)d_in[20];
    const int* edge_src   = (const int*)d_in[21];
    const int* edge_dst   = (const int*)d_in[22];
    float* out = (float*)d_out;

    // workspace carve-up (with aliasing)
    char* w = (char*)d_ws;
    size_t off = 0;
    auto alloc = [&](size_t bytes) {
        char* p = w + off;
        off += (bytes + 255) & ~(size_t)255;
        return p;
    };
    int*    row_ptr = (int*)alloc((NN + 1) * sizeof(int));
    int*    bcount  = (int*)alloc(256 * sizeof(int));
    int*    bbase   = (int*)alloc(256 * sizeof(int));
    int*    gcur    = (int*)alloc(256 * sizeof(int));
    int*    csr_src = (int*)alloc(NE * sizeof(int));
    uint2*  ebuf    = (uint2*)alloc((size_t)NE * sizeof(uint2));
    float*  el      = (float*)alloc((size_t)NN * 4 * sizeof(float));
    float*  er      = (float*)alloc((size_t)NN * 4 * sizeof(float));
    unsigned char*  zb   = (unsigned char*)alloc((size_t)NN * HID * 2);   // fp8 z; later m (bf16)
    unsigned short* sraw = (unsigned short*)alloc((size_t)NN * HID * 2);  // skip raw bf16
    unsigned short* slA  = (unsigned short*)alloc((size_t)NN * HID * 2);  // xh then h2h
    unsigned short* hh   = (unsigned short*)alloc((size_t)NN * HID * 2);  // h
    unsigned short* c0h = (unsigned short*)alloc(128 * 256 * 2);
    unsigned short* s0h = (unsigned short*)alloc(128 * 256 * 2);
    unsigned short* c1h = (unsigned short*)alloc(256 * 256 * 2);
    unsigned short* s1h = (unsigned short*)alloc(256 * 256 * 2);
    unsigned short* m1h = (unsigned short*)alloc(256 * 256 * 2);
    unsigned short* hWh = (unsigned short*)alloc(256 * 64 * 2);
    (void)ws_size;

    unsigned short* xh  = slA;   // 50000x128 (half the slab)
    unsigned short* h2h = slA;   // alive after x is dead
    unsigned short* mh  = (unsigned short*)zb;  // alive after zb is dead

    int gemm_grid = cdiv(NN, 32);      // 1563 blocks, 32-row tiles
    int head_grid = cdiv(NN, 64);
    int nodeblocks = cdiv(NN, 4);

    // weight cast + x cast (single launch)
    wcast_all_kernel<<<cdiv(278528 + NN * 128 / 4, 256), 256, 0, stream>>>(
        conv0_W, skip0_W, conv1_W, skip1_W, mlp_W1, mlp_W2, x,
        c0h, s0h, c1h, s1h, m1h, hWh, xh);

    // CSR build: bucketed, XCD-local writes
    hipMemsetAsync(bcount, 0, 256 * sizeof(int), stream);
    p1_bucket_hist<<<NB, 256, 0, stream>>>(edge_dst, bcount);
    p2_bucket_scan<<<1, 256, 0, stream>>>(bcount, bbase, gcur);
    p3_partition<<<NB, 256, 0, stream>>>(edge_src, edge_dst, gcur, ebuf);
    p4_bucket_csr<<<NB, 256, 0, stream>>>(ebuf, bbase, row_ptr, csr_src);

    // layer 0: fused conv+skip GEMM, then aggregate(+skip+ELU) -> h
    gemm_fused_kernel<<<gemm_grid, 256, 0, stream>>>(xh, c0h, s0h, NN, 128,
        zb, sraw, conv0_al, conv0_ar, el, er);
    aggregate_kernel<<<nodeblocks, 256, 0, stream>>>(row_ptr, csr_src,
        (const float4*)el, (const float4*)er, zb, conv0_b, sraw, skip0_b, hh, NN);

    // layer 1 (h2h aliases slA; xh dead after layer-0 gemm)
    gemm_fused_kernel<<<gemm_grid, 256, 0, stream>>>(hh, c1h, s1h, NN, 256,
        zb, sraw, conv1_al, conv1_ar, el, er);
    aggregate_kernel<<<nodeblocks, 256, 0, stream>>>(row_ptr, csr_src,
        (const float4*)el, (const float4*)er, zb, conv1_b, sraw, skip1_b, h2h, NN);

    // MLP head: m = relu(bn(h2 @ W1 + b1));  (mh aliases zb, dead now)
    gemm_bn_kernel<<<gemm_grid, 256, 0, stream>>>(h2h, m1h, NN, 256,
        mh, mlp_b1, bn_gamma, bn_beta, bn_mean, bn_var);
    head_kernel<<<head_grid, 256, 0, stream>>>(mh, hWh, mlp_b2, out, NN);
}

// Round 11
// 245.626 us; speedup vs baseline: 4.3579x; 1.0030x over previous
//
#include <hip/hip_runtime.h>
#include <math.h>

#define NN 50000
#define NE 800000
#define HID 256
#define NH 4
#define DH 64
#define NB 196          // dst buckets (dst >> 8), 256 dst each
#define CHUNK 4082      // cdiv(NE, NB)

static inline int cdiv(int a, int b) { return (a + b - 1) / b; }

typedef __attribute__((ext_vector_type(8))) short short8;
typedef __attribute__((ext_vector_type(4))) short short4v;
typedef __attribute__((ext_vector_type(4))) float f32x4;
typedef __attribute__((ext_vector_type(2))) float f32x2;

// bf16 helpers (round-to-nearest-even)
__device__ inline unsigned short f2bf(float x) {
    union { float f; unsigned u; } v; v.f = x;
    unsigned r = v.u + 0x7FFFu + ((v.u >> 16) & 1u);
    return (unsigned short)(r >> 16);
}
__device__ inline float bf2f(unsigned short h) {
    union { unsigned u; float f; } v; v.u = ((unsigned)h) << 16;
    return v.f;
}
__device__ inline short8 zero8() {
    short8 z;
#pragma unroll
    for (int j = 0; j < 8; j++) z[j] = 0;
    return z;
}
// fp8 e4m3 (OCP) encode via HW convert
__device__ inline unsigned char f2fp8(float x) {
    int p = __builtin_amdgcn_cvt_pk_fp8_f32(x, 0.f, 0, false);
    return (unsigned char)(p & 0xff);
}

// ------------------- CSR build: bucketed, XCD-local writes ---------------
__global__ __launch_bounds__(256) void p1_bucket_hist(const int* __restrict__ dst,
                                                      int* __restrict__ bcount) {
    __shared__ int h[NB];
    int tid = threadIdx.x;
    for (int i = tid; i < NB; i += 256) h[i] = 0;
    __syncthreads();
    int i0 = blockIdx.x * CHUNK;
    int n = min(CHUNK, NE - i0);
    for (int i = tid; i < n; i += 256) atomicAdd(&h[dst[i0 + i] >> 8], 1);
    __syncthreads();
    for (int i = tid; i < NB; i += 256)
        if (h[i]) atomicAdd(&bcount[i], h[i]);
}

__global__ __launch_bounds__(256) void p2_bucket_scan(const int* __restrict__ bcount,
                                                      int* __restrict__ bbase,
                                                      int* __restrict__ gcur) {
    __shared__ int s[256];
    int tid = threadIdx.x;
    int v = (tid < NB) ? bcount[tid] : 0;
    s[tid] = v;
    __syncthreads();
    for (int off = 1; off < 256; off <<= 1) {
        int t = (tid >= off) ? s[tid - off] : 0;
        __syncthreads();
        s[tid] += t;
        __syncthreads();
    }
    int ex = s[tid] - v;
    if (tid < NB) { bbase[tid] = ex; gcur[tid] = ex; }
    if (tid == NB - 1) bbase[NB] = s[tid];   // == NE
}

__global__ __launch_bounds__(256) void p3_partition(
    const int* __restrict__ src, const int* __restrict__ dst,
    int* __restrict__ gcur, uint2* __restrict__ ebuf) {
    __shared__ int cnt[NB], loff[NB], cur[NB], gpos[NB];
    __shared__ int s[256];
    __shared__ uint2 buf[CHUNK];
    int tid = threadIdx.x;
    int i0 = blockIdx.x * CHUNK;
    int n = min(CHUNK, NE - i0);
    for (int i = tid; i < NB; i += 256) cnt[i] = 0;
    __syncthreads();
    for (int i = tid; i < n; i += 256) atomicAdd(&cnt[dst[i0 + i] >> 8], 1);
    __syncthreads();
    int v = (tid < NB) ? cnt[tid] : 0;
    s[tid] = v;
    __syncthreads();
    for (int off = 1; off < 256; off <<= 1) {
        int t = (tid >= off) ? s[tid - off] : 0;
        __syncthreads();
        s[tid] += t;
        __syncthreads();
    }
    if (tid < NB) {
        int ex = s[tid] - v;
        loff[tid] = ex;
        cur[tid] = ex;
        gpos[tid] = v ? atomicAdd(&gcur[tid], v) : 0;
    }
    __syncthreads();
    for (int i = tid; i < n; i += 256) {
        int d = dst[i0 + i];
        int sv = src[i0 + i];
        int p = atomicAdd(&cur[d >> 8], 1);
        buf[p] = make_uint2((unsigned)sv, (unsigned)d);
    }
    __syncthreads();
    for (int i = tid; i < n; i += 256) {
        uint2 e = buf[i];
        int b = (int)(e.y >> 8);
        ebuf[gpos[b] + (i - loff[b])] = e;
    }
}

__global__ __launch_bounds__(256) void p4_bucket_csr(
    const uint2* __restrict__ ebuf, const int* __restrict__ bbase,
    int* __restrict__ row_ptr, int* __restrict__ csr_src) {
    __shared__ int hist[256], cur[256], s[256];
    int b = blockIdx.x;
    int tid = threadIdx.x;
    int e0 = bbase[b], e1 = bbase[b + 1];
    hist[tid] = 0;
    __syncthreads();
    for (int i = e0 + tid; i < e1; i += 256)
        atomicAdd(&hist[ebuf[i].y & 255], 1);
    __syncthreads();
    int v = hist[tid];
    s[tid] = v;
    __syncthreads();
    for (int off = 1; off < 256; off <<= 1) {
        int t = (tid >= off) ? s[tid - off] : 0;
        __syncthreads();
        s[tid] += t;
        __syncthreads();
    }
    int pre = s[tid] - v;
    cur[tid] = pre;
    int d = b * 256 + tid;
    if (d < NN) row_ptr[d] = e0 + pre;
    if (b == NB - 1 && tid == 0) row_ptr[NN] = NE;
    __syncthreads();
    for (int i = e0 + tid; i < e1; i += 256) {
        uint2 e = ebuf[i];
        int p = atomicAdd(&cur[e.y & 255], 1);
        csr_src[e0 + p] = (int)e.x;
    }
}

// ------------- weight cast (bf16, permuted frag order) + x cast ---------
__global__ void wcast_all_kernel(
    const float* __restrict__ c0W, const float* __restrict__ s0W,
    const float* __restrict__ c1W, const float* __restrict__ s1W,
    const float* __restrict__ m1W, const float* __restrict__ W2,
    const float* __restrict__ x,
    unsigned short* __restrict__ c0h, unsigned short* __restrict__ s0h,
    unsigned short* __restrict__ c1h, unsigned short* __restrict__ s1h,
    unsigned short* __restrict__ m1h, unsigned short* __restrict__ hWh,
    unsigned short* __restrict__ xh) {
    int i = blockIdx.x * blockDim.x + threadIdx.x;
    if (i >= 278528) {
        int j = i - 278528;               // float4 index into x
        if (j >= NN * 128 / 4) return;
        float4 v = ((const float4*)x)[j];
        short4v h;
        h[0] = (short)f2bf(v.x); h[1] = (short)f2bf(v.y);
        h[2] = (short)f2bf(v.z); h[3] = (short)f2bf(v.w);
        *(short4v*)&xh[j * 4] = h;
        return;
    }
    const float* W; unsigned short* H; int base; int head = 0;
    if (i < 32768)        { W = c0W; H = c0h; base = i; }
    else if (i < 65536)   { W = s0W; H = s0h; base = i - 32768; }
    else if (i < 131072)  { W = c1W; H = c1h; base = i - 65536; }
    else if (i < 196608)  { W = s1W; H = s1h; base = i - 131072; }
    else if (i < 262144)  { W = m1W; H = m1h; base = i - 196608; }
    else                  { W = W2;  H = hWh; base = i - 262144; head = 1; }
    float x_; int off;
    if (!head) {
        int k = base >> 8, n = base & 255;
        x_ = W[base];
        off = (k >> 5) * 8192 + (n >> 4) * 512 + ((k >> 3) & 3) * 128 + (n & 15) * 8 + (k & 7);
    } else {
        int k = base >> 6, n = base & 63;
        x_ = (n < 47) ? W[k * 47 + n] : 0.f;
        off = (k >> 5) * 2048 + (n >> 4) * 512 + ((k >> 3) & 3) * 128 + (n & 15) * 8 + (k & 7);
    }
    H[off] = f2bf(x_);
}

// ------------- fused conv+skip GEMM (plain bf16, B direct from L2) -------
__global__ __launch_bounds__(256) void gemm_fused_kernel(
    const unsigned short* __restrict__ Ah,
    const unsigned short* __restrict__ Wc, const unsigned short* __restrict__ Ws,
    int M, int K,
    unsigned char* __restrict__ zb, unsigned short* __restrict__ sraw,
    const float* __restrict__ al, const float* __restrict__ ar,
    float* __restrict__ el, float* __restrict__ er) {
    __shared__ short sA[2][1024];   // 32x32 bf16, frag-ordered, dbuf

    int tid = threadIdx.x;
    int lane = tid & 63;
    int wid = tid >> 6;
    int m0 = blockIdx.x * 32;

    f32x4 accc[2][4], accs[2][4];
#pragma unroll
    for (int i = 0; i < 2; i++)
#pragma unroll
        for (int j = 0; j < 4; j++) {
            accc[i][j] = (f32x4){0.f, 0.f, 0.f, 0.f};
            accs[i][j] = (f32x4){0.f, 0.f, 0.f, 0.f};
        }

    bool stager = (tid < 128);
    int t7 = tid & 127;
    int r = t7 >> 2, kq = t7 & 3;
    int gr = m0 + r;
    size_t abase = (size_t)gr * K + kq * 8;
    int aoff = (r >> 4) * 512 + kq * 128 + (r & 15) * 8;

    int nkt = K >> 5;
    if (stager) {
        short8 sreg = zero8();
        if (gr < M) sreg = *(const short8*)(Ah + abase);
        *(short8*)(&sA[0][0] + aoff) = sreg;
    }
    __syncthreads();

    const unsigned short* bcp = Wc + (wid * 4) * 512 + lane * 8;
    const unsigned short* bsp = Ws + (wid * 4) * 512 + lane * 8;

    for (int kt = 0; kt < nkt; kt++) {
        short8 nreg = zero8();
        if (stager && kt + 1 < nkt && gr < M)
            nreg = *(const short8*)(Ah + abase + (size_t)(kt + 1) * 32);
        short8 bc[4], bs[4];
#pragma unroll
        for (int nf = 0; nf < 4; nf++) {
            bc[nf] = *(const short8*)(bcp + kt * 8192 + nf * 512);
            bs[nf] = *(const short8*)(bsp + kt * 8192 + nf * 512);
        }
        const short* cur = &sA[kt & 1][0];
        short8 ah[2];
#pragma unroll
        for (int mf = 0; mf < 2; mf++)
            ah[mf] = *(const short8*)(cur + mf * 512 + lane * 8);
#pragma unroll
        for (int nf = 0; nf < 4; nf++)
#pragma unroll
            for (int mf = 0; mf < 2; mf++) {
                accc[mf][nf] = __builtin_amdgcn_mfma_f32_16x16x32_bf16(ah[mf], bc[nf], accc[mf][nf], 0, 0, 0);
                accs[mf][nf] = __builtin_amdgcn_mfma_f32_16x16x32_bf16(ah[mf], bs[nf], accs[mf][nf], 0, 0, 0);
            }
        if (stager && kt + 1 < nkt)
            *(short8*)(&sA[(kt + 1) & 1][0] + aoff) = nreg;
        __syncthreads();
    }

    // ---- epilogue: C layout col=lane&15, row=(lane>>4)*4+reg ----
#pragma unroll
    for (int mf = 0; mf < 2; mf++) {
        int row0 = m0 + mf * 16 + (lane >> 4) * 4;
#pragma unroll
        for (int reg = 0; reg < 4; reg++) {
            int row = row0 + reg;
            if (row >= M) continue;
            size_t rb = (size_t)row * HID;
#pragma unroll
            for (int nf = 0; nf < 4; nf++) {
                int col = wid * 64 + nf * 16 + (lane & 15);
                zb[rb + col] = f2fp8(accc[mf][nf][reg]);
                sraw[rb + col] = f2bf(accs[mf][nf][reg]);
            }
        }
    }

    // ---- fused attention scores: wave wid == head wid ----
    {
        float alv[4], arv[4];
#pragma unroll
        for (int nf = 0; nf < 4; nf++) {
            int col = wid * 64 + nf * 16 + (lane & 15);
            alv[nf] = al[col];
            arv[nf] = ar[col];
        }
#pragma unroll
        for (int mf = 0; mf < 2; mf++) {
#pragma unroll
            for (int reg = 0; reg < 4; reg++) {
                float pl = 0.f, pr = 0.f;
#pragma unroll
                for (int nf = 0; nf < 4; nf++) {
                    pl = fmaf(accc[mf][nf][reg], alv[nf], pl);
                    pr = fmaf(accc[mf][nf][reg], arv[nf], pr);
                }
#pragma unroll
                for (int off = 8; off; off >>= 1) {
                    pl += __shfl_xor(pl, off);
                    pr += __shfl_xor(pr, off);
                }
                int row = m0 + mf * 16 + (lane >> 4) * 4 + reg;
                if ((lane & 15) == 0 && row < M) {
                    el[row * 4 + wid] = pl;
                    er[row * 4 + wid] = pr;
                }
            }
        }
    }
}

// ---------- GAT aggregate v2: 4 rows/iter, 16 lanes/row, fused skip/ELU --
// one wave per dst node. Phase 1: lane = (edge sl, head grp), chunk=16 edges.
// Phase 2: 4 z-rows per iteration; lane reads 16 fp8 (16B) of row (e4+grp).
// h = elu(agg_avg + conv_b + sraw + skip_b) -> bf16
__global__ __launch_bounds__(256) void aggregate_kernel(
    const int* __restrict__ row_ptr, const int* __restrict__ csr_src,
    const float* __restrict__ el, const float4* __restrict__ er4,
    const unsigned char* __restrict__ zb, const float* __restrict__ conv_b,
    const unsigned short* __restrict__ sraw, const float* __restrict__ skip_b,
    unsigned short* __restrict__ outh, int n) {
    __shared__ float s_w[4][NH][16];
    __shared__ int s_s[4][16];
    int wid = threadIdx.x >> 6;
    int lane = threadIdx.x & 63;
    int node = blockIdx.x * 4 + wid;
    if (node >= n) return;
    int rb = row_ptr[node];
    int deg = row_ptr[node + 1] - rb;
    int sl = lane & 15;        // edge index in chunk (P1) / feature group (P2)
    int grp = lane >> 4;       // head (P1) / row slot (P2)
    int myh = sl >> 2;         // head owning features [16*sl, +16)
    float4 ern = er4[node];
    float erh = (grp == 0) ? ern.x : (grp == 1) ? ern.y : (grp == 2) ? ern.z : ern.w;

    float acc[16];
#pragma unroll
    for (int j = 0; j < 16; j++) acc[j] = 0.f;
    float wloc = 0.f;          // head `grp` partial denom

    for (int c = 0; c < deg; c += 16) {
        int i = c + sl;
        int cnt = min(16, deg - c);
        if (i < deg) {
            int s = csr_src[rb + i];
            if (grp == 0) s_s[wid][sl] = s;
            float e = el[(s << 2) + grp] + erh;
            e = (e > 0.f) ? e : 0.2f * e;
            float ee = __expf(e);
            s_w[wid][grp][sl] = ee;
            wloc += ee;
        }
        __builtin_amdgcn_wave_barrier();
        for (int e4 = 0; e4 < cnt; e4 += 4) {
            int ei = e4 + grp;
            if (ei < cnt) {
                int s = s_s[wid][ei];
                float wgt = s_w[wid][myh][ei];
                uint4 zv = *(const uint4*)(zb + (size_t)s * HID + sl * 16);
                f32x2 d0 = __builtin_amdgcn_cvt_pk_f32_fp8((int)zv.x, false);
                f32x2 d1 = __builtin_amdgcn_cvt_pk_f32_fp8((int)zv.x, true);
                f32x2 d2 = __builtin_amdgcn_cvt_pk_f32_fp8((int)zv.y, false);
                f32x2 d3 = __builtin_amdgcn_cvt_pk_f32_fp8((int)zv.y, true);
                f32x2 d4 = __builtin_amdgcn_cvt_pk_f32_fp8((int)zv.z, false);
                f32x2 d5 = __builtin_amdgcn_cvt_pk_f32_fp8((int)zv.z, true);
                f32x2 d6 = __builtin_amdgcn_cvt_pk_f32_fp8((int)zv.w, false);
                f32x2 d7 = __builtin_amdgcn_cvt_pk_f32_fp8((int)zv.w, true);
                acc[0]  = fmaf(wgt, d0[0], acc[0]);
                acc[1]  = fmaf(wgt, d0[1], acc[1]);
                acc[2]  = fmaf(wgt, d1[0], acc[2]);
                acc[3]  = fmaf(wgt, d1[1], acc[3]);
                acc[4]  = fmaf(wgt, d2[0], acc[4]);
                acc[5]  = fmaf(wgt, d2[1], acc[5]);
                acc[6]  = fmaf(wgt, d3[0], acc[6]);
                acc[7]  = fmaf(wgt, d3[1], acc[7]);
                acc[8]  = fmaf(wgt, d4[0], acc[8]);
                acc[9]  = fmaf(wgt, d4[1], acc[9]);
                acc[10] = fmaf(wgt, d5[0], acc[10]);
                acc[11] = fmaf(wgt, d5[1], acc[11]);
                acc[12] = fmaf(wgt, d6[0], acc[12]);
                acc[13] = fmaf(wgt, d6[1], acc[13]);
                acc[14] = fmaf(wgt, d7[0], acc[14]);
                acc[15] = fmaf(wgt, d7[1], acc[15]);
            }
        }
        __builtin_amdgcn_wave_barrier();
    }

    // denom: reduce head partials within each 16-lane group, then broadcast
#pragma unroll
    for (int off = 1; off < 16; off <<= 1) wloc += __shfl_xor(wloc, off);
    float wsum_my = __shfl(wloc, myh << 4);
    float inv = (wsum_my > 0.f) ? 1.f / wsum_my : 0.f;

    // cross-slot feature reduce: after this every lane holds full sums
#pragma unroll
    for (int j = 0; j < 16; j++) {
        acc[j] += __shfl_xor(acc[j], 16);
        acc[j] += __shfl_xor(acc[j], 32);
    }

    // epilogue: lane writes features [16*sl + 4*grp, +4) (compile-time idx)
#define SELA(k) ((grp & 2) ? ((grp & 1) ? acc[12 + (k)] : acc[8 + (k)]) \
                           : ((grp & 1) ? acc[4 + (k)]  : acc[0 + (k)]))
    int g0 = (sl << 4) + (grp << 2);
    float4 cb = *(const float4*)(conv_b + g0);
    float4 sb = *(const float4*)(skip_b + g0);
    uint2 sv = *(const uint2*)(sraw + (size_t)node * HID + g0);
    union { unsigned u; float f; } s0, s1, s2, s3;
    s0.u = sv.x << 16; s1.u = sv.x & 0xffff0000u;
    s2.u = sv.y << 16; s3.u = sv.y & 0xffff0000u;
    float v0 = SELA(0) * inv + cb.x + s0.f + sb.x;
    float v1 = SELA(1) * inv + cb.y + s1.f + sb.y;
    float v2 = SELA(2) * inv + cb.z + s2.f + sb.z;
    float v3 = SELA(3) * inv + cb.w + s3.f + sb.w;
#undef SELA
    v0 = (v0 > 0.f) ? v0 : expm1f(v0);
    v1 = (v1 > 0.f) ? v1 : expm1f(v1);
    v2 = (v2 > 0.f) ? v2 : expm1f(v2);
    v3 = (v3 > 0.f) ? v3 : expm1f(v3);
    short4v o;
    o[0] = (short)f2bf(v0); o[1] = (short)f2bf(v1);
    o[2] = (short)f2bf(v2); o[3] = (short)f2bf(v3);
    *(short4v*)(outh + (size_t)node * HID + g0) = o;
}

// ------------------------- MLP GEMM (plain bf16): relu(bn(A@W1+b1)) ------
__global__ __launch_bounds__(256) void gemm_bn_kernel(
    const unsigned short* __restrict__ Ah, const unsigned short* __restrict__ Bh_g,
    int M, int K, unsigned short* __restrict__ C,
    const float* __restrict__ bias, const float* __restrict__ g,
    const float* __restrict__ bt, const float* __restrict__ mean,
    const float* __restrict__ var) {
    __shared__ short sA[2][1024];
    int tid = threadIdx.x;
    int lane = tid & 63;
    int wid = tid >> 6;
    int m0 = blockIdx.x * 32;

    f32x4 acc[2][4];
#pragma unroll
    for (int i = 0; i < 2; i++)
#pragma unroll
        for (int j = 0; j < 4; j++) acc[i][j] = (f32x4){0.f, 0.f, 0.f, 0.f};

    bool stager = (tid < 128);
    int t7 = tid & 127;
    int r = t7 >> 2, kq = t7 & 3;
    int gr = m0 + r;
    size_t abase = (size_t)gr * K + kq * 8;
    int aoff = (r >> 4) * 512 + kq * 128 + (r & 15) * 8;

    int nkt = K >> 5;
    if (stager) {
        short8 sreg = zero8();
        if (gr < M) sreg = *(const short8*)(Ah + abase);
        *(short8*)(&sA[0][0] + aoff) = sreg;
    }
    __syncthreads();

    const unsigned short* bhp = Bh_g + (wid * 4) * 512 + lane * 8;

    for (int kt = 0; kt < nkt; kt++) {
        short8 nreg = zero8();
        if (stager && kt + 1 < nkt && gr < M)
            nreg = *(const short8*)(Ah + abase + (size_t)(kt + 1) * 32);
        short8 bh[4];
#pragma unroll
        for (int nf = 0; nf < 4; nf++)
            bh[nf] = *(const short8*)(bhp + kt * 8192 + nf * 512);
        const short* cur = &sA[kt & 1][0];
        short8 ah[2];
#pragma unroll
        for (int mf = 0; mf < 2; mf++)
            ah[mf] = *(const short8*)(cur + mf * 512 + lane * 8);
#pragma unroll
        for (int nf = 0; nf < 4; nf++)
#pragma unroll
            for (int mf = 0; mf < 2; mf++)
                acc[mf][nf] = __builtin_amdgcn_mfma_f32_16x16x32_bf16(ah[mf], bh[nf], acc[mf][nf], 0, 0, 0);
        if (stager && kt + 1 < nkt)
            *(short8*)(&sA[(kt + 1) & 1][0] + aoff) = nreg;
        __syncthreads();
    }

#pragma unroll
    for (int mf = 0; mf < 2; mf++) {
        int row0 = m0 + mf * 16 + (lane >> 4) * 4;
#pragma unroll
        for (int reg = 0; reg < 4; reg++) {
            int row = row0 + reg;
            if (row >= M) continue;
            size_t rb = (size_t)row * HID;
#pragma unroll
            for (int nf = 0; nf < 4; nf++) {
                int col = wid * 64 + nf * 16 + (lane & 15);
                float v = acc[mf][nf][reg];
                float s = g[col] * rsqrtf(var[col] + 1e-5f);
                v = (v + bias[col] - mean[col]) * s + bt[col];
                C[rb + col] = f2bf(fmaxf(v, 0.f));
            }
        }
    }
}

// ------------------------- MFMA head: logits + log_softmax ---------------
__global__ __launch_bounds__(256) void head_kernel(
    const unsigned short* __restrict__ Ah, const unsigned short* __restrict__ Bh_g,
    const float* __restrict__ b2, float* __restrict__ out, int M) {
    __shared__ short sA[2048];    // 64x32
    int tid = threadIdx.x;
    int lane = tid & 63;
    int wid = tid >> 6;
    int m0 = blockIdx.x * 64;

    f32x4 acc[4];
#pragma unroll
    for (int nf = 0; nf < 4; nf++) acc[nf] = (f32x4){0.f, 0.f, 0.f, 0.f};

    for (int kt = 0; kt < 8; kt++) {
        {
            int r = tid >> 2, kq = tid & 3;
            int gr = m0 + r;
            short8 h8 = zero8();
            if (gr < M) h8 = *(const short8*)(Ah + (size_t)gr * HID + kt * 32 + kq * 8);
            int off = (r >> 4) * 512 + kq * 128 + (r & 15) * 8;
            *(short8*)&sA[off] = h8;
        }
        __syncthreads();
        short8 ah = *(const short8*)&sA[wid * 512 + lane * 8];
#pragma unroll
        for (int nf = 0; nf < 4; nf++) {
            short8 bh = *(const short8*)(Bh_g + kt * 2048 + nf * 512 + lane * 8);
            acc[nf] = __builtin_amdgcn_mfma_f32_16x16x32_bf16(ah, bh, acc[nf], 0, 0, 0);
        }
        __syncthreads();
    }

    // fused log-softmax over 47 valid cols; row = m0+wid*16+(lane>>4)*4+reg
    int col0 = lane & 15;
    float bias_[4];
#pragma unroll
    for (int nf = 0; nf < 4; nf++) {
        int col = nf * 16 + col0;
        bias_[nf] = (col < 47) ? b2[col] : 0.f;
    }
#pragma unroll
    for (int reg = 0; reg < 4; reg++) {
        int row = m0 + wid * 16 + (lane >> 4) * 4 + reg;
        float lg[4];
        float mx = -INFINITY;
#pragma unroll
        for (int nf = 0; nf < 4; nf++) {
            int col = nf * 16 + col0;
            float v = acc[nf][reg] + bias_[nf];
            lg[nf] = v;
            if (col < 47) mx = fmaxf(mx, v);
        }
#pragma unroll
        for (int off = 8; off; off >>= 1) mx = fmaxf(mx, __shfl_xor(mx, off));
        float s = 0.f;
#pragma unroll
        for (int nf = 0; nf < 4; nf++) {
            int col = nf * 16 + col0;
            if (col < 47) s += __expf(lg[nf] - mx);
        }
#pragma unroll
        for (int off = 8; off; off >>= 1) s += __shfl_xor(s, off);
        float li = logf(s);
        if (row < M) {
#pragma unroll
            for (int nf = 0; nf < 3; nf++) {
                int col = nf * 16 + col0;
                if (col < 47) out[(size_t)row * 47 + col] = lg[nf] - mx - li;
            }
        }
    }
}

// ------------------------- launch -------------------------
extern "C" void kernel_launch(void* const* d_in, const int* in_sizes, int n_in,
                              void* d_out, int out_size, void* d_ws, size_t ws_size,
                              hipStream_t stream) {
    const float* x        = (const float*)d_in[0];
    const float* conv0_W  = (const float*)d_in[1];
    const float* conv0_al = (const float*)d_in[2];
    const float* conv0_ar = (const float*)d_in[3];
    const float* conv0_b  = (const float*)d_in[4];
    const float* skip0_W  = (const float*)d_in[5];
    const float* skip0_b  = (const float*)d_in[6];
    const float* conv1_W  = (const float*)d_in[7];
    const float* conv1_al = (const float*)d_in[8];
    const float* conv1_ar = (const float*)d_in[9];
    const float* conv1_b  = (const float*)d_in[10];
    const float* skip1_W  = (const float*)d_in[11];
    const float* skip1_b  = (const float*)d_in[12];
    const float* mlp_W1   = (const float*)d_in[13];
    const float* mlp_b1   = (const float*)d_in[14];
    const float* bn_gamma = (const float*)d_in[15];
    const float* bn_beta  = (const float*)d_in[16];
    const float* bn_mean  = (const float*)d_in[17];
    const float* bn_var   = (const float*)d_in[18];
    const float* mlp_W2   = (const float*)d_in[19];
    const float* mlp_b2   = (const float*)d_in[20];
    const int* edge_src   = (const int*)d_in[21];
    const int* edge_dst   = (const int*)d_in[22];
    float* out = (float*)d_out;

    // workspace carve-up (with aliasing)
    char* w = (char*)d_ws;
    size_t off = 0;
    auto alloc = [&](size_t bytes) {
        char* p = w + off;
        off += (bytes + 255) & ~(size_t)255;
        return p;
    };
    int*    row_ptr = (int*)alloc((NN + 1) * sizeof(int));
    int*    bcount  = (int*)alloc(256 * sizeof(int));
    int*    bbase   = (int*)alloc(256 * sizeof(int));
    int*    gcur    = (int*)alloc(256 * sizeof(int));
    int*    csr_src = (int*)alloc(NE * sizeof(int));
    uint2*  ebuf    = (uint2*)alloc((size_t)NE * sizeof(uint2));
    float*  el      = (float*)alloc((size_t)NN * 4 * sizeof(float));
    float*  er      = (float*)alloc((size_t)NN * 4 * sizeof(float));
    unsigned char*  zb   = (unsigned char*)alloc((size_t)NN * HID * 2);   // fp8 z; later m (bf16)
    unsigned short* sraw = (unsigned short*)alloc((size_t)NN * HID * 2);  // skip raw bf16
    unsigned short* slA  = (unsigned short*)alloc((size_t)NN * HID * 2);  // xh then h2h
    unsigned short* hh   = (unsigned short*)alloc((size_t)NN * HID * 2);  // h
    unsigned short* c0h = (unsigned short*)alloc(128 * 256 * 2);
    unsigned short* s0h = (unsigned short*)alloc(128 * 256 * 2);
    unsigned short* c1h = (unsigned short*)alloc(256 * 256 * 2);
    unsigned short* s1h = (unsigned short*)alloc(256 * 256 * 2);
    unsigned short* m1h = (unsigned short*)alloc(256 * 256 * 2);
    unsigned short* hWh = (unsigned short*)alloc(256 * 64 * 2);
    (void)ws_size;

    unsigned short* xh  = slA;   // 50000x128 (half the slab)
    unsigned short* h2h = slA;   // alive after x is dead
    unsigned short* mh  = (unsigned short*)zb;  // alive after zb is dead

    int gemm_grid = cdiv(NN, 32);      // 1563 blocks, 32-row tiles
    int head_grid = cdiv(NN, 64);
    int nodeblocks = cdiv(NN, 4);

    // weight cast + x cast (single launch)
    wcast_all_kernel<<<cdiv(278528 + NN * 128 / 4, 256), 256, 0, stream>>>(
        conv0_W, skip0_W, conv1_W, skip1_W, mlp_W1, mlp_W2, x,
        c0h, s0h, c1h, s1h, m1h, hWh, xh);

    // CSR build: bucketed, XCD-local writes
    hipMemsetAsync(bcount, 0, 256 * sizeof(int), stream);
    p1_bucket_hist<<<NB, 256, 0, stream>>>(edge_dst, bcount);
    p2_bucket_scan<<<1, 256, 0, stream>>>(bcount, bbase, gcur);
    p3_partition<<<NB, 256, 0, stream>>>(edge_src, edge_dst, gcur, ebuf);
    p4_bucket_csr<<<NB, 256, 0, stream>>>(ebuf, bbase, row_ptr, csr_src);

    // layer 0: fused conv+skip GEMM, then aggregate(+skip+ELU) -> h
    gemm_fused_kernel<<<gemm_grid, 256, 0, stream>>>(xh, c0h, s0h, NN, 128,
        zb, sraw, conv0_al, conv0_ar, el, er);
    aggregate_kernel<<<nodeblocks, 256, 0, stream>>>(row_ptr, csr_src,
        el, (const float4*)er, zb, conv0_b, sraw, skip0_b, hh, NN);

    // layer 1 (h2h aliases slA; xh dead after layer-0 gemm)
    gemm_fused_kernel<<<gemm_grid, 256, 0, stream>>>(hh, c1h, s1h, NN, 256,
        zb, sraw, conv1_al, conv1_ar, el, er);
    aggregate_kernel<<<nodeblocks, 256, 0, stream>>>(row_ptr, csr_src,
        el, (const float4*)er, zb, conv1_b, sraw, skip1_b, h2h, NN);

    // MLP head: m = relu(bn(h2 @ W1 + b1));  (mh aliases zb, dead now)
    gemm_bn_kernel<<<gemm_grid, 256, 0, stream>>>(h2h, m1h, NN, 256,
        mh, mlp_b1, bn_gamma, bn_beta, bn_mean, bn_var);
    head_kernel<<<head_grid, 256, 0, stream>>>(mh, hWh, mlp_b2, out, NN);
}